// Round 5
// baseline (3041.072 us; speedup 1.0000x reference)
//
#include <hip/hip_runtime.h>
#include <cstddef>
#include <cstdint>

#define EPS_BN 1e-5f
#define NBINS 4
#define NEG_INF (-__builtin_inff())

// =====================================================================
// Tiled fp32 GEMM:  Y[r][o] = sum_ci X'[r][ci] * W[o][ci]   (Y = X' W^T)
// 128x128 tile, BK=16, 256 threads, 8x8 microtile/thread (split
// quadrants, <=2-way LDS reads). R multiple of 128; Cout guarded.
// FUSE_IN:  X' = relu((X - mean)*scale) from st_in bins (prev layer BN).
// FUSE_MAX: instead of storing Y, store per-(ns-group, col) max of raw Y
//           into pooled[G][Cout]. Valid because ns | 128 (each tile has
//           only complete groups) and grid.y column ranges are disjoint
//           -> exactly one block writes each pooled element, no atomics.
//           BN+relu applied later on the pooled value (monotone => same
//           result as reference, exact fmaxf).
// Epilogue always: per-column sum/sumsq of raw Y into st_out bins.
// =====================================================================
template <bool FUSE_IN, bool FUSE_MAX>
__global__ __launch_bounds__(256) void gemm_xwt(const float* __restrict__ X,
                                                const float* __restrict__ Wm,
                                                float* __restrict__ Y,
                                                int R, int Cin, int Cout,
                                                const float* __restrict__ st_in, int Rin,
                                                float* __restrict__ st_out,
                                                float* __restrict__ pooled, int ns) {
  __shared__ __align__(16) float Xs[16][132];
  __shared__ __align__(16) float Ws[16][132];
  __shared__ float sMean[512], sScale[512];
  const int t  = threadIdx.x;
  const int r0 = blockIdx.x << 7;
  const int n0 = blockIdx.y << 7;
  const int tx = t & 15;
  const int ty = t >> 4;

  if constexpr (FUSE_IN) {
    const float inv = 1.f / (float)Rin;
    for (int k = t; k < Cin; k += 256) {
      float s = 0.f, q = 0.f;
#pragma unroll
      for (int bn = 0; bn < NBINS; ++bn) {
        s += st_in[bn * 2 * Cin + k];
        q += st_in[bn * 2 * Cin + Cin + k];
      }
      const float m  = s * inv;
      const float vr = fmaf(-m, m, q * inv);
      sMean[k]  = m;
      sScale[k] = rsqrtf(vr + EPS_BN);
    }
    __syncthreads();
  }

  float acc[8][8] = {};
  const int rStage = t >> 1;
  const int kBase  = (t & 1) << 3;
  const int nr     = n0 + rStage;

  for (int k0 = 0; k0 < Cin; k0 += 16) {
    const float* xrow = X  + (size_t)(r0 + rStage) * Cin + k0 + kBase;
    const float* wrow = Wm + (size_t)nr * Cin + k0 + kBase;
    if (((Cin & 3) == 0) && (k0 + 16 <= Cin)) {
      float4 xa = *(const float4*)(xrow);
      float4 xb = *(const float4*)(xrow + 4);
      if constexpr (FUSE_IN) {
        const int kb = k0 + kBase;
        xa.x = fmaxf(0.f, (xa.x - sMean[kb + 0]) * sScale[kb + 0]);
        xa.y = fmaxf(0.f, (xa.y - sMean[kb + 1]) * sScale[kb + 1]);
        xa.z = fmaxf(0.f, (xa.z - sMean[kb + 2]) * sScale[kb + 2]);
        xa.w = fmaxf(0.f, (xa.w - sMean[kb + 3]) * sScale[kb + 3]);
        xb.x = fmaxf(0.f, (xb.x - sMean[kb + 4]) * sScale[kb + 4]);
        xb.y = fmaxf(0.f, (xb.y - sMean[kb + 5]) * sScale[kb + 5]);
        xb.z = fmaxf(0.f, (xb.z - sMean[kb + 6]) * sScale[kb + 6]);
        xb.w = fmaxf(0.f, (xb.w - sMean[kb + 7]) * sScale[kb + 7]);
      }
      Xs[kBase + 0][rStage] = xa.x; Xs[kBase + 1][rStage] = xa.y;
      Xs[kBase + 2][rStage] = xa.z; Xs[kBase + 3][rStage] = xa.w;
      Xs[kBase + 4][rStage] = xb.x; Xs[kBase + 5][rStage] = xb.y;
      Xs[kBase + 6][rStage] = xb.z; Xs[kBase + 7][rStage] = xb.w;
      float4 wa = {0, 0, 0, 0}, wb = {0, 0, 0, 0};
      if (nr < Cout) { wa = *(const float4*)(wrow); wb = *(const float4*)(wrow + 4); }
      Ws[kBase + 0][rStage] = wa.x; Ws[kBase + 1][rStage] = wa.y;
      Ws[kBase + 2][rStage] = wa.z; Ws[kBase + 3][rStage] = wa.w;
      Ws[kBase + 4][rStage] = wb.x; Ws[kBase + 5][rStage] = wb.y;
      Ws[kBase + 6][rStage] = wb.z; Ws[kBase + 7][rStage] = wb.w;
    } else {
#pragma unroll
      for (int u = 0; u < 8; ++u) {
        const int k = k0 + kBase + u;
        float xe = 0.f, we = 0.f;
        if (k < Cin) {
          xe = xrow[u];
          if constexpr (FUSE_IN) xe = fmaxf(0.f, (xe - sMean[k]) * sScale[k]);
          if (nr < Cout) we = wrow[u];
        }
        Xs[kBase + u][rStage] = xe;
        Ws[kBase + u][rStage] = we;
      }
    }
    __syncthreads();
#pragma unroll
    for (int kk = 0; kk < 16; ++kk) {
      const float4 a0 = *(const float4*)(&Xs[kk][ty << 2]);
      const float4 a1 = *(const float4*)(&Xs[kk][64 + (ty << 2)]);
      const float4 b0 = *(const float4*)(&Ws[kk][tx << 2]);
      const float4 b1 = *(const float4*)(&Ws[kk][64 + (tx << 2)]);
      const float av[8] = {a0.x, a0.y, a0.z, a0.w, a1.x, a1.y, a1.z, a1.w};
      const float bw[8] = {b0.x, b0.y, b0.z, b0.w, b1.x, b1.y, b1.z, b1.w};
#pragma unroll
      for (int i = 0; i < 8; ++i)
#pragma unroll
        for (int j = 0; j < 8; ++j) acc[i][j] = fmaf(av[i], bw[j], acc[i][j]);
    }
    __syncthreads();
  }
  if constexpr (!FUSE_MAX) {
#pragma unroll
    for (int h = 0; h < 2; ++h)
#pragma unroll
      for (int i = 0; i < 4; ++i) {
        const int r = r0 + h * 64 + (ty << 2) + i;
        float* yr = Y + (size_t)r * Cout;
#pragma unroll
        for (int g = 0; g < 2; ++g) {
          const int n = n0 + g * 64 + (tx << 2);
          if (n < Cout) {
            float4 o = {acc[h * 4 + i][g * 4 + 0], acc[h * 4 + i][g * 4 + 1],
                        acc[h * 4 + i][g * 4 + 2], acc[h * 4 + i][g * 4 + 3]};
            *(float4*)(yr + n) = o;
          }
        }
      }
  }
  // stats epilogue: per-column partials -> LDS reduce -> binned atomics
#pragma unroll
  for (int g = 0; g < 2; ++g)
#pragma unroll
    for (int j = 0; j < 4; ++j) {
      float s = 0.f, q = 0.f;
#pragma unroll
      for (int rh = 0; rh < 8; ++rh) {
        const float v = acc[rh][g * 4 + j];
        s += v;
        q = fmaf(v, v, q);
      }
      Xs[ty][g * 64 + (tx << 2) + j] = s;
      Ws[ty][g * 64 + (tx << 2) + j] = q;
    }
  __syncthreads();
  if (t < 128) {
    const int n = n0 + t;
    if (n < Cout) {
      float s = 0.f, q = 0.f;
#pragma unroll
      for (int w = 0; w < 16; ++w) { s += Xs[w][t]; q += Ws[w][t]; }
      float* dst = st_out + (blockIdx.x & (NBINS - 1)) * 2 * Cout;
      atomicAdd(dst + n, s);
      atomicAdd(dst + Cout + n, q);
    }
  }
  // maxpool epilogue: ns in {32, 64, 128}
  if constexpr (FUSE_MAX) {
    __syncthreads();  // stats reduce done reading Xs/Ws
    float mxAll = NEG_INF;  // used only for ns==128 path (t<128)
#pragma unroll
    for (int h = 0; h < 2; ++h) {
      // thread's per-col max over its 4 rows in this half
#pragma unroll
      for (int g2 = 0; g2 < 2; ++g2)
#pragma unroll
        for (int j = 0; j < 4; ++j) {
          float mx = acc[h * 4 + 0][g2 * 4 + j];
          mx = fmaxf(mx, acc[h * 4 + 1][g2 * 4 + j]);
          mx = fmaxf(mx, acc[h * 4 + 2][g2 * 4 + j]);
          mx = fmaxf(mx, acc[h * 4 + 3][g2 * 4 + j]);
          Xs[ty][g2 * 64 + (tx << 2) + j] = mx;
        }
      __syncthreads();
      if (t < 128) {
        const int n = n0 + t;
        if (n < Cout) {
          if (ns <= 64) {
            const int tpg = ns >> 2;        // ty's per group
            const int gph = 64 / ns;        // groups per 64-row half
            for (int gq = 0; gq < gph; ++gq) {
              float mx = NEG_INF;
              for (int w = gq * tpg; w < gq * tpg + tpg; ++w) mx = fmaxf(mx, Xs[w][t]);
              const int g = (r0 + h * 64) / ns + gq;
              pooled[(size_t)g * Cout + n] = mx;
            }
          } else {  // ns == 128: single group spans both halves
            float mx = NEG_INF;
            for (int w = 0; w < 16; ++w) mx = fmaxf(mx, Xs[w][t]);
            mxAll = fmaxf(mxAll, mx);
          }
        }
      }
      __syncthreads();
    }
    if (ns > 64 && t < 128) {
      const int n = n0 + t;
      if (n < Cout) pooled[(size_t)(r0 >> 7) * Cout + n] = mxAll;
    }
  }
}

// BN apply on an already-pooled G x C buffer (Rtrue = rows of the raw Y)
__global__ void bn_apply_pooled(const float* __restrict__ P, const float* __restrict__ st,
                                float* __restrict__ o, int G, int C, int Rtrue) {
  const int i = blockIdx.x * 256 + threadIdx.x;
  if (i >= G * C) return;
  const int c = i % C;
  float s = 0.f, q = 0.f;
#pragma unroll
  for (int bn = 0; bn < NBINS; ++bn) {
    s += st[bn * 2 * C + c];
    q += st[bn * 2 * C + C + c];
  }
  const float inv = 1.f / (float)Rtrue;
  const float m  = s * inv;
  const float vr = fmaf(-m, m, q * inv);
  const float sc = rsqrtf(vr + EPS_BN);
  o[i] = fmaxf(0.f, (P[i] - m) * sc);
}

// normalize -> relu -> max over ns rows per group (gripper path, ns=512)
__global__ void bn_apply_relu_maxpool(const float* __restrict__ Y,
                                      const float* __restrict__ st,
                                      float* __restrict__ o, int G, int ns, int C) {
  const int i = blockIdx.x * 256 + threadIdx.x;
  if (i >= G * C) return;
  const int c = i % C;
  const int g = i / C;
  float s = 0.f, q = 0.f;
#pragma unroll
  for (int bn = 0; bn < NBINS; ++bn) {
    s += st[bn * 2 * C + c];
    q += st[bn * 2 * C + C + c];
  }
  const int R = G * ns;
  const float inv = 1.f / (float)R;
  const float m  = s * inv;
  const float vr = fmaf(-m, m, q * inv);
  const float sc = rsqrtf(vr + EPS_BN);
  const float* p = Y + (size_t)g * ns * C + c;
  float mx = NEG_INF;
  for (int k = 0; k < ns; ++k) mx = fmaxf(mx, p[(size_t)k * C]);
  o[i] = fmaxf(0.f, (mx - m) * sc);
}

// =====================================================================
// FPS for SA1 (N=20000 -> 512) — R18: R5's exact step structure (scan ->
// 64-lane butterfly -> owner-detect sv write -> barrier -> wave0 16-wide
// reduce -> bc broadcast -> barrier), with the scan converted to FULL
// REGISTER residency: all 20 point-groups (coords + dd) live in VGPRs
// (~80 regs). R5's hybrid kept 12 groups' coords in global (re-read from
// L2 every step, ~147 KB/block/step) and dd in LDS (ds_read+ds_write
// round-trips) — that machinery was ~2.5k of the 6.6k cyc/step. The grid
// is 8 blocks (one 1024-thread block per CU), so nothing co-resides and
// VGPR count is free up to the 128/thread cap of a 16-wave block.
// Selection semantics bit-identical to R5 (absmax 0.0): same ascending
// group order with identical index formula tid + k*1024, same
// __fmul_rn/__fadd_rn/fminf chain, same strict-> update, same two-barrier
// owner-detect reduce verbatim. R17's single-barrier all-wave reduce
// reverted (+53 us regression).
// =====================================================================
#define FPS_NG 20

__global__ __launch_bounds__(1024)
void fps_sa1_kernel(const float* __restrict__ xyz, float* __restrict__ new_xyz) {
  const int b    = blockIdx.x;
  const int tid  = threadIdx.x;
  const int lane = tid & 63;
  const int wave = tid >> 6;  // 0..15
  const float* p = xyz + (size_t)b * 20000 * 3;

  __shared__ float sv[16], sx[16], sy[16], sz[16];
  __shared__ int   si[16];
  __shared__ float bc[3];

  float px[FPS_NG], py[FPS_NG], pz[FPS_NG], dd[FPS_NG];
#pragma unroll
  for (int k = 0; k < FPS_NG; ++k) {
    const int i = tid + (k << 10);
    if (i < 20000) {
      px[k] = p[i * 3 + 0]; py[k] = p[i * 3 + 1]; pz[k] = p[i * 3 + 2];
      dd[k] = 1e10f;
    } else {
      px[k] = 0.f; py[k] = 0.f; pz[k] = 0.f;
      dd[k] = NEG_INF;
    }
  }

  float fx = p[0], fy = p[1], fz = p[2];
  if (tid == 0) {
    float* o = new_xyz + (size_t)b * 512 * 3;
    o[0] = fx; o[1] = fy; o[2] = fz;
  }
  __syncthreads();

  for (int s = 1; s < 512; ++s) {
    float bv = NEG_INF;
    int   bi = 0x7fffffff;
    float bx = 0.f, by = 0.f, bz = 0.f;
#pragma unroll
    for (int k = 0; k < FPS_NG; ++k) {
      const float dx = px[k] - fx, dy = py[k] - fy, dz = pz[k] - fz;
      const float d  = __fadd_rn(__fadd_rn(__fmul_rn(dx, dx), __fmul_rn(dy, dy)),
                                 __fmul_rn(dz, dz));
      const float nd = fminf(dd[k], d);
      dd[k] = nd;
      if (nd > bv) { bv = nd; bi = tid + (k << 10); bx = px[k]; by = py[k]; bz = pz[k]; }
    }
    float v  = bv;
    int   i0 = bi;
#pragma unroll
    for (int m = 1; m < 64; m <<= 1) {
      const float ov = __shfl_xor(v, m, 64);
      const int   oi = __shfl_xor(i0, m, 64);
      if (ov > v || (ov == v && oi < i0)) { v = ov; i0 = oi; }
    }
    if (i0 == bi) {  // unique owner lane of this wave's winner
      sv[wave] = bv; si[wave] = bi; sx[wave] = bx; sy[wave] = by; sz[wave] = bz;
    }
    __syncthreads();
    if (tid < 64) {
      const float lv = (lane < 16) ? sv[lane] : NEG_INF;
      const int   li = (lane < 16) ? si[lane] : 0x7fffffff;
      float v2 = lv;
      int   i2 = li;
#pragma unroll
      for (int m = 1; m < 16; m <<= 1) {
        const float ov = __shfl_xor(v2, m, 64);
        const int   oi = __shfl_xor(i2, m, 64);
        if (ov > v2 || (ov == v2 && oi < i2)) { v2 = ov; i2 = oi; }
      }
      if (lane < 16 && li == i2) {  // unique global owner
        const float wx = sx[lane], wy = sy[lane], wz = sz[lane];
        bc[0] = wx; bc[1] = wy; bc[2] = wz;
        float* o = new_xyz + ((size_t)b * 512 + s) * 3;
        o[0] = wx; o[1] = wy; o[2] = wz;
      }
    }
    __syncthreads();
    fx = bc[0]; fy = bc[1]; fz = bc[2];
  }
}

// =====================================================================
// FPS small (SA2: 512 -> 128), one block per batch, all state in regs.
// =====================================================================
template <int N, int NP, int THREADS, int NPT>
__global__ __launch_bounds__(THREADS)
void fps2_kernel(const float* __restrict__ xyz, float* __restrict__ new_xyz) {
  constexpr int NW = THREADS / 64;
  const int b    = blockIdx.x;
  const int tid  = threadIdx.x;
  const int lane = tid & 63;
  const int wave = tid >> 6;
  const float* p = xyz + (size_t)b * N * 3;
  float px[NPT], py[NPT], pz[NPT], dd[NPT];
#pragma unroll
  for (int j = 0; j < NPT; ++j) {
    const int i = tid + j * THREADS;
    if (i < N) {
      px[j] = p[i * 3 + 0];
      py[j] = p[i * 3 + 1];
      pz[j] = p[i * 3 + 2];
      dd[j] = 1e10f;
    } else {
      px[j] = 0.f; py[j] = 0.f; pz[j] = 0.f;
      dd[j] = NEG_INF;
    }
  }
  __shared__ float sv[NW], sx[NW], sy[NW], sz[NW];
  __shared__ int   si[NW];
  __shared__ float bc[3];
  float fx = p[0], fy = p[1], fz = p[2];
  if (tid == 0) {
    float* o = new_xyz + (size_t)b * NP * 3;
    o[0] = fx; o[1] = fy; o[2] = fz;
  }
  for (int s = 1; s < NP; ++s) {
    float bv = NEG_INF;
    int   bi = 0x7fffffff;
    float bx = 0.f, by = 0.f, bz = 0.f;
#pragma unroll
    for (int j = 0; j < NPT; ++j) {
      const float dx = px[j] - fx;
      const float dy = py[j] - fy;
      const float dz = pz[j] - fz;
      const float d  = __fadd_rn(__fadd_rn(__fmul_rn(dx, dx), __fmul_rn(dy, dy)),
                                 __fmul_rn(dz, dz));
      const float nd = fminf(dd[j], d);
      dd[j] = nd;
      if (nd > bv) { bv = nd; bi = tid + j * THREADS; bx = px[j]; by = py[j]; bz = pz[j]; }
    }
    float v = bv;
    int   i0 = bi;
#pragma unroll
    for (int m = 1; m < 64; m <<= 1) {
      const float ov = __shfl_xor(v, m, 64);
      const int   oi = __shfl_xor(i0, m, 64);
      if (ov > v || (ov == v && oi < i0)) { v = ov; i0 = oi; }
    }
    if (i0 == bi) {
      sv[wave] = bv; si[wave] = bi; sx[wave] = bx; sy[wave] = by; sz[wave] = bz;
    }
    __syncthreads();
    if (tid < 64) {
      const float lv = (lane < NW) ? sv[lane] : NEG_INF;
      const int   li = (lane < NW) ? si[lane] : 0x7fffffff;
      float v2 = lv;
      int   i2 = li;
#pragma unroll
      for (int m = 1; m < NW; m <<= 1) {
        const float ov = __shfl_xor(v2, m, 64);
        const int   oi = __shfl_xor(i2, m, 64);
        if (ov > v2 || (ov == v2 && oi < i2)) { v2 = ov; i2 = oi; }
      }
      if (lane < NW && li == i2) {
        const float wx = sx[lane], wy = sy[lane], wz = sz[lane];
        bc[0] = wx; bc[1] = wy; bc[2] = wz;
        float* o = new_xyz + ((size_t)b * NP + s) * 3;
        o[0] = wx; o[1] = wy; o[2] = wz;
      }
    }
    __syncthreads();
    fx = bc[0]; fy = bc[1]; fz = bc[2];
  }
}

// =====================================================================
// Ball query: ONE WAVE PER CENTER, ballot + prefix-popcount (R11,
// validated). Emits the first NS qualifying indices in ascending order.
// =====================================================================
template <int N, int NS>
__global__ __launch_bounds__(256)
void ballquery_wave_kernel(const float* __restrict__ centers,
                           const float* __restrict__ pts,
                           int* __restrict__ idx, int BS, int S, float r2) {
  const int w    = (blockIdx.x * 256 + threadIdx.x) >> 6;  // global wave id
  const int lane = threadIdx.x & 63;
  if (w >= BS) return;
  const int b = w / S;
  const float cx = centers[w * 3 + 0];
  const float cy = centers[w * 3 + 1];
  const float cz = centers[w * 3 + 2];
  const float* p = pts + (size_t)b * N * 3;
  int* o = idx + (size_t)w * NS;
  int total = 0;
  int first = -1;
  for (int i0 = 0; i0 < N && total < NS; i0 += 64) {
    const int i = i0 + lane;
    bool pred = false;
    if (i < N) {
      const float dx = cx - p[i * 3 + 0];
      const float dy = cy - p[i * 3 + 1];
      const float dz = cz - p[i * 3 + 2];
      const float d2 = __fadd_rn(__fadd_rn(__fmul_rn(dx, dx), __fmul_rn(dy, dy)),
                                 __fmul_rn(dz, dz));
      pred = (d2 < r2);
    }
    const unsigned long long mask = __ballot(pred);
    if (mask) {
      const unsigned long long below = (lane == 0) ? 0ull : (mask << (64 - lane));
      const int before = __popcll(below);
      if (pred && (total + before) < NS) o[total + before] = i;
      if (first < 0) first = i0 + (__ffsll((long long)mask) - 1);  // wave-uniform
      total += __popcll(mask);
    }
  }
  if (lane >= total && lane < NS) o[lane] = first;
}

// =====================================================================
// Grouping / concat kernels
// =====================================================================
__global__ void group1_kernel(const float* __restrict__ xyz, const float* __restrict__ ctr,
                              const int* __restrict__ idx, float* __restrict__ X1) {
  const int t = blockIdx.x * 256 + threadIdx.x;
  if (t >= 8 * 512 * 32) return;
  const int g = t >> 5;
  const int b = g >> 9;
  const int i = idx[t];
  const float* p = xyz + ((size_t)b * 20000 + i) * 3;
  const float* c = ctr + (size_t)g * 3;
  X1[t * 3 + 0] = (p[0] - c[0]) / 0.2f;
  X1[t * 3 + 1] = (p[1] - c[1]) / 0.2f;
  X1[t * 3 + 2] = (p[2] - c[2]) / 0.2f;
}

__global__ void group2_kernel(const float* __restrict__ xyz1,
                              const float* __restrict__ xyz2,
                              const float* __restrict__ f1,
                              const int* __restrict__ idx2,
                              float* __restrict__ X2) {
  const int t = blockIdx.x * 256 + threadIdx.x;
  if (t >= 65536 * 131) return;
  const int r = t / 131;
  const int c = t - r * 131;
  const int g = r >> 6;
  const int b = g >> 7;
  const int i = idx2[r];
  float v;
  if (c < 3) {
    v = (xyz1[((size_t)b * 512 + i) * 3 + c] - xyz2[(size_t)g * 3 + c]) / 0.4f;
  } else {
    v = f1[((size_t)b * 512 + i) * 128 + (c - 3)];
  }
  X2[t] = v;
}

__global__ void build_x3_kernel(const float* __restrict__ xyz2, const float* __restrict__ f2,
                                float* __restrict__ X3) {
  const int t = blockIdx.x * 256 + threadIdx.x;
  if (t >= 1024 * 259) return;
  const int r = t / 259;
  const int c = t - r * 259;
  X3[t] = (c < 3) ? xyz2[r * 3 + c] : f2[(size_t)r * 256 + (c - 3)];
}

// =====================================================================
// Fused head — float4 weight + LDS reads (R11, validated)
// =====================================================================
__global__ __launch_bounds__(512) void head_kernel(
    const float* __restrict__ gfeat, const float* __restrict__ objf,
    const float* __restrict__ w0, const float* __restrict__ b0,
    const float* __restrict__ w1, const float* __restrict__ b1,
    const float* __restrict__ w2, const float* __restrict__ b2,
    float* __restrict__ out) {
  __shared__ __align__(16) float comb[8 * 1152];
  __shared__ __align__(16) float h1[8 * 512];
  __shared__ __align__(16) float h2[8 * 256];
  const int tid = threadIdx.x;
  for (int i = tid; i < 8 * 1152; i += 512) {
    const int b = i / 1152, c = i - b * 1152;
    comb[i] = (c < 128) ? gfeat[b * 128 + c] : objf[b * 1024 + (c - 128)];
  }
  __syncthreads();
  for (int c = tid; c < 1152; c += 512) {
    float s = 0.f;
#pragma unroll
    for (int b = 0; b < 8; ++b) s += comb[b * 1152 + c];
    const float m = s * 0.125f;
    float v = 0.f;
#pragma unroll
    for (int b = 0; b < 8; ++b) { const float d = comb[b * 1152 + c] - m; v = fmaf(d, d, v); }
    const float sc = rsqrtf(v * 0.125f + EPS_BN);
#pragma unroll
    for (int b = 0; b < 8; ++b) comb[b * 1152 + c] = (comb[b * 1152 + c] - m) * sc;
  }
  __syncthreads();
  {  // layer 0: 1152 -> 512, float4 over k
    float a[8];
#pragma unroll
    for (int b = 0; b < 8; ++b) a[b] = b0[tid];
    const float* wr = w0 + (size_t)tid * 1152;
    for (int ci = 0; ci < 1152; ci += 4) {
      const float4 wv = *(const float4*)(wr + ci);
#pragma unroll
      for (int b = 0; b < 8; ++b) {
        const float4 xv = *(const float4*)(&comb[b * 1152 + ci]);
        a[b] = fmaf(xv.x, wv.x, a[b]);
        a[b] = fmaf(xv.y, wv.y, a[b]);
        a[b] = fmaf(xv.z, wv.z, a[b]);
        a[b] = fmaf(xv.w, wv.w, a[b]);
      }
    }
    float s = 0.f;
#pragma unroll
    for (int b = 0; b < 8; ++b) s += a[b];
    const float m = s * 0.125f;
    float v = 0.f;
#pragma unroll
    for (int b = 0; b < 8; ++b) { const float d = a[b] - m; v = fmaf(d, d, v); }
    const float sc = rsqrtf(v * 0.125f + EPS_BN);
#pragma unroll
    for (int b = 0; b < 8; ++b) h1[b * 512 + tid] = fmaxf(0.f, (a[b] - m) * sc);
  }
  __syncthreads();
  if (tid < 256) {  // layer 1: 512 -> 256, float4 over k
    float a[8];
#pragma unroll
    for (int b = 0; b < 8; ++b) a[b] = b1[tid];
    const float* wr = w1 + (size_t)tid * 512;
    for (int ci = 0; ci < 512; ci += 4) {
      const float4 wv = *(const float4*)(wr + ci);
#pragma unroll
      for (int b = 0; b < 8; ++b) {
        const float4 xv = *(const float4*)(&h1[b * 512 + ci]);
        a[b] = fmaf(xv.x, wv.x, a[b]);
        a[b] = fmaf(xv.y, wv.y, a[b]);
        a[b] = fmaf(xv.z, wv.z, a[b]);
        a[b] = fmaf(xv.w, wv.w, a[b]);
      }
    }
    float s = 0.f;
#pragma unroll
    for (int b = 0; b < 8; ++b) s += a[b];
    const float m = s * 0.125f;
    float v = 0.f;
#pragma unroll
    for (int b = 0; b < 8; ++b) { const float d = a[b] - m; v = fmaf(d, d, v); }
    const float sc = rsqrtf(v * 0.125f + EPS_BN);
#pragma unroll
    for (int b = 0; b < 8; ++b) h2[b * 256 + tid] = fmaxf(0.f, (a[b] - m) * sc);
  }
  __syncthreads();
  if (tid < 8) {  // layer 2: 256 -> 1, relu
    float s = b2[0];
    for (int ci = 0; ci < 256; ++ci) s = fmaf(h2[tid * 256 + ci], w2[ci], s);
    out[tid] = fmaxf(0.f, s);
  }
}

// =====================================================================
// Host orchestration
// =====================================================================
extern "C" void kernel_launch(void* const* d_in, const int* in_sizes, int n_in,
                              void* d_out, int out_size, void* d_ws, size_t ws_size,
                              hipStream_t stream) {
  (void)in_sizes; (void)n_in; (void)out_size; (void)ws_size;
  const float* obj  = (const float*)d_in[0];
  const float* grip = (const float*)d_in[1];
  const float* s1w0 = (const float*)d_in[2];
  const float* s1w1 = (const float*)d_in[3];
  const float* s1w2 = (const float*)d_in[4];
  const float* s2w0 = (const float*)d_in[5];
  const float* s2w1 = (const float*)d_in[6];
  const float* s2w2 = (const float*)d_in[7];
  const float* s3w0 = (const float*)d_in[8];
  const float* s3w1 = (const float*)d_in[9];
  const float* s3w2 = (const float*)d_in[10];
  const float* gw0  = (const float*)d_in[11];
  const float* gw1  = (const float*)d_in[12];
  const float* gw2  = (const float*)d_in[13];
  const float* hw0  = (const float*)d_in[14];
  const float* hb0  = (const float*)d_in[15];
  const float* hw1  = (const float*)d_in[16];
  const float* hb1  = (const float*)d_in[17];
  const float* hw2  = (const float*)d_in[18];
  const float* hb2  = (const float*)d_in[19];
  float* out = (float*)d_out;

  // ---- workspace layout (float offsets); total 26,658,304 floats ----
  float* wsf   = (float*)d_ws;
  float* stats = wsf;
  float* xyz1  = wsf + 23040;
  float* xyz2  = wsf + 35328;
  float* gfeat = wsf + 38400;
  float* objf  = wsf + 39424;
  float* f1    = wsf + 47616;
  float* f2    = wsf + 571904;
  float* x3    = wsf + 834048;
  int*   idx1  = (int*)(wsf + 1099264);
  int*   idx2  = (int*)(wsf + 1230336);
  float* bufP  = wsf + 1295872;
  float* bufQ  = wsf + 18073088;

  static const int st_off[12] = {0, 512, 1536, 2560, 3072, 3584,
                                 4608, 5632, 6656, 8704, 10752, 14848};
  auto st = [&](int li) { return stats + st_off[li]; };

  hipMemsetAsync(stats, 0, 23040 * sizeof(float), stream);

  auto gemm0 = [&](const float* X, const float* Wm, float* Y, int R, int Cin, int Cout,
                   int lo) {
    dim3 g((R + 127) / 128, (Cout + 127) / 128);
    gemm_xwt<false, false><<<g, 256, 0, stream>>>(X, Wm, Y, R, Cin, Cout, nullptr, 0,
                                                  st(lo), nullptr, 0);
  };
  auto gemmf = [&](const float* X, const float* Wm, float* Y, int R, int Cin, int Cout,
                   int li, int lo) {
    dim3 g((R + 127) / 128, (Cout + 127) / 128);
    gemm_xwt<true, false><<<g, 256, 0, stream>>>(X, Wm, Y, R, Cin, Cout, st(li), R,
                                                 st(lo), nullptr, 0);
  };
  auto gemmfM = [&](const float* X, const float* Wm, float* pooled, int R, int Cin,
                    int Cout, int li, int lo, int ns) {
    dim3 g((R + 127) / 128, (Cout + 127) / 128);
    gemm_xwt<true, true><<<g, 256, 0, stream>>>(X, Wm, nullptr, R, Cin, Cout, st(li), R,
                                                st(lo), pooled, ns);
  };
  auto applymax_k = [&](const float* Y, int li, int G, int ns, int C, float* o) {
    const int n = G * C;
    bn_apply_relu_maxpool<<<(n + 255) / 256, 256, 0, stream>>>(Y, st(li), o, G, ns, C);
  };
  auto applypool_k = [&](const float* P, int li, int G, int C, int Rtrue, float* o) {
    const int n = G * C;
    bn_apply_pooled<<<(n + 255) / 256, 256, 0, stream>>>(P, st(li), o, G, C, Rtrue);
  };

  // ---- SA1 FPS (R18: R5 structure, all-register scan) ----
  fps_sa1_kernel<<<8, 1024, 0, stream>>>(obj, xyz1);

  // ---- gripper encoder: [8,512,3] -> 64 -> 128 -> 128 -> maxpool (ns=512 path) ----
  float* gY1 = bufP;
  float* gY2 = bufP + 262144;
  float* gY3 = bufP + 786432;
  gemm0(grip, gw0, gY1, 4096, 3, 64, 0);
  gemmf(gY1, gw1, gY2, 4096, 64, 128, 0, 1);
  gemmf(gY2, gw2, gY3, 4096, 128, 128, 1, 2);
  applymax_k(gY3, 2, 8, 512, 128, gfeat);

  // ---- SA1: ball r=0.2 ns=32 (wave-per-center), MLP 3->64->64->128 ----
  ballquery_wave_kernel<20000, 32><<<1024, 256, 0, stream>>>(xyz1, obj, idx1, 4096, 512, 0.04f);
  float* X1 = bufQ;
  group1_kernel<<<512, 256, 0, stream>>>(obj, xyz1, idx1, X1);
  gemm0(X1, s1w0, bufP, 131072, 3, 64, 3);
  gemmf(bufP, s1w1, bufQ, 131072, 64, 64, 3, 4);
  gemmfM(bufQ, s1w2, bufP, 131072, 64, 128, 4, 5, 32);   // pooled: 4096x128
  applypool_k(bufP, 5, 4096, 128, 131072, f1);

  // ---- SA2: FPS 512->128, ball r=0.4 ns=64, MLP 131->128->128->256 ----
  fps2_kernel<512, 128, 256, 2><<<8, 256, 0, stream>>>(xyz1, xyz2);
  ballquery_wave_kernel<512, 64><<<256, 256, 0, stream>>>(xyz2, xyz1, idx2, 1024, 128, 0.16f);
  float* X2 = bufQ;
  group2_kernel<<<(65536 * 131 + 255) / 256, 256, 0, stream>>>(xyz1, xyz2, f1, idx2, X2);
  gemm0(X2, s2w0, bufP, 65536, 131, 128, 6);
  gemmf(bufP, s2w1, bufQ, 65536, 128, 128, 6, 7);
  gemmfM(bufQ, s2w2, bufP, 65536, 128, 256, 7, 8, 64);   // pooled: 1024x256
  applypool_k(bufP, 8, 1024, 256, 65536, f2);

  // ---- SA3 (group_all): concat[xyz2,f2] -> 256 -> 512 -> 1024 -> maxpool ----
  build_x3_kernel<<<(1024 * 259 + 255) / 256, 256, 0, stream>>>(xyz2, f2, x3);
  float* Y3a = bufQ;
  float* Y3b = bufQ + 262144;
  float* Y3p = bufQ + 786432;
  gemm0(x3, s3w0, Y3a, 1024, 259, 256, 9);
  gemmf(Y3a, s3w1, Y3b, 1024, 256, 512, 9, 10);
  gemmfM(Y3b, s3w2, Y3p, 1024, 512, 1024, 10, 11, 128);  // pooled: 8x1024
  applypool_k(Y3p, 11, 8, 1024, 1024, objf);

  // ---- head ----
  head_kernel<<<1, 512, 0, stream>>>(gfeat, objf, hw0, hb0, hw1, hb1, hw2, hb2, out);
}

// Round 6
// 3031.044 us; speedup vs baseline: 1.0033x; 1.0033x over previous
//
#include <hip/hip_runtime.h>
#include <cstddef>
#include <cstdint>

#define EPS_BN 1e-5f
#define NBINS 4
#define NEG_INF (-__builtin_inff())

// =====================================================================
// Tiled fp32 GEMM:  Y[r][o] = sum_ci X'[r][ci] * W[o][ci]   (Y = X' W^T)
// 128x128 tile, BK=16, 256 threads, 8x8 microtile/thread (split
// quadrants, <=2-way LDS reads). R multiple of 128; Cout guarded.
// FUSE_IN:  X' = relu((X - mean)*scale) from st_in bins (prev layer BN).
// FUSE_MAX: instead of storing Y, store per-(ns-group, col) max of raw Y
//           into pooled[G][Cout]. Valid because ns | 128 (each tile has
//           only complete groups) and grid.y column ranges are disjoint
//           -> exactly one block writes each pooled element, no atomics.
//           BN+relu applied later on the pooled value (monotone => same
//           result as reference, exact fmaxf).
// Epilogue always: per-column sum/sumsq of raw Y into st_out bins.
// =====================================================================
template <bool FUSE_IN, bool FUSE_MAX>
__global__ __launch_bounds__(256) void gemm_xwt(const float* __restrict__ X,
                                                const float* __restrict__ Wm,
                                                float* __restrict__ Y,
                                                int R, int Cin, int Cout,
                                                const float* __restrict__ st_in, int Rin,
                                                float* __restrict__ st_out,
                                                float* __restrict__ pooled, int ns) {
  __shared__ __align__(16) float Xs[16][132];
  __shared__ __align__(16) float Ws[16][132];
  __shared__ float sMean[512], sScale[512];
  const int t  = threadIdx.x;
  const int r0 = blockIdx.x << 7;
  const int n0 = blockIdx.y << 7;
  const int tx = t & 15;
  const int ty = t >> 4;

  if constexpr (FUSE_IN) {
    const float inv = 1.f / (float)Rin;
    for (int k = t; k < Cin; k += 256) {
      float s = 0.f, q = 0.f;
#pragma unroll
      for (int bn = 0; bn < NBINS; ++bn) {
        s += st_in[bn * 2 * Cin + k];
        q += st_in[bn * 2 * Cin + Cin + k];
      }
      const float m  = s * inv;
      const float vr = fmaf(-m, m, q * inv);
      sMean[k]  = m;
      sScale[k] = rsqrtf(vr + EPS_BN);
    }
    __syncthreads();
  }

  float acc[8][8] = {};
  const int rStage = t >> 1;
  const int kBase  = (t & 1) << 3;
  const int nr     = n0 + rStage;

  for (int k0 = 0; k0 < Cin; k0 += 16) {
    const float* xrow = X  + (size_t)(r0 + rStage) * Cin + k0 + kBase;
    const float* wrow = Wm + (size_t)nr * Cin + k0 + kBase;
    if (((Cin & 3) == 0) && (k0 + 16 <= Cin)) {
      float4 xa = *(const float4*)(xrow);
      float4 xb = *(const float4*)(xrow + 4);
      if constexpr (FUSE_IN) {
        const int kb = k0 + kBase;
        xa.x = fmaxf(0.f, (xa.x - sMean[kb + 0]) * sScale[kb + 0]);
        xa.y = fmaxf(0.f, (xa.y - sMean[kb + 1]) * sScale[kb + 1]);
        xa.z = fmaxf(0.f, (xa.z - sMean[kb + 2]) * sScale[kb + 2]);
        xa.w = fmaxf(0.f, (xa.w - sMean[kb + 3]) * sScale[kb + 3]);
        xb.x = fmaxf(0.f, (xb.x - sMean[kb + 4]) * sScale[kb + 4]);
        xb.y = fmaxf(0.f, (xb.y - sMean[kb + 5]) * sScale[kb + 5]);
        xb.z = fmaxf(0.f, (xb.z - sMean[kb + 6]) * sScale[kb + 6]);
        xb.w = fmaxf(0.f, (xb.w - sMean[kb + 7]) * sScale[kb + 7]);
      }
      Xs[kBase + 0][rStage] = xa.x; Xs[kBase + 1][rStage] = xa.y;
      Xs[kBase + 2][rStage] = xa.z; Xs[kBase + 3][rStage] = xa.w;
      Xs[kBase + 4][rStage] = xb.x; Xs[kBase + 5][rStage] = xb.y;
      Xs[kBase + 6][rStage] = xb.z; Xs[kBase + 7][rStage] = xb.w;
      float4 wa = {0, 0, 0, 0}, wb = {0, 0, 0, 0};
      if (nr < Cout) { wa = *(const float4*)(wrow); wb = *(const float4*)(wrow + 4); }
      Ws[kBase + 0][rStage] = wa.x; Ws[kBase + 1][rStage] = wa.y;
      Ws[kBase + 2][rStage] = wa.z; Ws[kBase + 3][rStage] = wa.w;
      Ws[kBase + 4][rStage] = wb.x; Ws[kBase + 5][rStage] = wb.y;
      Ws[kBase + 6][rStage] = wb.z; Ws[kBase + 7][rStage] = wb.w;
    } else {
#pragma unroll
      for (int u = 0; u < 8; ++u) {
        const int k = k0 + kBase + u;
        float xe = 0.f, we = 0.f;
        if (k < Cin) {
          xe = xrow[u];
          if constexpr (FUSE_IN) xe = fmaxf(0.f, (xe - sMean[k]) * sScale[k]);
          if (nr < Cout) we = wrow[u];
        }
        Xs[kBase + u][rStage] = xe;
        Ws[kBase + u][rStage] = we;
      }
    }
    __syncthreads();
#pragma unroll
    for (int kk = 0; kk < 16; ++kk) {
      const float4 a0 = *(const float4*)(&Xs[kk][ty << 2]);
      const float4 a1 = *(const float4*)(&Xs[kk][64 + (ty << 2)]);
      const float4 b0 = *(const float4*)(&Ws[kk][tx << 2]);
      const float4 b1 = *(const float4*)(&Ws[kk][64 + (tx << 2)]);
      const float av[8] = {a0.x, a0.y, a0.z, a0.w, a1.x, a1.y, a1.z, a1.w};
      const float bw[8] = {b0.x, b0.y, b0.z, b0.w, b1.x, b1.y, b1.z, b1.w};
#pragma unroll
      for (int i = 0; i < 8; ++i)
#pragma unroll
        for (int j = 0; j < 8; ++j) acc[i][j] = fmaf(av[i], bw[j], acc[i][j]);
    }
    __syncthreads();
  }
  if constexpr (!FUSE_MAX) {
#pragma unroll
    for (int h = 0; h < 2; ++h)
#pragma unroll
      for (int i = 0; i < 4; ++i) {
        const int r = r0 + h * 64 + (ty << 2) + i;
        float* yr = Y + (size_t)r * Cout;
#pragma unroll
        for (int g = 0; g < 2; ++g) {
          const int n = n0 + g * 64 + (tx << 2);
          if (n < Cout) {
            float4 o = {acc[h * 4 + i][g * 4 + 0], acc[h * 4 + i][g * 4 + 1],
                        acc[h * 4 + i][g * 4 + 2], acc[h * 4 + i][g * 4 + 3]};
            *(float4*)(yr + n) = o;
          }
        }
      }
  }
  // stats epilogue: per-column partials -> LDS reduce -> binned atomics
#pragma unroll
  for (int g = 0; g < 2; ++g)
#pragma unroll
    for (int j = 0; j < 4; ++j) {
      float s = 0.f, q = 0.f;
#pragma unroll
      for (int rh = 0; rh < 8; ++rh) {
        const float v = acc[rh][g * 4 + j];
        s += v;
        q = fmaf(v, v, q);
      }
      Xs[ty][g * 64 + (tx << 2) + j] = s;
      Ws[ty][g * 64 + (tx << 2) + j] = q;
    }
  __syncthreads();
  if (t < 128) {
    const int n = n0 + t;
    if (n < Cout) {
      float s = 0.f, q = 0.f;
#pragma unroll
      for (int w = 0; w < 16; ++w) { s += Xs[w][t]; q += Ws[w][t]; }
      float* dst = st_out + (blockIdx.x & (NBINS - 1)) * 2 * Cout;
      atomicAdd(dst + n, s);
      atomicAdd(dst + Cout + n, q);
    }
  }
  // maxpool epilogue: ns in {32, 64, 128}
  if constexpr (FUSE_MAX) {
    __syncthreads();  // stats reduce done reading Xs/Ws
    float mxAll = NEG_INF;  // used only for ns==128 path (t<128)
#pragma unroll
    for (int h = 0; h < 2; ++h) {
      // thread's per-col max over its 4 rows in this half
#pragma unroll
      for (int g2 = 0; g2 < 2; ++g2)
#pragma unroll
        for (int j = 0; j < 4; ++j) {
          float mx = acc[h * 4 + 0][g2 * 4 + j];
          mx = fmaxf(mx, acc[h * 4 + 1][g2 * 4 + j]);
          mx = fmaxf(mx, acc[h * 4 + 2][g2 * 4 + j]);
          mx = fmaxf(mx, acc[h * 4 + 3][g2 * 4 + j]);
          Xs[ty][g2 * 64 + (tx << 2) + j] = mx;
        }
      __syncthreads();
      if (t < 128) {
        const int n = n0 + t;
        if (n < Cout) {
          if (ns <= 64) {
            const int tpg = ns >> 2;        // ty's per group
            const int gph = 64 / ns;        // groups per 64-row half
            for (int gq = 0; gq < gph; ++gq) {
              float mx = NEG_INF;
              for (int w = gq * tpg; w < gq * tpg + tpg; ++w) mx = fmaxf(mx, Xs[w][t]);
              const int g = (r0 + h * 64) / ns + gq;
              pooled[(size_t)g * Cout + n] = mx;
            }
          } else {  // ns == 128: single group spans both halves
            float mx = NEG_INF;
            for (int w = 0; w < 16; ++w) mx = fmaxf(mx, Xs[w][t]);
            mxAll = fmaxf(mxAll, mx);
          }
        }
      }
      __syncthreads();
    }
    if (ns > 64 && t < 128) {
      const int n = n0 + t;
      if (n < Cout) pooled[(size_t)(r0 >> 7) * Cout + n] = mxAll;
    }
  }
}

// BN apply on an already-pooled G x C buffer (Rtrue = rows of the raw Y)
__global__ void bn_apply_pooled(const float* __restrict__ P, const float* __restrict__ st,
                                float* __restrict__ o, int G, int C, int Rtrue) {
  const int i = blockIdx.x * 256 + threadIdx.x;
  if (i >= G * C) return;
  const int c = i % C;
  float s = 0.f, q = 0.f;
#pragma unroll
  for (int bn = 0; bn < NBINS; ++bn) {
    s += st[bn * 2 * C + c];
    q += st[bn * 2 * C + C + c];
  }
  const float inv = 1.f / (float)Rtrue;
  const float m  = s * inv;
  const float vr = fmaf(-m, m, q * inv);
  const float sc = rsqrtf(vr + EPS_BN);
  o[i] = fmaxf(0.f, (P[i] - m) * sc);
}

// normalize -> relu -> max over ns rows per group (gripper path, ns=512)
__global__ void bn_apply_relu_maxpool(const float* __restrict__ Y,
                                      const float* __restrict__ st,
                                      float* __restrict__ o, int G, int ns, int C) {
  const int i = blockIdx.x * 256 + threadIdx.x;
  if (i >= G * C) return;
  const int c = i % C;
  const int g = i / C;
  float s = 0.f, q = 0.f;
#pragma unroll
  for (int bn = 0; bn < NBINS; ++bn) {
    s += st[bn * 2 * C + c];
    q += st[bn * 2 * C + C + c];
  }
  const int R = G * ns;
  const float inv = 1.f / (float)R;
  const float m  = s * inv;
  const float vr = fmaf(-m, m, q * inv);
  const float sc = rsqrtf(vr + EPS_BN);
  const float* p = Y + (size_t)g * ns * C + c;
  float mx = NEG_INF;
  for (int k = 0; k < ns; ++k) mx = fmaxf(mx, p[(size_t)k * C]);
  o[i] = fmaxf(0.f, (mx - m) * sc);
}

// =====================================================================
// FPS for SA1 (N=20000 -> 512) — R19: R18's all-register scan (R5 step
// structure, all 20 point-groups in VGPRs) with the REGISTER BUDGET
// actually granted: __launch_bounds__(1024, 4). R18 measured VGPR=64 +
// WRITE_SIZE 48->1136 KB = the compiler spilled the 80-reg arrays to
// scratch (default launch_bounds occupancy target caps at 64 VGPR).
// A 1024-thread block is 16 waves/CU = 4 waves/SIMD; declaring min 4
// waves/EU raises the allocator cap to 128 VGPR (occupancy steps at
// 64/128/256), which fits the ~110-VGPR scan with zero spill. Grid is
// 8 blocks / 8 CUs -> no occupancy actually lost.
// Selection semantics bit-identical to R5 (absmax 0.0): same ascending
// group order with identical index formula tid + k*1024, same
// __fmul_rn/__fadd_rn/fminf chain, same strict-> update, same two-barrier
// owner-detect reduce verbatim.
// =====================================================================
#define FPS_NG 20

__global__ __launch_bounds__(1024, 4)
void fps_sa1_kernel(const float* __restrict__ xyz, float* __restrict__ new_xyz) {
  const int b    = blockIdx.x;
  const int tid  = threadIdx.x;
  const int lane = tid & 63;
  const int wave = tid >> 6;  // 0..15
  const float* p = xyz + (size_t)b * 20000 * 3;

  __shared__ float sv[16], sx[16], sy[16], sz[16];
  __shared__ int   si[16];
  __shared__ float bc[3];

  float px[FPS_NG], py[FPS_NG], pz[FPS_NG], dd[FPS_NG];
#pragma unroll
  for (int k = 0; k < FPS_NG; ++k) {
    const int i = tid + (k << 10);
    if (i < 20000) {
      px[k] = p[i * 3 + 0]; py[k] = p[i * 3 + 1]; pz[k] = p[i * 3 + 2];
      dd[k] = 1e10f;
    } else {
      px[k] = 0.f; py[k] = 0.f; pz[k] = 0.f;
      dd[k] = NEG_INF;
    }
  }

  float fx = p[0], fy = p[1], fz = p[2];
  if (tid == 0) {
    float* o = new_xyz + (size_t)b * 512 * 3;
    o[0] = fx; o[1] = fy; o[2] = fz;
  }
  __syncthreads();

  for (int s = 1; s < 512; ++s) {
    float bv = NEG_INF;
    int   bi = 0x7fffffff;
    float bx = 0.f, by = 0.f, bz = 0.f;
#pragma unroll
    for (int k = 0; k < FPS_NG; ++k) {
      const float dx = px[k] - fx, dy = py[k] - fy, dz = pz[k] - fz;
      const float d  = __fadd_rn(__fadd_rn(__fmul_rn(dx, dx), __fmul_rn(dy, dy)),
                                 __fmul_rn(dz, dz));
      const float nd = fminf(dd[k], d);
      dd[k] = nd;
      if (nd > bv) { bv = nd; bi = tid + (k << 10); bx = px[k]; by = py[k]; bz = pz[k]; }
    }
    float v  = bv;
    int   i0 = bi;
#pragma unroll
    for (int m = 1; m < 64; m <<= 1) {
      const float ov = __shfl_xor(v, m, 64);
      const int   oi = __shfl_xor(i0, m, 64);
      if (ov > v || (ov == v && oi < i0)) { v = ov; i0 = oi; }
    }
    if (i0 == bi) {  // unique owner lane of this wave's winner
      sv[wave] = bv; si[wave] = bi; sx[wave] = bx; sy[wave] = by; sz[wave] = bz;
    }
    __syncthreads();
    if (tid < 64) {
      const float lv = (lane < 16) ? sv[lane] : NEG_INF;
      const int   li = (lane < 16) ? si[lane] : 0x7fffffff;
      float v2 = lv;
      int   i2 = li;
#pragma unroll
      for (int m = 1; m < 16; m <<= 1) {
        const float ov = __shfl_xor(v2, m, 64);
        const int   oi = __shfl_xor(i2, m, 64);
        if (ov > v2 || (ov == v2 && oi < i2)) { v2 = ov; i2 = oi; }
      }
      if (lane < 16 && li == i2) {  // unique global owner
        const float wx = sx[lane], wy = sy[lane], wz = sz[lane];
        bc[0] = wx; bc[1] = wy; bc[2] = wz;
        float* o = new_xyz + ((size_t)b * 512 + s) * 3;
        o[0] = wx; o[1] = wy; o[2] = wz;
      }
    }
    __syncthreads();
    fx = bc[0]; fy = bc[1]; fz = bc[2];
  }
}

// =====================================================================
// FPS small (SA2: 512 -> 128), one block per batch, all state in regs.
// =====================================================================
template <int N, int NP, int THREADS, int NPT>
__global__ __launch_bounds__(THREADS)
void fps2_kernel(const float* __restrict__ xyz, float* __restrict__ new_xyz) {
  constexpr int NW = THREADS / 64;
  const int b    = blockIdx.x;
  const int tid  = threadIdx.x;
  const int lane = tid & 63;
  const int wave = tid >> 6;
  const float* p = xyz + (size_t)b * N * 3;
  float px[NPT], py[NPT], pz[NPT], dd[NPT];
#pragma unroll
  for (int j = 0; j < NPT; ++j) {
    const int i = tid + j * THREADS;
    if (i < N) {
      px[j] = p[i * 3 + 0];
      py[j] = p[i * 3 + 1];
      pz[j] = p[i * 3 + 2];
      dd[j] = 1e10f;
    } else {
      px[j] = 0.f; py[j] = 0.f; pz[j] = 0.f;
      dd[j] = NEG_INF;
    }
  }
  __shared__ float sv[NW], sx[NW], sy[NW], sz[NW];
  __shared__ int   si[NW];
  __shared__ float bc[3];
  float fx = p[0], fy = p[1], fz = p[2];
  if (tid == 0) {
    float* o = new_xyz + (size_t)b * NP * 3;
    o[0] = fx; o[1] = fy; o[2] = fz;
  }
  for (int s = 1; s < NP; ++s) {
    float bv = NEG_INF;
    int   bi = 0x7fffffff;
    float bx = 0.f, by = 0.f, bz = 0.f;
#pragma unroll
    for (int j = 0; j < NPT; ++j) {
      const float dx = px[j] - fx;
      const float dy = py[j] - fy;
      const float dz = pz[j] - fz;
      const float d  = __fadd_rn(__fadd_rn(__fmul_rn(dx, dx), __fmul_rn(dy, dy)),
                                 __fmul_rn(dz, dz));
      const float nd = fminf(dd[j], d);
      dd[j] = nd;
      if (nd > bv) { bv = nd; bi = tid + j * THREADS; bx = px[j]; by = py[j]; bz = pz[j]; }
    }
    float v = bv;
    int   i0 = bi;
#pragma unroll
    for (int m = 1; m < 64; m <<= 1) {
      const float ov = __shfl_xor(v, m, 64);
      const int   oi = __shfl_xor(i0, m, 64);
      if (ov > v || (ov == v && oi < i0)) { v = ov; i0 = oi; }
    }
    if (i0 == bi) {
      sv[wave] = bv; si[wave] = bi; sx[wave] = bx; sy[wave] = by; sz[wave] = bz;
    }
    __syncthreads();
    if (tid < 64) {
      const float lv = (lane < NW) ? sv[lane] : NEG_INF;
      const int   li = (lane < NW) ? si[lane] : 0x7fffffff;
      float v2 = lv;
      int   i2 = li;
#pragma unroll
      for (int m = 1; m < NW; m <<= 1) {
        const float ov = __shfl_xor(v2, m, 64);
        const int   oi = __shfl_xor(i2, m, 64);
        if (ov > v2 || (ov == v2 && oi < i2)) { v2 = ov; i2 = oi; }
      }
      if (lane < NW && li == i2) {
        const float wx = sx[lane], wy = sy[lane], wz = sz[lane];
        bc[0] = wx; bc[1] = wy; bc[2] = wz;
        float* o = new_xyz + ((size_t)b * NP + s) * 3;
        o[0] = wx; o[1] = wy; o[2] = wz;
      }
    }
    __syncthreads();
    fx = bc[0]; fy = bc[1]; fz = bc[2];
  }
}

// =====================================================================
// Ball query: ONE WAVE PER CENTER, ballot + prefix-popcount (R11,
// validated). Emits the first NS qualifying indices in ascending order.
// =====================================================================
template <int N, int NS>
__global__ __launch_bounds__(256)
void ballquery_wave_kernel(const float* __restrict__ centers,
                           const float* __restrict__ pts,
                           int* __restrict__ idx, int BS, int S, float r2) {
  const int w    = (blockIdx.x * 256 + threadIdx.x) >> 6;  // global wave id
  const int lane = threadIdx.x & 63;
  if (w >= BS) return;
  const int b = w / S;
  const float cx = centers[w * 3 + 0];
  const float cy = centers[w * 3 + 1];
  const float cz = centers[w * 3 + 2];
  const float* p = pts + (size_t)b * N * 3;
  int* o = idx + (size_t)w * NS;
  int total = 0;
  int first = -1;
  for (int i0 = 0; i0 < N && total < NS; i0 += 64) {
    const int i = i0 + lane;
    bool pred = false;
    if (i < N) {
      const float dx = cx - p[i * 3 + 0];
      const float dy = cy - p[i * 3 + 1];
      const float dz = cz - p[i * 3 + 2];
      const float d2 = __fadd_rn(__fadd_rn(__fmul_rn(dx, dx), __fmul_rn(dy, dy)),
                                 __fmul_rn(dz, dz));
      pred = (d2 < r2);
    }
    const unsigned long long mask = __ballot(pred);
    if (mask) {
      const unsigned long long below = (lane == 0) ? 0ull : (mask << (64 - lane));
      const int before = __popcll(below);
      if (pred && (total + before) < NS) o[total + before] = i;
      if (first < 0) first = i0 + (__ffsll((long long)mask) - 1);  // wave-uniform
      total += __popcll(mask);
    }
  }
  if (lane >= total && lane < NS) o[lane] = first;
}

// =====================================================================
// Grouping / concat kernels
// =====================================================================
__global__ void group1_kernel(const float* __restrict__ xyz, const float* __restrict__ ctr,
                              const int* __restrict__ idx, float* __restrict__ X1) {
  const int t = blockIdx.x * 256 + threadIdx.x;
  if (t >= 8 * 512 * 32) return;
  const int g = t >> 5;
  const int b = g >> 9;
  const int i = idx[t];
  const float* p = xyz + ((size_t)b * 20000 + i) * 3;
  const float* c = ctr + (size_t)g * 3;
  X1[t * 3 + 0] = (p[0] - c[0]) / 0.2f;
  X1[t * 3 + 1] = (p[1] - c[1]) / 0.2f;
  X1[t * 3 + 2] = (p[2] - c[2]) / 0.2f;
}

__global__ void group2_kernel(const float* __restrict__ xyz1,
                              const float* __restrict__ xyz2,
                              const float* __restrict__ f1,
                              const int* __restrict__ idx2,
                              float* __restrict__ X2) {
  const int t = blockIdx.x * 256 + threadIdx.x;
  if (t >= 65536 * 131) return;
  const int r = t / 131;
  const int c = t - r * 131;
  const int g = r >> 6;
  const int b = g >> 7;
  const int i = idx2[r];
  float v;
  if (c < 3) {
    v = (xyz1[((size_t)b * 512 + i) * 3 + c] - xyz2[(size_t)g * 3 + c]) / 0.4f;
  } else {
    v = f1[((size_t)b * 512 + i) * 128 + (c - 3)];
  }
  X2[t] = v;
}

__global__ void build_x3_kernel(const float* __restrict__ xyz2, const float* __restrict__ f2,
                                float* __restrict__ X3) {
  const int t = blockIdx.x * 256 + threadIdx.x;
  if (t >= 1024 * 259) return;
  const int r = t / 259;
  const int c = t - r * 259;
  X3[t] = (c < 3) ? xyz2[r * 3 + c] : f2[(size_t)r * 256 + (c - 3)];
}

// =====================================================================
// Fused head — float4 weight + LDS reads (R11, validated)
// =====================================================================
__global__ __launch_bounds__(512) void head_kernel(
    const float* __restrict__ gfeat, const float* __restrict__ objf,
    const float* __restrict__ w0, const float* __restrict__ b0,
    const float* __restrict__ w1, const float* __restrict__ b1,
    const float* __restrict__ w2, const float* __restrict__ b2,
    float* __restrict__ out) {
  __shared__ __align__(16) float comb[8 * 1152];
  __shared__ __align__(16) float h1[8 * 512];
  __shared__ __align__(16) float h2[8 * 256];
  const int tid = threadIdx.x;
  for (int i = tid; i < 8 * 1152; i += 512) {
    const int b = i / 1152, c = i - b * 1152;
    comb[i] = (c < 128) ? gfeat[b * 128 + c] : objf[b * 1024 + (c - 128)];
  }
  __syncthreads();
  for (int c = tid; c < 1152; c += 512) {
    float s = 0.f;
#pragma unroll
    for (int b = 0; b < 8; ++b) s += comb[b * 1152 + c];
    const float m = s * 0.125f;
    float v = 0.f;
#pragma unroll
    for (int b = 0; b < 8; ++b) { const float d = comb[b * 1152 + c] - m; v = fmaf(d, d, v); }
    const float sc = rsqrtf(v * 0.125f + EPS_BN);
#pragma unroll
    for (int b = 0; b < 8; ++b) comb[b * 1152 + c] = (comb[b * 1152 + c] - m) * sc;
  }
  __syncthreads();
  {  // layer 0: 1152 -> 512, float4 over k
    float a[8];
#pragma unroll
    for (int b = 0; b < 8; ++b) a[b] = b0[tid];
    const float* wr = w0 + (size_t)tid * 1152;
    for (int ci = 0; ci < 1152; ci += 4) {
      const float4 wv = *(const float4*)(wr + ci);
#pragma unroll
      for (int b = 0; b < 8; ++b) {
        const float4 xv = *(const float4*)(&comb[b * 1152 + ci]);
        a[b] = fmaf(xv.x, wv.x, a[b]);
        a[b] = fmaf(xv.y, wv.y, a[b]);
        a[b] = fmaf(xv.z, wv.z, a[b]);
        a[b] = fmaf(xv.w, wv.w, a[b]);
      }
    }
    float s = 0.f;
#pragma unroll
    for (int b = 0; b < 8; ++b) s += a[b];
    const float m = s * 0.125f;
    float v = 0.f;
#pragma unroll
    for (int b = 0; b < 8; ++b) { const float d = a[b] - m; v = fmaf(d, d, v); }
    const float sc = rsqrtf(v * 0.125f + EPS_BN);
#pragma unroll
    for (int b = 0; b < 8; ++b) h1[b * 512 + tid] = fmaxf(0.f, (a[b] - m) * sc);
  }
  __syncthreads();
  if (tid < 256) {  // layer 1: 512 -> 256, float4 over k
    float a[8];
#pragma unroll
    for (int b = 0; b < 8; ++b) a[b] = b1[tid];
    const float* wr = w1 + (size_t)tid * 512;
    for (int ci = 0; ci < 512; ci += 4) {
      const float4 wv = *(const float4*)(wr + ci);
#pragma unroll
      for (int b = 0; b < 8; ++b) {
        const float4 xv = *(const float4*)(&h1[b * 512 + ci]);
        a[b] = fmaf(xv.x, wv.x, a[b]);
        a[b] = fmaf(xv.y, wv.y, a[b]);
        a[b] = fmaf(xv.z, wv.z, a[b]);
        a[b] = fmaf(xv.w, wv.w, a[b]);
      }
    }
    float s = 0.f;
#pragma unroll
    for (int b = 0; b < 8; ++b) s += a[b];
    const float m = s * 0.125f;
    float v = 0.f;
#pragma unroll
    for (int b = 0; b < 8; ++b) { const float d = a[b] - m; v = fmaf(d, d, v); }
    const float sc = rsqrtf(v * 0.125f + EPS_BN);
#pragma unroll
    for (int b = 0; b < 8; ++b) h2[b * 256 + tid] = fmaxf(0.f, (a[b] - m) * sc);
  }
  __syncthreads();
  if (tid < 8) {  // layer 2: 256 -> 1, relu
    float s = b2[0];
    for (int ci = 0; ci < 256; ++ci) s = fmaf(h2[tid * 256 + ci], w2[ci], s);
    out[tid] = fmaxf(0.f, s);
  }
}

// =====================================================================
// Host orchestration
// =====================================================================
extern "C" void kernel_launch(void* const* d_in, const int* in_sizes, int n_in,
                              void* d_out, int out_size, void* d_ws, size_t ws_size,
                              hipStream_t stream) {
  (void)in_sizes; (void)n_in; (void)out_size; (void)ws_size;
  const float* obj  = (const float*)d_in[0];
  const float* grip = (const float*)d_in[1];
  const float* s1w0 = (const float*)d_in[2];
  const float* s1w1 = (const float*)d_in[3];
  const float* s1w2 = (const float*)d_in[4];
  const float* s2w0 = (const float*)d_in[5];
  const float* s2w1 = (const float*)d_in[6];
  const float* s2w2 = (const float*)d_in[7];
  const float* s3w0 = (const float*)d_in[8];
  const float* s3w1 = (const float*)d_in[9];
  const float* s3w2 = (const float*)d_in[10];
  const float* gw0  = (const float*)d_in[11];
  const float* gw1  = (const float*)d_in[12];
  const float* gw2  = (const float*)d_in[13];
  const float* hw0  = (const float*)d_in[14];
  const float* hb0  = (const float*)d_in[15];
  const float* hw1  = (const float*)d_in[16];
  const float* hb1  = (const float*)d_in[17];
  const float* hw2  = (const float*)d_in[18];
  const float* hb2  = (const float*)d_in[19];
  float* out = (float*)d_out;

  // ---- workspace layout (float offsets); total 26,658,304 floats ----
  float* wsf   = (float*)d_ws;
  float* stats = wsf;
  float* xyz1  = wsf + 23040;
  float* xyz2  = wsf + 35328;
  float* gfeat = wsf + 38400;
  float* objf  = wsf + 39424;
  float* f1    = wsf + 47616;
  float* f2    = wsf + 571904;
  float* x3    = wsf + 834048;
  int*   idx1  = (int*)(wsf + 1099264);
  int*   idx2  = (int*)(wsf + 1230336);
  float* bufP  = wsf + 1295872;
  float* bufQ  = wsf + 18073088;

  static const int st_off[12] = {0, 512, 1536, 2560, 3072, 3584,
                                 4608, 5632, 6656, 8704, 10752, 14848};
  auto st = [&](int li) { return stats + st_off[li]; };

  hipMemsetAsync(stats, 0, 23040 * sizeof(float), stream);

  auto gemm0 = [&](const float* X, const float* Wm, float* Y, int R, int Cin, int Cout,
                   int lo) {
    dim3 g((R + 127) / 128, (Cout + 127) / 128);
    gemm_xwt<false, false><<<g, 256, 0, stream>>>(X, Wm, Y, R, Cin, Cout, nullptr, 0,
                                                  st(lo), nullptr, 0);
  };
  auto gemmf = [&](const float* X, const float* Wm, float* Y, int R, int Cin, int Cout,
                   int li, int lo) {
    dim3 g((R + 127) / 128, (Cout + 127) / 128);
    gemm_xwt<true, false><<<g, 256, 0, stream>>>(X, Wm, Y, R, Cin, Cout, st(li), R,
                                                 st(lo), nullptr, 0);
  };
  auto gemmfM = [&](const float* X, const float* Wm, float* pooled, int R, int Cin,
                    int Cout, int li, int lo, int ns) {
    dim3 g((R + 127) / 128, (Cout + 127) / 128);
    gemm_xwt<true, true><<<g, 256, 0, stream>>>(X, Wm, nullptr, R, Cin, Cout, st(li), R,
                                                st(lo), pooled, ns);
  };
  auto applymax_k = [&](const float* Y, int li, int G, int ns, int C, float* o) {
    const int n = G * C;
    bn_apply_relu_maxpool<<<(n + 255) / 256, 256, 0, stream>>>(Y, st(li), o, G, ns, C);
  };
  auto applypool_k = [&](const float* P, int li, int G, int C, int Rtrue, float* o) {
    const int n = G * C;
    bn_apply_pooled<<<(n + 255) / 256, 256, 0, stream>>>(P, st(li), o, G, C, Rtrue);
  };

  // ---- SA1 FPS (R19: all-register scan, launch_bounds(1024,4) = 128 VGPR cap) ----
  fps_sa1_kernel<<<8, 1024, 0, stream>>>(obj, xyz1);

  // ---- gripper encoder: [8,512,3] -> 64 -> 128 -> 128 -> maxpool (ns=512 path) ----
  float* gY1 = bufP;
  float* gY2 = bufP + 262144;
  float* gY3 = bufP + 786432;
  gemm0(grip, gw0, gY1, 4096, 3, 64, 0);
  gemmf(gY1, gw1, gY2, 4096, 64, 128, 0, 1);
  gemmf(gY2, gw2, gY3, 4096, 128, 128, 1, 2);
  applymax_k(gY3, 2, 8, 512, 128, gfeat);

  // ---- SA1: ball r=0.2 ns=32 (wave-per-center), MLP 3->64->64->128 ----
  ballquery_wave_kernel<20000, 32><<<1024, 256, 0, stream>>>(xyz1, obj, idx1, 4096, 512, 0.04f);
  float* X1 = bufQ;
  group1_kernel<<<512, 256, 0, stream>>>(obj, xyz1, idx1, X1);
  gemm0(X1, s1w0, bufP, 131072, 3, 64, 3);
  gemmf(bufP, s1w1, bufQ, 131072, 64, 64, 3, 4);
  gemmfM(bufQ, s1w2, bufP, 131072, 64, 128, 4, 5, 32);   // pooled: 4096x128
  applypool_k(bufP, 5, 4096, 128, 131072, f1);

  // ---- SA2: FPS 512->128, ball r=0.4 ns=64, MLP 131->128->128->256 ----
  fps2_kernel<512, 128, 256, 2><<<8, 256, 0, stream>>>(xyz1, xyz2);
  ballquery_wave_kernel<512, 64><<<256, 256, 0, stream>>>(xyz2, xyz1, idx2, 1024, 128, 0.16f);
  float* X2 = bufQ;
  group2_kernel<<<(65536 * 131 + 255) / 256, 256, 0, stream>>>(xyz1, xyz2, f1, idx2, X2);
  gemm0(X2, s2w0, bufP, 65536, 131, 128, 6);
  gemmf(bufP, s2w1, bufQ, 65536, 128, 128, 6, 7);
  gemmfM(bufQ, s2w2, bufP, 65536, 128, 256, 7, 8, 64);   // pooled: 1024x256
  applypool_k(bufP, 8, 1024, 256, 65536, f2);

  // ---- SA3 (group_all): concat[xyz2,f2] -> 256 -> 512 -> 1024 -> maxpool ----
  build_x3_kernel<<<(1024 * 259 + 255) / 256, 256, 0, stream>>>(xyz2, f2, x3);
  float* Y3a = bufQ;
  float* Y3b = bufQ + 262144;
  float* Y3p = bufQ + 786432;
  gemm0(x3, s3w0, Y3a, 1024, 259, 256, 9);
  gemmf(Y3a, s3w1, Y3b, 1024, 256, 512, 9, 10);
  gemmfM(Y3b, s3w2, Y3p, 1024, 512, 1024, 10, 11, 128);  // pooled: 8x1024
  applypool_k(Y3p, 11, 8, 1024, 1024, objf);

  // ---- head ----
  head_kernel<<<1, 512, 0, stream>>>(gfeat, objf, hw0, hb0, hw1, hb1, hw2, hb2, out);
}

// Round 7
// 2348.680 us; speedup vs baseline: 1.2948x; 1.2905x over previous
//
#include <hip/hip_runtime.h>
#include <cstddef>
#include <cstdint>

#define EPS_BN 1e-5f
#define NBINS 4
#define NEG_INF (-__builtin_inff())

// =====================================================================
// Tiled fp32 GEMM:  Y[r][o] = sum_ci X'[r][ci] * W[o][ci]   (Y = X' W^T)
// 128x128 tile, BK=16, 256 threads, 8x8 microtile/thread (split
// quadrants, <=2-way LDS reads). R multiple of 128; Cout guarded.
// FUSE_IN:  X' = relu((X - mean)*scale) from st_in bins (prev layer BN).
// FUSE_MAX: instead of storing Y, store per-(ns-group, col) max of raw Y
//           into pooled[G][Cout]. Valid because ns | 128 (each tile has
//           only complete groups) and grid.y column ranges are disjoint
//           -> exactly one block writes each pooled element, no atomics.
//           BN+relu applied later on the pooled value (monotone => same
//           result as reference, exact fmaxf).
// Epilogue always: per-column sum/sumsq of raw Y into st_out bins.
// =====================================================================
template <bool FUSE_IN, bool FUSE_MAX>
__global__ __launch_bounds__(256) void gemm_xwt(const float* __restrict__ X,
                                                const float* __restrict__ Wm,
                                                float* __restrict__ Y,
                                                int R, int Cin, int Cout,
                                                const float* __restrict__ st_in, int Rin,
                                                float* __restrict__ st_out,
                                                float* __restrict__ pooled, int ns) {
  __shared__ __align__(16) float Xs[16][132];
  __shared__ __align__(16) float Ws[16][132];
  __shared__ float sMean[512], sScale[512];
  const int t  = threadIdx.x;
  const int r0 = blockIdx.x << 7;
  const int n0 = blockIdx.y << 7;
  const int tx = t & 15;
  const int ty = t >> 4;

  if constexpr (FUSE_IN) {
    const float inv = 1.f / (float)Rin;
    for (int k = t; k < Cin; k += 256) {
      float s = 0.f, q = 0.f;
#pragma unroll
      for (int bn = 0; bn < NBINS; ++bn) {
        s += st_in[bn * 2 * Cin + k];
        q += st_in[bn * 2 * Cin + Cin + k];
      }
      const float m  = s * inv;
      const float vr = fmaf(-m, m, q * inv);
      sMean[k]  = m;
      sScale[k] = rsqrtf(vr + EPS_BN);
    }
    __syncthreads();
  }

  float acc[8][8] = {};
  const int rStage = t >> 1;
  const int kBase  = (t & 1) << 3;
  const int nr     = n0 + rStage;

  for (int k0 = 0; k0 < Cin; k0 += 16) {
    const float* xrow = X  + (size_t)(r0 + rStage) * Cin + k0 + kBase;
    const float* wrow = Wm + (size_t)nr * Cin + k0 + kBase;
    if (((Cin & 3) == 0) && (k0 + 16 <= Cin)) {
      float4 xa = *(const float4*)(xrow);
      float4 xb = *(const float4*)(xrow + 4);
      if constexpr (FUSE_IN) {
        const int kb = k0 + kBase;
        xa.x = fmaxf(0.f, (xa.x - sMean[kb + 0]) * sScale[kb + 0]);
        xa.y = fmaxf(0.f, (xa.y - sMean[kb + 1]) * sScale[kb + 1]);
        xa.z = fmaxf(0.f, (xa.z - sMean[kb + 2]) * sScale[kb + 2]);
        xa.w = fmaxf(0.f, (xa.w - sMean[kb + 3]) * sScale[kb + 3]);
        xb.x = fmaxf(0.f, (xb.x - sMean[kb + 4]) * sScale[kb + 4]);
        xb.y = fmaxf(0.f, (xb.y - sMean[kb + 5]) * sScale[kb + 5]);
        xb.z = fmaxf(0.f, (xb.z - sMean[kb + 6]) * sScale[kb + 6]);
        xb.w = fmaxf(0.f, (xb.w - sMean[kb + 7]) * sScale[kb + 7]);
      }
      Xs[kBase + 0][rStage] = xa.x; Xs[kBase + 1][rStage] = xa.y;
      Xs[kBase + 2][rStage] = xa.z; Xs[kBase + 3][rStage] = xa.w;
      Xs[kBase + 4][rStage] = xb.x; Xs[kBase + 5][rStage] = xb.y;
      Xs[kBase + 6][rStage] = xb.z; Xs[kBase + 7][rStage] = xb.w;
      float4 wa = {0, 0, 0, 0}, wb = {0, 0, 0, 0};
      if (nr < Cout) { wa = *(const float4*)(wrow); wb = *(const float4*)(wrow + 4); }
      Ws[kBase + 0][rStage] = wa.x; Ws[kBase + 1][rStage] = wa.y;
      Ws[kBase + 2][rStage] = wa.z; Ws[kBase + 3][rStage] = wa.w;
      Ws[kBase + 4][rStage] = wb.x; Ws[kBase + 5][rStage] = wb.y;
      Ws[kBase + 6][rStage] = wb.z; Ws[kBase + 7][rStage] = wb.w;
    } else {
#pragma unroll
      for (int u = 0; u < 8; ++u) {
        const int k = k0 + kBase + u;
        float xe = 0.f, we = 0.f;
        if (k < Cin) {
          xe = xrow[u];
          if constexpr (FUSE_IN) xe = fmaxf(0.f, (xe - sMean[k]) * sScale[k]);
          if (nr < Cout) we = wrow[u];
        }
        Xs[kBase + u][rStage] = xe;
        Ws[kBase + u][rStage] = we;
      }
    }
    __syncthreads();
#pragma unroll
    for (int kk = 0; kk < 16; ++kk) {
      const float4 a0 = *(const float4*)(&Xs[kk][ty << 2]);
      const float4 a1 = *(const float4*)(&Xs[kk][64 + (ty << 2)]);
      const float4 b0 = *(const float4*)(&Ws[kk][tx << 2]);
      const float4 b1 = *(const float4*)(&Ws[kk][64 + (tx << 2)]);
      const float av[8] = {a0.x, a0.y, a0.z, a0.w, a1.x, a1.y, a1.z, a1.w};
      const float bw[8] = {b0.x, b0.y, b0.z, b0.w, b1.x, b1.y, b1.z, b1.w};
#pragma unroll
      for (int i = 0; i < 8; ++i)
#pragma unroll
        for (int j = 0; j < 8; ++j) acc[i][j] = fmaf(av[i], bw[j], acc[i][j]);
    }
    __syncthreads();
  }
  if constexpr (!FUSE_MAX) {
#pragma unroll
    for (int h = 0; h < 2; ++h)
#pragma unroll
      for (int i = 0; i < 4; ++i) {
        const int r = r0 + h * 64 + (ty << 2) + i;
        float* yr = Y + (size_t)r * Cout;
#pragma unroll
        for (int g = 0; g < 2; ++g) {
          const int n = n0 + g * 64 + (tx << 2);
          if (n < Cout) {
            float4 o = {acc[h * 4 + i][g * 4 + 0], acc[h * 4 + i][g * 4 + 1],
                        acc[h * 4 + i][g * 4 + 2], acc[h * 4 + i][g * 4 + 3]};
            *(float4*)(yr + n) = o;
          }
        }
      }
  }
  // stats epilogue: per-column partials -> LDS reduce -> binned atomics
#pragma unroll
  for (int g = 0; g < 2; ++g)
#pragma unroll
    for (int j = 0; j < 4; ++j) {
      float s = 0.f, q = 0.f;
#pragma unroll
      for (int rh = 0; rh < 8; ++rh) {
        const float v = acc[rh][g * 4 + j];
        s += v;
        q = fmaf(v, v, q);
      }
      Xs[ty][g * 64 + (tx << 2) + j] = s;
      Ws[ty][g * 64 + (tx << 2) + j] = q;
    }
  __syncthreads();
  if (t < 128) {
    const int n = n0 + t;
    if (n < Cout) {
      float s = 0.f, q = 0.f;
#pragma unroll
      for (int w = 0; w < 16; ++w) { s += Xs[w][t]; q += Ws[w][t]; }
      float* dst = st_out + (blockIdx.x & (NBINS - 1)) * 2 * Cout;
      atomicAdd(dst + n, s);
      atomicAdd(dst + Cout + n, q);
    }
  }
  // maxpool epilogue: ns in {32, 64, 128}
  if constexpr (FUSE_MAX) {
    __syncthreads();  // stats reduce done reading Xs/Ws
    float mxAll = NEG_INF;  // used only for ns==128 path (t<128)
#pragma unroll
    for (int h = 0; h < 2; ++h) {
      // thread's per-col max over its 4 rows in this half
#pragma unroll
      for (int g2 = 0; g2 < 2; ++g2)
#pragma unroll
        for (int j = 0; j < 4; ++j) {
          float mx = acc[h * 4 + 0][g2 * 4 + j];
          mx = fmaxf(mx, acc[h * 4 + 1][g2 * 4 + j]);
          mx = fmaxf(mx, acc[h * 4 + 2][g2 * 4 + j]);
          mx = fmaxf(mx, acc[h * 4 + 3][g2 * 4 + j]);
          Xs[ty][g2 * 64 + (tx << 2) + j] = mx;
        }
      __syncthreads();
      if (t < 128) {
        const int n = n0 + t;
        if (n < Cout) {
          if (ns <= 64) {
            const int tpg = ns >> 2;        // ty's per group
            const int gph = 64 / ns;        // groups per 64-row half
            for (int gq = 0; gq < gph; ++gq) {
              float mx = NEG_INF;
              for (int w = gq * tpg; w < gq * tpg + tpg; ++w) mx = fmaxf(mx, Xs[w][t]);
              const int g = (r0 + h * 64) / ns + gq;
              pooled[(size_t)g * Cout + n] = mx;
            }
          } else {  // ns == 128: single group spans both halves
            float mx = NEG_INF;
            for (int w = 0; w < 16; ++w) mx = fmaxf(mx, Xs[w][t]);
            mxAll = fmaxf(mxAll, mx);
          }
        }
      }
      __syncthreads();
    }
    if (ns > 64 && t < 128) {
      const int n = n0 + t;
      if (n < Cout) pooled[(size_t)(r0 >> 7) * Cout + n] = mxAll;
    }
  }
}

// BN apply on an already-pooled G x C buffer (Rtrue = rows of the raw Y)
__global__ void bn_apply_pooled(const float* __restrict__ P, const float* __restrict__ st,
                                float* __restrict__ o, int G, int C, int Rtrue) {
  const int i = blockIdx.x * 256 + threadIdx.x;
  if (i >= G * C) return;
  const int c = i % C;
  float s = 0.f, q = 0.f;
#pragma unroll
  for (int bn = 0; bn < NBINS; ++bn) {
    s += st[bn * 2 * C + c];
    q += st[bn * 2 * C + C + c];
  }
  const float inv = 1.f / (float)Rtrue;
  const float m  = s * inv;
  const float vr = fmaf(-m, m, q * inv);
  const float sc = rsqrtf(vr + EPS_BN);
  o[i] = fmaxf(0.f, (P[i] - m) * sc);
}

// normalize -> relu -> max over ns rows per group (gripper path, ns=512)
__global__ void bn_apply_relu_maxpool(const float* __restrict__ Y,
                                      const float* __restrict__ st,
                                      float* __restrict__ o, int G, int ns, int C) {
  const int i = blockIdx.x * 256 + threadIdx.x;
  if (i >= G * C) return;
  const int c = i % C;
  const int g = i / C;
  float s = 0.f, q = 0.f;
#pragma unroll
  for (int bn = 0; bn < NBINS; ++bn) {
    s += st[bn * 2 * C + c];
    q += st[bn * 2 * C + C + c];
  }
  const int R = G * ns;
  const float inv = 1.f / (float)R;
  const float m  = s * inv;
  const float vr = fmaf(-m, m, q * inv);
  const float sc = rsqrtf(vr + EPS_BN);
  const float* p = Y + (size_t)g * ns * C + c;
  float mx = NEG_INF;
  for (int k = 0; k < ns; ++k) mx = fmaxf(mx, p[(size_t)k * C]);
  o[i] = fmaxf(0.f, (mx - m) * sc);
}

// =====================================================================
// FPS for SA1 (N=20000 -> 512) — R20: all-register scan, take 3.
// R18/R19 post-mortem: the 80-float arrays spilled to scratch (VGPR=64,
// WRITE_SIZE 1136KB) because (a) the backend's default occupancy
// heuristic caps at 64 VGPR and __launch_bounds__(1024,4)'s min-waves
// hint did NOT raise it, and possibly (b) SROA failed on the arrays.
// Fix both: explicit __attribute__((amdgpu_waves_per_eu(4,4))) pins the
// range to exactly 4 waves/EU (= one 16-wave block/CU, all the 8-block
// grid can use) -> VGPR budget 512/4 = 128; and the 20 point-groups are
// macro-named SCALARS (R5's proven REP-macro style), no arrays to
// promote. ~100 VGPR needed, fits the 128 budget with zero spill.
// Step semantics bit-identical to R5 (absmax 0.0): ascending group
// order, index formula tid + (k<<10), same __fmul_rn/__fadd_rn/fminf
// chain, strict-> update, R5's two-barrier owner-detect reduce verbatim.
// SUCCESS SIGNAL: VGPR_Count ~96-128, WRITE_SIZE ~48KB. If VGPR stays
// 64 -> axis closed, revert to R5 next round.
// =====================================================================
#define REP20(X) X(0) X(1) X(2) X(3) X(4) X(5) X(6) X(7) X(8) X(9) \
                 X(10) X(11) X(12) X(13) X(14) X(15) X(16) X(17) X(18) X(19)

__global__ __launch_bounds__(1024)
__attribute__((amdgpu_waves_per_eu(4, 4)))
void fps_sa1_kernel(const float* __restrict__ xyz, float* __restrict__ new_xyz) {
  const int b    = blockIdx.x;
  const int tid  = threadIdx.x;
  const int lane = tid & 63;
  const int wave = tid >> 6;  // 0..15
  const float* p = xyz + (size_t)b * 20000 * 3;

  __shared__ float sv[16], sx[16], sy[16], sz[16];
  __shared__ int   si[16];
  __shared__ float bc[3];

#define DECLR(k) float px##k, py##k, pz##k, dd##k;
  REP20(DECLR)
#undef DECLR

#define INITR(k) {                                                          \
    const int i = tid + ((k) << 10);                                        \
    if (i < 20000) {                                                        \
      px##k = p[i * 3 + 0]; py##k = p[i * 3 + 1]; pz##k = p[i * 3 + 2];     \
      dd##k = 1e10f;                                                        \
    } else {                                                                \
      px##k = 0.f; py##k = 0.f; pz##k = 0.f;                                \
      dd##k = NEG_INF;                                                      \
    } }
  REP20(INITR)
#undef INITR

  float fx = p[0], fy = p[1], fz = p[2];
  if (tid == 0) {
    float* o = new_xyz + (size_t)b * 512 * 3;
    o[0] = fx; o[1] = fy; o[2] = fz;
  }
  __syncthreads();

  for (int s = 1; s < 512; ++s) {
    float bv = NEG_INF;
    int   bi = 0x7fffffff;
    float bx = 0.f, by = 0.f, bz = 0.f;
#define SCANR(k) {                                                          \
    const float dx = px##k - fx, dy = py##k - fy, dz = pz##k - fz;          \
    const float d  = __fadd_rn(__fadd_rn(__fmul_rn(dx, dx), __fmul_rn(dy, dy)), \
                               __fmul_rn(dz, dz));                          \
    const float nd = fminf(dd##k, d);                                       \
    dd##k = nd;                                                             \
    if (nd > bv) { bv = nd; bi = tid + ((k) << 10);                         \
                   bx = px##k; by = py##k; bz = pz##k; } }
    REP20(SCANR)
#undef SCANR
    float v  = bv;
    int   i0 = bi;
#pragma unroll
    for (int m = 1; m < 64; m <<= 1) {
      const float ov = __shfl_xor(v, m, 64);
      const int   oi = __shfl_xor(i0, m, 64);
      if (ov > v || (ov == v && oi < i0)) { v = ov; i0 = oi; }
    }
    if (i0 == bi) {  // unique owner lane of this wave's winner
      sv[wave] = bv; si[wave] = bi; sx[wave] = bx; sy[wave] = by; sz[wave] = bz;
    }
    __syncthreads();
    if (tid < 64) {
      const float lv = (lane < 16) ? sv[lane] : NEG_INF;
      const int   li = (lane < 16) ? si[lane] : 0x7fffffff;
      float v2 = lv;
      int   i2 = li;
#pragma unroll
      for (int m = 1; m < 16; m <<= 1) {
        const float ov = __shfl_xor(v2, m, 64);
        const int   oi = __shfl_xor(i2, m, 64);
        if (ov > v2 || (ov == v2 && oi < i2)) { v2 = ov; i2 = oi; }
      }
      if (lane < 16 && li == i2) {  // unique global owner
        const float wx = sx[lane], wy = sy[lane], wz = sz[lane];
        bc[0] = wx; bc[1] = wy; bc[2] = wz;
        float* o = new_xyz + ((size_t)b * 512 + s) * 3;
        o[0] = wx; o[1] = wy; o[2] = wz;
      }
    }
    __syncthreads();
    fx = bc[0]; fy = bc[1]; fz = bc[2];
  }
}

// =====================================================================
// FPS small (SA2: 512 -> 128), one block per batch, all state in regs.
// =====================================================================
template <int N, int NP, int THREADS, int NPT>
__global__ __launch_bounds__(THREADS)
void fps2_kernel(const float* __restrict__ xyz, float* __restrict__ new_xyz) {
  constexpr int NW = THREADS / 64;
  const int b    = blockIdx.x;
  const int tid  = threadIdx.x;
  const int lane = tid & 63;
  const int wave = tid >> 6;
  const float* p = xyz + (size_t)b * N * 3;
  float px[NPT], py[NPT], pz[NPT], dd[NPT];
#pragma unroll
  for (int j = 0; j < NPT; ++j) {
    const int i = tid + j * THREADS;
    if (i < N) {
      px[j] = p[i * 3 + 0];
      py[j] = p[i * 3 + 1];
      pz[j] = p[i * 3 + 2];
      dd[j] = 1e10f;
    } else {
      px[j] = 0.f; py[j] = 0.f; pz[j] = 0.f;
      dd[j] = NEG_INF;
    }
  }
  __shared__ float sv[NW], sx[NW], sy[NW], sz[NW];
  __shared__ int   si[NW];
  __shared__ float bc[3];
  float fx = p[0], fy = p[1], fz = p[2];
  if (tid == 0) {
    float* o = new_xyz + (size_t)b * NP * 3;
    o[0] = fx; o[1] = fy; o[2] = fz;
  }
  for (int s = 1; s < NP; ++s) {
    float bv = NEG_INF;
    int   bi = 0x7fffffff;
    float bx = 0.f, by = 0.f, bz = 0.f;
#pragma unroll
    for (int j = 0; j < NPT; ++j) {
      const float dx = px[j] - fx;
      const float dy = py[j] - fy;
      const float dz = pz[j] - fz;
      const float d  = __fadd_rn(__fadd_rn(__fmul_rn(dx, dx), __fmul_rn(dy, dy)),
                                 __fmul_rn(dz, dz));
      const float nd = fminf(dd[j], d);
      dd[j] = nd;
      if (nd > bv) { bv = nd; bi = tid + j * THREADS; bx = px[j]; by = py[j]; bz = pz[j]; }
    }
    float v = bv;
    int   i0 = bi;
#pragma unroll
    for (int m = 1; m < 64; m <<= 1) {
      const float ov = __shfl_xor(v, m, 64);
      const int   oi = __shfl_xor(i0, m, 64);
      if (ov > v || (ov == v && oi < i0)) { v = ov; i0 = oi; }
    }
    if (i0 == bi) {
      sv[wave] = bv; si[wave] = bi; sx[wave] = bx; sy[wave] = by; sz[wave] = bz;
    }
    __syncthreads();
    if (tid < 64) {
      const float lv = (lane < NW) ? sv[lane] : NEG_INF;
      const int   li = (lane < NW) ? si[lane] : 0x7fffffff;
      float v2 = lv;
      int   i2 = li;
#pragma unroll
      for (int m = 1; m < NW; m <<= 1) {
        const float ov = __shfl_xor(v2, m, 64);
        const int   oi = __shfl_xor(i2, m, 64);
        if (ov > v2 || (ov == v2 && oi < i2)) { v2 = ov; i2 = oi; }
      }
      if (lane < NW && li == i2) {
        const float wx = sx[lane], wy = sy[lane], wz = sz[lane];
        bc[0] = wx; bc[1] = wy; bc[2] = wz;
        float* o = new_xyz + ((size_t)b * NP + s) * 3;
        o[0] = wx; o[1] = wy; o[2] = wz;
      }
    }
    __syncthreads();
    fx = bc[0]; fy = bc[1]; fz = bc[2];
  }
}

// =====================================================================
// Ball query: ONE WAVE PER CENTER, ballot + prefix-popcount (R11,
// validated). Emits the first NS qualifying indices in ascending order.
// =====================================================================
template <int N, int NS>
__global__ __launch_bounds__(256)
void ballquery_wave_kernel(const float* __restrict__ centers,
                           const float* __restrict__ pts,
                           int* __restrict__ idx, int BS, int S, float r2) {
  const int w    = (blockIdx.x * 256 + threadIdx.x) >> 6;  // global wave id
  const int lane = threadIdx.x & 63;
  if (w >= BS) return;
  const int b = w / S;
  const float cx = centers[w * 3 + 0];
  const float cy = centers[w * 3 + 1];
  const float cz = centers[w * 3 + 2];
  const float* p = pts + (size_t)b * N * 3;
  int* o = idx + (size_t)w * NS;
  int total = 0;
  int first = -1;
  for (int i0 = 0; i0 < N && total < NS; i0 += 64) {
    const int i = i0 + lane;
    bool pred = false;
    if (i < N) {
      const float dx = cx - p[i * 3 + 0];
      const float dy = cy - p[i * 3 + 1];
      const float dz = cz - p[i * 3 + 2];
      const float d2 = __fadd_rn(__fadd_rn(__fmul_rn(dx, dx), __fmul_rn(dy, dy)),
                                 __fmul_rn(dz, dz));
      pred = (d2 < r2);
    }
    const unsigned long long mask = __ballot(pred);
    if (mask) {
      const unsigned long long below = (lane == 0) ? 0ull : (mask << (64 - lane));
      const int before = __popcll(below);
      if (pred && (total + before) < NS) o[total + before] = i;
      if (first < 0) first = i0 + (__ffsll((long long)mask) - 1);  // wave-uniform
      total += __popcll(mask);
    }
  }
  if (lane >= total && lane < NS) o[lane] = first;
}

// =====================================================================
// Grouping / concat kernels
// =====================================================================
__global__ void group1_kernel(const float* __restrict__ xyz, const float* __restrict__ ctr,
                              const int* __restrict__ idx, float* __restrict__ X1) {
  const int t = blockIdx.x * 256 + threadIdx.x;
  if (t >= 8 * 512 * 32) return;
  const int g = t >> 5;
  const int b = g >> 9;
  const int i = idx[t];
  const float* p = xyz + ((size_t)b * 20000 + i) * 3;
  const float* c = ctr + (size_t)g * 3;
  X1[t * 3 + 0] = (p[0] - c[0]) / 0.2f;
  X1[t * 3 + 1] = (p[1] - c[1]) / 0.2f;
  X1[t * 3 + 2] = (p[2] - c[2]) / 0.2f;
}

__global__ void group2_kernel(const float* __restrict__ xyz1,
                              const float* __restrict__ xyz2,
                              const float* __restrict__ f1,
                              const int* __restrict__ idx2,
                              float* __restrict__ X2) {
  const int t = blockIdx.x * 256 + threadIdx.x;
  if (t >= 65536 * 131) return;
  const int r = t / 131;
  const int c = t - r * 131;
  const int g = r >> 6;
  const int b = g >> 7;
  const int i = idx2[r];
  float v;
  if (c < 3) {
    v = (xyz1[((size_t)b * 512 + i) * 3 + c] - xyz2[(size_t)g * 3 + c]) / 0.4f;
  } else {
    v = f1[((size_t)b * 512 + i) * 128 + (c - 3)];
  }
  X2[t] = v;
}

__global__ void build_x3_kernel(const float* __restrict__ xyz2, const float* __restrict__ f2,
                                float* __restrict__ X3) {
  const int t = blockIdx.x * 256 + threadIdx.x;
  if (t >= 1024 * 259) return;
  const int r = t / 259;
  const int c = t - r * 259;
  X3[t] = (c < 3) ? xyz2[r * 3 + c] : f2[(size_t)r * 256 + (c - 3)];
}

// =====================================================================
// Fused head — float4 weight + LDS reads (R11, validated)
// =====================================================================
__global__ __launch_bounds__(512) void head_kernel(
    const float* __restrict__ gfeat, const float* __restrict__ objf,
    const float* __restrict__ w0, const float* __restrict__ b0,
    const float* __restrict__ w1, const float* __restrict__ b1,
    const float* __restrict__ w2, const float* __restrict__ b2,
    float* __restrict__ out) {
  __shared__ __align__(16) float comb[8 * 1152];
  __shared__ __align__(16) float h1[8 * 512];
  __shared__ __align__(16) float h2[8 * 256];
  const int tid = threadIdx.x;
  for (int i = tid; i < 8 * 1152; i += 512) {
    const int b = i / 1152, c = i - b * 1152;
    comb[i] = (c < 128) ? gfeat[b * 128 + c] : objf[b * 1024 + (c - 128)];
  }
  __syncthreads();
  for (int c = tid; c < 1152; c += 512) {
    float s = 0.f;
#pragma unroll
    for (int b = 0; b < 8; ++b) s += comb[b * 1152 + c];
    const float m = s * 0.125f;
    float v = 0.f;
#pragma unroll
    for (int b = 0; b < 8; ++b) { const float d = comb[b * 1152 + c] - m; v = fmaf(d, d, v); }
    const float sc = rsqrtf(v * 0.125f + EPS_BN);
#pragma unroll
    for (int b = 0; b < 8; ++b) comb[b * 1152 + c] = (comb[b * 1152 + c] - m) * sc;
  }
  __syncthreads();
  {  // layer 0: 1152 -> 512, float4 over k
    float a[8];
#pragma unroll
    for (int b = 0; b < 8; ++b) a[b] = b0[tid];
    const float* wr = w0 + (size_t)tid * 1152;
    for (int ci = 0; ci < 1152; ci += 4) {
      const float4 wv = *(const float4*)(wr + ci);
#pragma unroll
      for (int b = 0; b < 8; ++b) {
        const float4 xv = *(const float4*)(&comb[b * 1152 + ci]);
        a[b] = fmaf(xv.x, wv.x, a[b]);
        a[b] = fmaf(xv.y, wv.y, a[b]);
        a[b] = fmaf(xv.z, wv.z, a[b]);
        a[b] = fmaf(xv.w, wv.w, a[b]);
      }
    }
    float s = 0.f;
#pragma unroll
    for (int b = 0; b < 8; ++b) s += a[b];
    const float m = s * 0.125f;
    float v = 0.f;
#pragma unroll
    for (int b = 0; b < 8; ++b) { const float d = a[b] - m; v = fmaf(d, d, v); }
    const float sc = rsqrtf(v * 0.125f + EPS_BN);
#pragma unroll
    for (int b = 0; b < 8; ++b) h1[b * 512 + tid] = fmaxf(0.f, (a[b] - m) * sc);
  }
  __syncthreads();
  if (tid < 256) {  // layer 1: 512 -> 256, float4 over k
    float a[8];
#pragma unroll
    for (int b = 0; b < 8; ++b) a[b] = b1[tid];
    const float* wr = w1 + (size_t)tid * 512;
    for (int ci = 0; ci < 512; ci += 4) {
      const float4 wv = *(const float4*)(wr + ci);
#pragma unroll
      for (int b = 0; b < 8; ++b) {
        const float4 xv = *(const float4*)(&h1[b * 512 + ci]);
        a[b] = fmaf(xv.x, wv.x, a[b]);
        a[b] = fmaf(xv.y, wv.y, a[b]);
        a[b] = fmaf(xv.z, wv.z, a[b]);
        a[b] = fmaf(xv.w, wv.w, a[b]);
      }
    }
    float s = 0.f;
#pragma unroll
    for (int b = 0; b < 8; ++b) s += a[b];
    const float m = s * 0.125f;
    float v = 0.f;
#pragma unroll
    for (int b = 0; b < 8; ++b) { const float d = a[b] - m; v = fmaf(d, d, v); }
    const float sc = rsqrtf(v * 0.125f + EPS_BN);
#pragma unroll
    for (int b = 0; b < 8; ++b) h2[b * 256 + tid] = fmaxf(0.f, (a[b] - m) * sc);
  }
  __syncthreads();
  if (tid < 8) {  // layer 2: 256 -> 1, relu
    float s = b2[0];
    for (int ci = 0; ci < 256; ++ci) s = fmaf(h2[tid * 256 + ci], w2[ci], s);
    out[tid] = fmaxf(0.f, s);
  }
}

// =====================================================================
// Host orchestration
// =====================================================================
extern "C" void kernel_launch(void* const* d_in, const int* in_sizes, int n_in,
                              void* d_out, int out_size, void* d_ws, size_t ws_size,
                              hipStream_t stream) {
  (void)in_sizes; (void)n_in; (void)out_size; (void)ws_size;
  const float* obj  = (const float*)d_in[0];
  const float* grip = (const float*)d_in[1];
  const float* s1w0 = (const float*)d_in[2];
  const float* s1w1 = (const float*)d_in[3];
  const float* s1w2 = (const float*)d_in[4];
  const float* s2w0 = (const float*)d_in[5];
  const float* s2w1 = (const float*)d_in[6];
  const float* s2w2 = (const float*)d_in[7];
  const float* s3w0 = (const float*)d_in[8];
  const float* s3w1 = (const float*)d_in[9];
  const float* s3w2 = (const float*)d_in[10];
  const float* gw0  = (const float*)d_in[11];
  const float* gw1  = (const float*)d_in[12];
  const float* gw2  = (const float*)d_in[13];
  const float* hw0  = (const float*)d_in[14];
  const float* hb0  = (const float*)d_in[15];
  const float* hw1  = (const float*)d_in[16];
  const float* hb1  = (const float*)d_in[17];
  const float* hw2  = (const float*)d_in[18];
  const float* hb2  = (const float*)d_in[19];
  float* out = (float*)d_out;

  // ---- workspace layout (float offsets); total 26,658,304 floats ----
  float* wsf   = (float*)d_ws;
  float* stats = wsf;
  float* xyz1  = wsf + 23040;
  float* xyz2  = wsf + 35328;
  float* gfeat = wsf + 38400;
  float* objf  = wsf + 39424;
  float* f1    = wsf + 47616;
  float* f2    = wsf + 571904;
  float* x3    = wsf + 834048;
  int*   idx1  = (int*)(wsf + 1099264);
  int*   idx2  = (int*)(wsf + 1230336);
  float* bufP  = wsf + 1295872;
  float* bufQ  = wsf + 18073088;

  static const int st_off[12] = {0, 512, 1536, 2560, 3072, 3584,
                                 4608, 5632, 6656, 8704, 10752, 14848};
  auto st = [&](int li) { return stats + st_off[li]; };

  hipMemsetAsync(stats, 0, 23040 * sizeof(float), stream);

  auto gemm0 = [&](const float* X, const float* Wm, float* Y, int R, int Cin, int Cout,
                   int lo) {
    dim3 g((R + 127) / 128, (Cout + 127) / 128);
    gemm_xwt<false, false><<<g, 256, 0, stream>>>(X, Wm, Y, R, Cin, Cout, nullptr, 0,
                                                  st(lo), nullptr, 0);
  };
  auto gemmf = [&](const float* X, const float* Wm, float* Y, int R, int Cin, int Cout,
                   int li, int lo) {
    dim3 g((R + 127) / 128, (Cout + 127) / 128);
    gemm_xwt<true, false><<<g, 256, 0, stream>>>(X, Wm, Y, R, Cin, Cout, st(li), R,
                                                 st(lo), nullptr, 0);
  };
  auto gemmfM = [&](const float* X, const float* Wm, float* pooled, int R, int Cin,
                    int Cout, int li, int lo, int ns) {
    dim3 g((R + 127) / 128, (Cout + 127) / 128);
    gemm_xwt<true, true><<<g, 256, 0, stream>>>(X, Wm, nullptr, R, Cin, Cout, st(li), R,
                                                st(lo), pooled, ns);
  };
  auto applymax_k = [&](const float* Y, int li, int G, int ns, int C, float* o) {
    const int n = G * C;
    bn_apply_relu_maxpool<<<(n + 255) / 256, 256, 0, stream>>>(Y, st(li), o, G, ns, C);
  };
  auto applypool_k = [&](const float* P, int li, int G, int C, int Rtrue, float* o) {
    const int n = G * C;
    bn_apply_pooled<<<(n + 255) / 256, 256, 0, stream>>>(P, st(li), o, G, C, Rtrue);
  };

  // ---- SA1 FPS (R20: named-scalar all-register scan, waves_per_eu(4,4)) ----
  fps_sa1_kernel<<<8, 1024, 0, stream>>>(obj, xyz1);

  // ---- gripper encoder: [8,512,3] -> 64 -> 128 -> 128 -> maxpool (ns=512 path) ----
  float* gY1 = bufP;
  float* gY2 = bufP + 262144;
  float* gY3 = bufP + 786432;
  gemm0(grip, gw0, gY1, 4096, 3, 64, 0);
  gemmf(gY1, gw1, gY2, 4096, 64, 128, 0, 1);
  gemmf(gY2, gw2, gY3, 4096, 128, 128, 1, 2);
  applymax_k(gY3, 2, 8, 512, 128, gfeat);

  // ---- SA1: ball r=0.2 ns=32 (wave-per-center), MLP 3->64->64->128 ----
  ballquery_wave_kernel<20000, 32><<<1024, 256, 0, stream>>>(xyz1, obj, idx1, 4096, 512, 0.04f);
  float* X1 = bufQ;
  group1_kernel<<<512, 256, 0, stream>>>(obj, xyz1, idx1, X1);
  gemm0(X1, s1w0, bufP, 131072, 3, 64, 3);
  gemmf(bufP, s1w1, bufQ, 131072, 64, 64, 3, 4);
  gemmfM(bufQ, s1w2, bufP, 131072, 64, 128, 4, 5, 32);   // pooled: 4096x128
  applypool_k(bufP, 5, 4096, 128, 131072, f1);

  // ---- SA2: FPS 512->128, ball r=0.4 ns=64, MLP 131->128->128->256 ----
  fps2_kernel<512, 128, 256, 2><<<8, 256, 0, stream>>>(xyz1, xyz2);
  ballquery_wave_kernel<512, 64><<<256, 256, 0, stream>>>(xyz2, xyz1, idx2, 1024, 128, 0.16f);
  float* X2 = bufQ;
  group2_kernel<<<(65536 * 131 + 255) / 256, 256, 0, stream>>>(xyz1, xyz2, f1, idx2, X2);
  gemm0(X2, s2w0, bufP, 65536, 131, 128, 6);
  gemmf(bufP, s2w1, bufQ, 65536, 128, 128, 6, 7);
  gemmfM(bufQ, s2w2, bufP, 65536, 128, 256, 7, 8, 64);   // pooled: 1024x256
  applypool_k(bufP, 8, 1024, 256, 65536, f2);

  // ---- SA3 (group_all): concat[xyz2,f2] -> 256 -> 512 -> 1024 -> maxpool ----
  build_x3_kernel<<<(1024 * 259 + 255) / 256, 256, 0, stream>>>(xyz2, f2, x3);
  float* Y3a = bufQ;
  float* Y3b = bufQ + 262144;
  float* Y3p = bufQ + 786432;
  gemm0(x3, s3w0, Y3a, 1024, 259, 256, 9);
  gemmf(Y3a, s3w1, Y3b, 1024, 256, 512, 9, 10);
  gemmfM(Y3b, s3w2, Y3p, 1024, 512, 1024, 10, 11, 128);  // pooled: 8x1024
  applypool_k(Y3p, 11, 8, 1024, 1024, objf);

  // ---- head ----
  head_kernel<<<1, 512, 0, stream>>>(gfeat, objf, hw0, hb0, hw1, hb1, hw2, hb2, out);
}

// Round 8
// 2325.740 us; speedup vs baseline: 1.3076x; 1.0099x over previous
//
#include <hip/hip_runtime.h>
#include <cstddef>
#include <cstdint>

#define EPS_BN 1e-5f
#define NBINS 4
#define NEG_INF (-__builtin_inff())

// =====================================================================
// Tiled fp32 GEMM:  Y[r][o] = sum_ci X'[r][ci] * W[o][ci]   (Y = X' W^T)
// 128x128 tile, BK=16, 256 threads, 8x8 microtile/thread. See prior
// rounds; unchanged (validated).
// =====================================================================
template <bool FUSE_IN, bool FUSE_MAX>
__global__ __launch_bounds__(256) void gemm_xwt(const float* __restrict__ X,
                                                const float* __restrict__ Wm,
                                                float* __restrict__ Y,
                                                int R, int Cin, int Cout,
                                                const float* __restrict__ st_in, int Rin,
                                                float* __restrict__ st_out,
                                                float* __restrict__ pooled, int ns) {
  __shared__ __align__(16) float Xs[16][132];
  __shared__ __align__(16) float Ws[16][132];
  __shared__ float sMean[512], sScale[512];
  const int t  = threadIdx.x;
  const int r0 = blockIdx.x << 7;
  const int n0 = blockIdx.y << 7;
  const int tx = t & 15;
  const int ty = t >> 4;

  if constexpr (FUSE_IN) {
    const float inv = 1.f / (float)Rin;
    for (int k = t; k < Cin; k += 256) {
      float s = 0.f, q = 0.f;
#pragma unroll
      for (int bn = 0; bn < NBINS; ++bn) {
        s += st_in[bn * 2 * Cin + k];
        q += st_in[bn * 2 * Cin + Cin + k];
      }
      const float m  = s * inv;
      const float vr = fmaf(-m, m, q * inv);
      sMean[k]  = m;
      sScale[k] = rsqrtf(vr + EPS_BN);
    }
    __syncthreads();
  }

  float acc[8][8] = {};
  const int rStage = t >> 1;
  const int kBase  = (t & 1) << 3;
  const int nr     = n0 + rStage;

  for (int k0 = 0; k0 < Cin; k0 += 16) {
    const float* xrow = X  + (size_t)(r0 + rStage) * Cin + k0 + kBase;
    const float* wrow = Wm + (size_t)nr * Cin + k0 + kBase;
    if (((Cin & 3) == 0) && (k0 + 16 <= Cin)) {
      float4 xa = *(const float4*)(xrow);
      float4 xb = *(const float4*)(xrow + 4);
      if constexpr (FUSE_IN) {
        const int kb = k0 + kBase;
        xa.x = fmaxf(0.f, (xa.x - sMean[kb + 0]) * sScale[kb + 0]);
        xa.y = fmaxf(0.f, (xa.y - sMean[kb + 1]) * sScale[kb + 1]);
        xa.z = fmaxf(0.f, (xa.z - sMean[kb + 2]) * sScale[kb + 2]);
        xa.w = fmaxf(0.f, (xa.w - sMean[kb + 3]) * sScale[kb + 3]);
        xb.x = fmaxf(0.f, (xb.x - sMean[kb + 4]) * sScale[kb + 4]);
        xb.y = fmaxf(0.f, (xb.y - sMean[kb + 5]) * sScale[kb + 5]);
        xb.z = fmaxf(0.f, (xb.z - sMean[kb + 6]) * sScale[kb + 6]);
        xb.w = fmaxf(0.f, (xb.w - sMean[kb + 7]) * sScale[kb + 7]);
      }
      Xs[kBase + 0][rStage] = xa.x; Xs[kBase + 1][rStage] = xa.y;
      Xs[kBase + 2][rStage] = xa.z; Xs[kBase + 3][rStage] = xa.w;
      Xs[kBase + 4][rStage] = xb.x; Xs[kBase + 5][rStage] = xb.y;
      Xs[kBase + 6][rStage] = xb.z; Xs[kBase + 7][rStage] = xb.w;
      float4 wa = {0, 0, 0, 0}, wb = {0, 0, 0, 0};
      if (nr < Cout) { wa = *(const float4*)(wrow); wb = *(const float4*)(wrow + 4); }
      Ws[kBase + 0][rStage] = wa.x; Ws[kBase + 1][rStage] = wa.y;
      Ws[kBase + 2][rStage] = wa.z; Ws[kBase + 3][rStage] = wa.w;
      Ws[kBase + 4][rStage] = wb.x; Ws[kBase + 5][rStage] = wb.y;
      Ws[kBase + 6][rStage] = wb.z; Ws[kBase + 7][rStage] = wb.w;
    } else {
#pragma unroll
      for (int u = 0; u < 8; ++u) {
        const int k = k0 + kBase + u;
        float xe = 0.f, we = 0.f;
        if (k < Cin) {
          xe = xrow[u];
          if constexpr (FUSE_IN) xe = fmaxf(0.f, (xe - sMean[k]) * sScale[k]);
          if (nr < Cout) we = wrow[u];
        }
        Xs[kBase + u][rStage] = xe;
        Ws[kBase + u][rStage] = we;
      }
    }
    __syncthreads();
#pragma unroll
    for (int kk = 0; kk < 16; ++kk) {
      const float4 a0 = *(const float4*)(&Xs[kk][ty << 2]);
      const float4 a1 = *(const float4*)(&Xs[kk][64 + (ty << 2)]);
      const float4 b0 = *(const float4*)(&Ws[kk][tx << 2]);
      const float4 b1 = *(const float4*)(&Ws[kk][64 + (tx << 2)]);
      const float av[8] = {a0.x, a0.y, a0.z, a0.w, a1.x, a1.y, a1.z, a1.w};
      const float bw[8] = {b0.x, b0.y, b0.z, b0.w, b1.x, b1.y, b1.z, b1.w};
#pragma unroll
      for (int i = 0; i < 8; ++i)
#pragma unroll
        for (int j = 0; j < 8; ++j) acc[i][j] = fmaf(av[i], bw[j], acc[i][j]);
    }
    __syncthreads();
  }
  if constexpr (!FUSE_MAX) {
#pragma unroll
    for (int h = 0; h < 2; ++h)
#pragma unroll
      for (int i = 0; i < 4; ++i) {
        const int r = r0 + h * 64 + (ty << 2) + i;
        float* yr = Y + (size_t)r * Cout;
#pragma unroll
        for (int g = 0; g < 2; ++g) {
          const int n = n0 + g * 64 + (tx << 2);
          if (n < Cout) {
            float4 o = {acc[h * 4 + i][g * 4 + 0], acc[h * 4 + i][g * 4 + 1],
                        acc[h * 4 + i][g * 4 + 2], acc[h * 4 + i][g * 4 + 3]};
            *(float4*)(yr + n) = o;
          }
        }
      }
  }
  // stats epilogue: per-column partials -> LDS reduce -> binned atomics
#pragma unroll
  for (int g = 0; g < 2; ++g)
#pragma unroll
    for (int j = 0; j < 4; ++j) {
      float s = 0.f, q = 0.f;
#pragma unroll
      for (int rh = 0; rh < 8; ++rh) {
        const float v = acc[rh][g * 4 + j];
        s += v;
        q = fmaf(v, v, q);
      }
      Xs[ty][g * 64 + (tx << 2) + j] = s;
      Ws[ty][g * 64 + (tx << 2) + j] = q;
    }
  __syncthreads();
  if (t < 128) {
    const int n = n0 + t;
    if (n < Cout) {
      float s = 0.f, q = 0.f;
#pragma unroll
      for (int w = 0; w < 16; ++w) { s += Xs[w][t]; q += Ws[w][t]; }
      float* dst = st_out + (blockIdx.x & (NBINS - 1)) * 2 * Cout;
      atomicAdd(dst + n, s);
      atomicAdd(dst + Cout + n, q);
    }
  }
  // maxpool epilogue: ns in {32, 64, 128}
  if constexpr (FUSE_MAX) {
    __syncthreads();
    float mxAll = NEG_INF;
#pragma unroll
    for (int h = 0; h < 2; ++h) {
#pragma unroll
      for (int g2 = 0; g2 < 2; ++g2)
#pragma unroll
        for (int j = 0; j < 4; ++j) {
          float mx = acc[h * 4 + 0][g2 * 4 + j];
          mx = fmaxf(mx, acc[h * 4 + 1][g2 * 4 + j]);
          mx = fmaxf(mx, acc[h * 4 + 2][g2 * 4 + j]);
          mx = fmaxf(mx, acc[h * 4 + 3][g2 * 4 + j]);
          Xs[ty][g2 * 64 + (tx << 2) + j] = mx;
        }
      __syncthreads();
      if (t < 128) {
        const int n = n0 + t;
        if (n < Cout) {
          if (ns <= 64) {
            const int tpg = ns >> 2;
            const int gph = 64 / ns;
            for (int gq = 0; gq < gph; ++gq) {
              float mx = NEG_INF;
              for (int w = gq * tpg; w < gq * tpg + tpg; ++w) mx = fmaxf(mx, Xs[w][t]);
              const int g = (r0 + h * 64) / ns + gq;
              pooled[(size_t)g * Cout + n] = mx;
            }
          } else {
            float mx = NEG_INF;
            for (int w = 0; w < 16; ++w) mx = fmaxf(mx, Xs[w][t]);
            mxAll = fmaxf(mxAll, mx);
          }
        }
      }
      __syncthreads();
    }
    if (ns > 64 && t < 128) {
      const int n = n0 + t;
      if (n < Cout) pooled[(size_t)(r0 >> 7) * Cout + n] = mxAll;
    }
  }
}

// normalize -> relu -> max over ns rows per group (gripper path, ns=512)
__global__ void bn_apply_relu_maxpool(const float* __restrict__ Y,
                                      const float* __restrict__ st,
                                      float* __restrict__ o, int G, int ns, int C) {
  const int i = blockIdx.x * 256 + threadIdx.x;
  if (i >= G * C) return;
  const int c = i % C;
  const int g = i / C;
  float s = 0.f, q = 0.f;
#pragma unroll
  for (int bn = 0; bn < NBINS; ++bn) {
    s += st[bn * 2 * C + c];
    q += st[bn * 2 * C + C + c];
  }
  const int R = G * ns;
  const float inv = 1.f / (float)R;
  const float m  = s * inv;
  const float vr = fmaf(-m, m, q * inv);
  const float sc = rsqrtf(vr + EPS_BN);
  const float* p = Y + (size_t)g * ns * C + c;
  float mx = NEG_INF;
  for (int k = 0; k < ns; ++k) mx = fmaxf(mx, p[(size_t)k * C]);
  o[i] = fmaxf(0.f, (mx - m) * sc);
}

// =====================================================================
// FPS for SA1 — R20 FROZEN (1348 us, best measured; do not modify).
// Named-scalar 20-group scan + waves_per_eu(4,4); R5 two-barrier reduce.
// =====================================================================
#define REP20(X) X(0) X(1) X(2) X(3) X(4) X(5) X(6) X(7) X(8) X(9) \
                 X(10) X(11) X(12) X(13) X(14) X(15) X(16) X(17) X(18) X(19)

__global__ __launch_bounds__(1024)
__attribute__((amdgpu_waves_per_eu(4, 4)))
void fps_sa1_kernel(const float* __restrict__ xyz, float* __restrict__ new_xyz) {
  const int b    = blockIdx.x;
  const int tid  = threadIdx.x;
  const int lane = tid & 63;
  const int wave = tid >> 6;  // 0..15
  const float* p = xyz + (size_t)b * 20000 * 3;

  __shared__ float sv[16], sx[16], sy[16], sz[16];
  __shared__ int   si[16];
  __shared__ float bc[3];

#define DECLR(k) float px##k, py##k, pz##k, dd##k;
  REP20(DECLR)
#undef DECLR

#define INITR(k) {                                                          \
    const int i = tid + ((k) << 10);                                        \
    if (i < 20000) {                                                        \
      px##k = p[i * 3 + 0]; py##k = p[i * 3 + 1]; pz##k = p[i * 3 + 2];     \
      dd##k = 1e10f;                                                        \
    } else {                                                                \
      px##k = 0.f; py##k = 0.f; pz##k = 0.f;                                \
      dd##k = NEG_INF;                                                      \
    } }
  REP20(INITR)
#undef INITR

  float fx = p[0], fy = p[1], fz = p[2];
  if (tid == 0) {
    float* o = new_xyz + (size_t)b * 512 * 3;
    o[0] = fx; o[1] = fy; o[2] = fz;
  }
  __syncthreads();

  for (int s = 1; s < 512; ++s) {
    float bv = NEG_INF;
    int   bi = 0x7fffffff;
    float bx = 0.f, by = 0.f, bz = 0.f;
#define SCANR(k) {                                                          \
    const float dx = px##k - fx, dy = py##k - fy, dz = pz##k - fz;          \
    const float d  = __fadd_rn(__fadd_rn(__fmul_rn(dx, dx), __fmul_rn(dy, dy)), \
                               __fmul_rn(dz, dz));                          \
    const float nd = fminf(dd##k, d);                                       \
    dd##k = nd;                                                             \
    if (nd > bv) { bv = nd; bi = tid + ((k) << 10);                         \
                   bx = px##k; by = py##k; bz = pz##k; } }
    REP20(SCANR)
#undef SCANR
    float v  = bv;
    int   i0 = bi;
#pragma unroll
    for (int m = 1; m < 64; m <<= 1) {
      const float ov = __shfl_xor(v, m, 64);
      const int   oi = __shfl_xor(i0, m, 64);
      if (ov > v || (ov == v && oi < i0)) { v = ov; i0 = oi; }
    }
    if (i0 == bi) {  // unique owner lane of this wave's winner
      sv[wave] = bv; si[wave] = bi; sx[wave] = bx; sy[wave] = by; sz[wave] = bz;
    }
    __syncthreads();
    if (tid < 64) {
      const float lv = (lane < 16) ? sv[lane] : NEG_INF;
      const int   li = (lane < 16) ? si[lane] : 0x7fffffff;
      float v2 = lv;
      int   i2 = li;
#pragma unroll
      for (int m = 1; m < 16; m <<= 1) {
        const float ov = __shfl_xor(v2, m, 64);
        const int   oi = __shfl_xor(i2, m, 64);
        if (ov > v2 || (ov == v2 && oi < i2)) { v2 = ov; i2 = oi; }
      }
      if (lane < 16 && li == i2) {  // unique global owner
        const float wx = sx[lane], wy = sy[lane], wz = sz[lane];
        bc[0] = wx; bc[1] = wy; bc[2] = wz;
        float* o = new_xyz + ((size_t)b * 512 + s) * 3;
        o[0] = wx; o[1] = wy; o[2] = wz;
      }
    }
    __syncthreads();
    fx = bc[0]; fy = bc[1]; fz = bc[2];
  }
}

// =====================================================================
// FPS small (SA2: 512 -> 128) — R21: SINGLE WAVE, zero barriers, zero
// LDS. 64 lanes x 8 points in regs; butterfly carries (v, idx, coords)
// so the winner's coords converge on all lanes (5 shuffles/stage).
// Selection semantics identical to the old 256-thread fps2 (bi is the
// true point index in both; same strict-> local keep-first in ascending
// index order; same (value, idx) butterfly tiebreak).
// =====================================================================
__global__ __launch_bounds__(64)
void fps2_wave_kernel(const float* __restrict__ xyz, float* __restrict__ new_xyz) {
  const int b    = blockIdx.x;
  const int lane = threadIdx.x;
  const float* p = xyz + (size_t)b * 512 * 3;
  float px[8], py[8], pz[8], dd[8];
#pragma unroll
  for (int j = 0; j < 8; ++j) {
    const int i = lane + (j << 6);
    px[j] = p[i * 3 + 0]; py[j] = p[i * 3 + 1]; pz[j] = p[i * 3 + 2];
    dd[j] = 1e10f;
  }
  float fx = p[0], fy = p[1], fz = p[2];
  if (lane == 0) {
    float* o = new_xyz + (size_t)b * 128 * 3;
    o[0] = fx; o[1] = fy; o[2] = fz;
  }
  for (int s = 1; s < 128; ++s) {
    float bv = NEG_INF;
    int   bi = 0x7fffffff;
    float bx = 0.f, by = 0.f, bz = 0.f;
#pragma unroll
    for (int j = 0; j < 8; ++j) {
      const float dx = px[j] - fx, dy = py[j] - fy, dz = pz[j] - fz;
      const float d  = __fadd_rn(__fadd_rn(__fmul_rn(dx, dx), __fmul_rn(dy, dy)),
                                 __fmul_rn(dz, dz));
      const float nd = fminf(dd[j], d);
      dd[j] = nd;
      if (nd > bv) { bv = nd; bi = lane + (j << 6); bx = px[j]; by = py[j]; bz = pz[j]; }
    }
    float v = bv; int i0 = bi;
    float wx = bx, wy = by, wz = bz;
#pragma unroll
    for (int m = 1; m < 64; m <<= 1) {
      const float ov = __shfl_xor(v, m, 64);
      const int   oi = __shfl_xor(i0, m, 64);
      const float ox = __shfl_xor(wx, m, 64);
      const float oy = __shfl_xor(wy, m, 64);
      const float oz = __shfl_xor(wz, m, 64);
      if (ov > v || (ov == v && oi < i0)) { v = ov; i0 = oi; wx = ox; wy = oy; wz = oz; }
    }
    fx = wx; fy = wy; fz = wz;  // converged on all lanes
    if (lane == 0) {
      float* o = new_xyz + ((size_t)b * 128 + s) * 3;
      o[0] = fx; o[1] = fy; o[2] = fz;
    }
  }
}

// =====================================================================
// Ball query (SA2): ONE WAVE PER CENTER, ballot + prefix-popcount.
// =====================================================================
template <int N, int NS>
__global__ __launch_bounds__(256)
void ballquery_wave_kernel(const float* __restrict__ centers,
                           const float* __restrict__ pts,
                           int* __restrict__ idx, int BS, int S, float r2) {
  const int w    = (blockIdx.x * 256 + threadIdx.x) >> 6;
  const int lane = threadIdx.x & 63;
  if (w >= BS) return;
  const int b = w / S;
  const float cx = centers[w * 3 + 0];
  const float cy = centers[w * 3 + 1];
  const float cz = centers[w * 3 + 2];
  const float* p = pts + (size_t)b * N * 3;
  int* o = idx + (size_t)w * NS;
  int total = 0;
  int first = -1;
  for (int i0 = 0; i0 < N && total < NS; i0 += 64) {
    const int i = i0 + lane;
    bool pred = false;
    if (i < N) {
      const float dx = cx - p[i * 3 + 0];
      const float dy = cy - p[i * 3 + 1];
      const float dz = cz - p[i * 3 + 2];
      const float d2 = __fadd_rn(__fadd_rn(__fmul_rn(dx, dx), __fmul_rn(dy, dy)),
                                 __fmul_rn(dz, dz));
      pred = (d2 < r2);
    }
    const unsigned long long mask = __ballot(pred);
    if (mask) {
      const unsigned long long below = (lane == 0) ? 0ull : (mask << (64 - lane));
      const int before = __popcll(below);
      if (pred && (total + before) < NS) o[total + before] = i;
      if (first < 0) first = i0 + (__ffsll((long long)mask) - 1);
      total += __popcll(mask);
    }
  }
  if (lane >= total && lane < NS) o[lane] = first;
}

// =====================================================================
// R21: fused ballquery(SA1, r=0.2, ns=32) + group1. Wave-per-center:
// indices collected into per-wave LDS (never hit global), then the wave
// gathers + normalizes + writes X1 rows directly. Identical index
// semantics to ballquery_wave_kernel (running-total prefix allocation,
// pad-with-first) and identical normalize expr to group1 ((p-c)/0.2f).
// =====================================================================
__global__ __launch_bounds__(256)
void ballq_group1_kernel(const float* __restrict__ centers,  // xyz1 [8,512,3]
                         const float* __restrict__ pts,      // obj  [8,20000,3]
                         float* __restrict__ X1) {           // [8*512*32,3]
  __shared__ int sIdx[4][32];
  const int wIn  = threadIdx.x >> 6;                         // wave in block
  const int w    = (blockIdx.x * 256 + threadIdx.x) >> 6;    // center id
  const int lane = threadIdx.x & 63;
  if (w >= 4096) return;
  const int b = w >> 9;
  const float cx = centers[w * 3 + 0];
  const float cy = centers[w * 3 + 1];
  const float cz = centers[w * 3 + 2];
  const float* p = pts + (size_t)b * 20000 * 3;
  int total = 0;
  int first = -1;
  for (int i0 = 0; i0 < 20000 && total < 32; i0 += 64) {
    const int i = i0 + lane;
    bool pred = false;
    if (i < 20000) {
      const float dx = cx - p[i * 3 + 0];
      const float dy = cy - p[i * 3 + 1];
      const float dz = cz - p[i * 3 + 2];
      const float d2 = __fadd_rn(__fadd_rn(__fmul_rn(dx, dx), __fmul_rn(dy, dy)),
                                 __fmul_rn(dz, dz));
      pred = (d2 < 0.04f);
    }
    const unsigned long long mask = __ballot(pred);
    if (mask) {
      const unsigned long long below = (lane == 0) ? 0ull : (mask << (64 - lane));
      const int before = __popcll(below);
      if (pred && (total + before) < 32) sIdx[wIn][total + before] = i;
      if (first < 0) first = i0 + (__ffsll((long long)mask) - 1);
      total += __popcll(mask);
    }
  }
  __builtin_amdgcn_wave_barrier();  // scheduling fence: LDS writes before reads
  if (lane < 32) {
    const int i = (lane < total) ? sIdx[wIn][lane] : first;
    const float* q = p + (size_t)i * 3;
    float* o = X1 + ((size_t)w * 32 + lane) * 3;
    o[0] = (q[0] - cx) / 0.2f;
    o[1] = (q[1] - cy) / 0.2f;
    o[2] = (q[2] - cz) / 0.2f;
  }
}

// =====================================================================
// R21: group2 with BN(f1) fused. Reads raw pooled P1 [4096,128] + st(5)
// stats; per-block LDS mean/scale table (bit-identical formula/order to
// the removed bn_apply_pooled with C=128, Rtrue=131072).
// =====================================================================
__global__ __launch_bounds__(256)
void group2_kernel(const float* __restrict__ xyz1,
                   const float* __restrict__ xyz2,
                   const float* __restrict__ P1,
                   const float* __restrict__ st,
                   const int* __restrict__ idx2,
                   float* __restrict__ X2) {
  __shared__ float sM[128], sS[128];
  const int t0 = threadIdx.x;
  if (t0 < 128) {
    float s = 0.f, q = 0.f;
#pragma unroll
    for (int bn = 0; bn < NBINS; ++bn) {
      s += st[bn * 256 + t0];
      q += st[bn * 256 + 128 + t0];
    }
    const float inv = 1.f / 131072.f;
    const float m  = s * inv;
    const float vr = fmaf(-m, m, q * inv);
    sM[t0] = m;
    sS[t0] = rsqrtf(vr + EPS_BN);
  }
  __syncthreads();
  const int t = blockIdx.x * 256 + t0;
  if (t >= 65536 * 131) return;
  const int r = t / 131;
  const int c = t - r * 131;
  const int g = r >> 6;
  const int b = g >> 7;
  const int i = idx2[r];
  float v;
  if (c < 3) {
    v = (xyz1[((size_t)b * 512 + i) * 3 + c] - xyz2[(size_t)g * 3 + c]) / 0.4f;
  } else {
    const int cc = c - 3;
    v = P1[((size_t)b * 512 + i) * 128 + cc];
    v = fmaxf(0.f, (v - sM[cc]) * sS[cc]);
  }
  X2[t] = v;
}

// =====================================================================
// R21: build_x3 with BN(f2) fused. Reads raw pooled P2 [1024,256] +
// st(8); per-block LDS table (C=256, Rtrue=65536).
// =====================================================================
__global__ __launch_bounds__(256)
void build_x3_kernel(const float* __restrict__ xyz2, const float* __restrict__ P2,
                     const float* __restrict__ st, float* __restrict__ X3) {
  __shared__ float sM[256], sS[256];
  const int t0 = threadIdx.x;
  {
    float s = 0.f, q = 0.f;
#pragma unroll
    for (int bn = 0; bn < NBINS; ++bn) {
      s += st[bn * 512 + t0];
      q += st[bn * 512 + 256 + t0];
    }
    const float inv = 1.f / 65536.f;
    const float m  = s * inv;
    const float vr = fmaf(-m, m, q * inv);
    sM[t0] = m;
    sS[t0] = rsqrtf(vr + EPS_BN);
  }
  __syncthreads();
  const int t = blockIdx.x * 256 + t0;
  if (t >= 1024 * 259) return;
  const int r = t / 259;
  const int c = t - r * 259;
  float v;
  if (c < 3) {
    v = xyz2[r * 3 + c];
  } else {
    const int cc = c - 3;
    v = P2[(size_t)r * 256 + cc];
    v = fmaxf(0.f, (v - sM[cc]) * sS[cc]);
  }
  X3[t] = v;
}

// =====================================================================
// Fused head — R21: BN(objf) inlined into the comb load (reads raw
// pooled Y3p [8,1024] + st(11), C=1024, Rtrue=1024; identical formula).
// =====================================================================
__global__ __launch_bounds__(512) void head_kernel(
    const float* __restrict__ gfeat, const float* __restrict__ Y3p,
    const float* __restrict__ st11,
    const float* __restrict__ w0, const float* __restrict__ b0,
    const float* __restrict__ w1, const float* __restrict__ b1,
    const float* __restrict__ w2, const float* __restrict__ b2,
    float* __restrict__ out) {
  __shared__ __align__(16) float comb[8 * 1152];
  __shared__ __align__(16) float h1[8 * 512];
  __shared__ __align__(16) float h2[8 * 256];
  const int tid = threadIdx.x;
  for (int i = tid; i < 8 * 1152; i += 512) {
    const int b = i / 1152, c = i - b * 1152;
    float v;
    if (c < 128) {
      v = gfeat[b * 128 + c];
    } else {
      const int cc = c - 128;
      float s = 0.f, q = 0.f;
#pragma unroll
      for (int bn = 0; bn < NBINS; ++bn) {
        s += st11[bn * 2048 + cc];
        q += st11[bn * 2048 + 1024 + cc];
      }
      const float inv = 1.f / 1024.f;
      const float m  = s * inv;
      const float vr = fmaf(-m, m, q * inv);
      const float sc = rsqrtf(vr + EPS_BN);
      v = fmaxf(0.f, (Y3p[b * 1024 + cc] - m) * sc);
    }
    comb[i] = v;
  }
  __syncthreads();
  for (int c = tid; c < 1152; c += 512) {
    float s = 0.f;
#pragma unroll
    for (int b = 0; b < 8; ++b) s += comb[b * 1152 + c];
    const float m = s * 0.125f;
    float v = 0.f;
#pragma unroll
    for (int b = 0; b < 8; ++b) { const float d = comb[b * 1152 + c] - m; v = fmaf(d, d, v); }
    const float sc = rsqrtf(v * 0.125f + EPS_BN);
#pragma unroll
    for (int b = 0; b < 8; ++b) comb[b * 1152 + c] = (comb[b * 1152 + c] - m) * sc;
  }
  __syncthreads();
  {  // layer 0: 1152 -> 512
    float a[8];
#pragma unroll
    for (int b = 0; b < 8; ++b) a[b] = b0[tid];
    const float* wr = w0 + (size_t)tid * 1152;
    for (int ci = 0; ci < 1152; ci += 4) {
      const float4 wv = *(const float4*)(wr + ci);
#pragma unroll
      for (int b = 0; b < 8; ++b) {
        const float4 xv = *(const float4*)(&comb[b * 1152 + ci]);
        a[b] = fmaf(xv.x, wv.x, a[b]);
        a[b] = fmaf(xv.y, wv.y, a[b]);
        a[b] = fmaf(xv.z, wv.z, a[b]);
        a[b] = fmaf(xv.w, wv.w, a[b]);
      }
    }
    float s = 0.f;
#pragma unroll
    for (int b = 0; b < 8; ++b) s += a[b];
    const float m = s * 0.125f;
    float v = 0.f;
#pragma unroll
    for (int b = 0; b < 8; ++b) { const float d = a[b] - m; v = fmaf(d, d, v); }
    const float sc = rsqrtf(v * 0.125f + EPS_BN);
#pragma unroll
    for (int b = 0; b < 8; ++b) h1[b * 512 + tid] = fmaxf(0.f, (a[b] - m) * sc);
  }
  __syncthreads();
  if (tid < 256) {  // layer 1: 512 -> 256
    float a[8];
#pragma unroll
    for (int b = 0; b < 8; ++b) a[b] = b1[tid];
    const float* wr = w1 + (size_t)tid * 512;
    for (int ci = 0; ci < 512; ci += 4) {
      const float4 wv = *(const float4*)(wr + ci);
#pragma unroll
      for (int b = 0; b < 8; ++b) {
        const float4 xv = *(const float4*)(&h1[b * 512 + ci]);
        a[b] = fmaf(xv.x, wv.x, a[b]);
        a[b] = fmaf(xv.y, wv.y, a[b]);
        a[b] = fmaf(xv.z, wv.z, a[b]);
        a[b] = fmaf(xv.w, wv.w, a[b]);
      }
    }
    float s = 0.f;
#pragma unroll
    for (int b = 0; b < 8; ++b) s += a[b];
    const float m = s * 0.125f;
    float v = 0.f;
#pragma unroll
    for (int b = 0; b < 8; ++b) { const float d = a[b] - m; v = fmaf(d, d, v); }
    const float sc = rsqrtf(v * 0.125f + EPS_BN);
#pragma unroll
    for (int b = 0; b < 8; ++b) h2[b * 256 + tid] = fmaxf(0.f, (a[b] - m) * sc);
  }
  __syncthreads();
  if (tid < 8) {  // layer 2: 256 -> 1, relu
    float s = b2[0];
    for (int ci = 0; ci < 256; ++ci) s = fmaf(h2[tid * 256 + ci], w2[ci], s);
    out[tid] = fmaxf(0.f, s);
  }
}

// =====================================================================
// Host orchestration — R21: 4 dispatches removed (group1, applypool x3)
// via fusion; fps2 single-wave.
// =====================================================================
extern "C" void kernel_launch(void* const* d_in, const int* in_sizes, int n_in,
                              void* d_out, int out_size, void* d_ws, size_t ws_size,
                              hipStream_t stream) {
  (void)in_sizes; (void)n_in; (void)out_size; (void)ws_size;
  const float* obj  = (const float*)d_in[0];
  const float* grip = (const float*)d_in[1];
  const float* s1w0 = (const float*)d_in[2];
  const float* s1w1 = (const float*)d_in[3];
  const float* s1w2 = (const float*)d_in[4];
  const float* s2w0 = (const float*)d_in[5];
  const float* s2w1 = (const float*)d_in[6];
  const float* s2w2 = (const float*)d_in[7];
  const float* s3w0 = (const float*)d_in[8];
  const float* s3w1 = (const float*)d_in[9];
  const float* s3w2 = (const float*)d_in[10];
  const float* gw0  = (const float*)d_in[11];
  const float* gw1  = (const float*)d_in[12];
  const float* gw2  = (const float*)d_in[13];
  const float* hw0  = (const float*)d_in[14];
  const float* hb0  = (const float*)d_in[15];
  const float* hw1  = (const float*)d_in[16];
  const float* hb1  = (const float*)d_in[17];
  const float* hw2  = (const float*)d_in[18];
  const float* hb2  = (const float*)d_in[19];
  float* out = (float*)d_out;

  // ---- workspace layout (float offsets) ----
  float* wsf   = (float*)d_ws;
  float* stats = wsf;
  float* xyz1  = wsf + 23040;
  float* xyz2  = wsf + 35328;
  float* gfeat = wsf + 38400;
  float* x3    = wsf + 834048;
  int*   idx2  = (int*)(wsf + 1230336);
  float* bufP  = wsf + 1295872;
  float* bufQ  = wsf + 18073088;

  static const int st_off[12] = {0, 512, 1536, 2560, 3072, 3584,
                                 4608, 5632, 6656, 8704, 10752, 14848};
  auto st = [&](int li) { return stats + st_off[li]; };

  hipMemsetAsync(stats, 0, 23040 * sizeof(float), stream);

  auto gemm0 = [&](const float* X, const float* Wm, float* Y, int R, int Cin, int Cout,
                   int lo) {
    dim3 g((R + 127) / 128, (Cout + 127) / 128);
    gemm_xwt<false, false><<<g, 256, 0, stream>>>(X, Wm, Y, R, Cin, Cout, nullptr, 0,
                                                  st(lo), nullptr, 0);
  };
  auto gemmf = [&](const float* X, const float* Wm, float* Y, int R, int Cin, int Cout,
                   int li, int lo) {
    dim3 g((R + 127) / 128, (Cout + 127) / 128);
    gemm_xwt<true, false><<<g, 256, 0, stream>>>(X, Wm, Y, R, Cin, Cout, st(li), R,
                                                 st(lo), nullptr, 0);
  };
  auto gemmfM = [&](const float* X, const float* Wm, float* pooled, int R, int Cin,
                    int Cout, int li, int lo, int ns) {
    dim3 g((R + 127) / 128, (Cout + 127) / 128);
    gemm_xwt<true, true><<<g, 256, 0, stream>>>(X, Wm, nullptr, R, Cin, Cout, st(li), R,
                                                st(lo), pooled, ns);
  };
  auto applymax_k = [&](const float* Y, int li, int G, int ns, int C, float* o) {
    const int n = G * C;
    bn_apply_relu_maxpool<<<(n + 255) / 256, 256, 0, stream>>>(Y, st(li), o, G, ns, C);
  };

  // ---- SA1 FPS (R20 frozen) ----
  fps_sa1_kernel<<<8, 1024, 0, stream>>>(obj, xyz1);

  // ---- gripper encoder: 3 -> 64 -> 128 -> 128 -> maxpool ----
  float* gY1 = bufP;
  float* gY2 = bufP + 262144;
  float* gY3 = bufP + 786432;
  gemm0(grip, gw0, gY1, 4096, 3, 64, 0);
  gemmf(gY1, gw1, gY2, 4096, 64, 128, 0, 1);
  gemmf(gY2, gw2, gY3, 4096, 128, 128, 1, 2);
  applymax_k(gY3, 2, 8, 512, 128, gfeat);

  // ---- SA1: fused ballquery+group (ns=32), MLP 3->64->64->128 ----
  float* X1 = bufQ;
  ballq_group1_kernel<<<1024, 256, 0, stream>>>(xyz1, obj, X1);
  gemm0(X1, s1w0, bufP, 131072, 3, 64, 3);
  gemmf(bufP, s1w1, bufQ, 131072, 64, 64, 3, 4);
  gemmfM(bufQ, s1w2, bufP, 131072, 64, 128, 4, 5, 32);   // bufP: pooled f1-raw 4096x128

  // ---- SA2: FPS 512->128 (single wave), ball ns=64, MLP 131->128->128->256 ----
  fps2_wave_kernel<<<8, 64, 0, stream>>>(xyz1, xyz2);
  ballquery_wave_kernel<512, 64><<<256, 256, 0, stream>>>(xyz2, xyz1, idx2, 1024, 128, 0.16f);
  float* X2 = bufQ;
  group2_kernel<<<(65536 * 131 + 255) / 256, 256, 0, stream>>>(xyz1, xyz2, bufP, st(5),
                                                               idx2, X2);
  gemm0(X2, s2w0, bufP, 65536, 131, 128, 6);
  gemmf(bufP, s2w1, bufQ, 65536, 128, 128, 6, 7);
  gemmfM(bufQ, s2w2, bufP, 65536, 128, 256, 7, 8, 64);   // bufP: pooled f2-raw 1024x256

  // ---- SA3 (group_all): x3 (BN fused) -> 256 -> 512 -> 1024 -> maxpool ----
  build_x3_kernel<<<(1024 * 259 + 255) / 256, 256, 0, stream>>>(xyz2, bufP, st(8), x3);
  float* Y3a = bufQ;
  float* Y3b = bufQ + 262144;
  float* Y3p = bufQ + 786432;
  gemm0(x3, s3w0, Y3a, 1024, 259, 256, 9);
  gemmf(Y3a, s3w1, Y3b, 1024, 256, 512, 9, 10);
  gemmfM(Y3b, s3w2, Y3p, 1024, 512, 1024, 10, 11, 128);  // Y3p: pooled objf-raw 8x1024

  // ---- head (BN(objf) fused) ----
  head_kernel<<<1, 512, 0, stream>>>(gfeat, Y3p, st(11), hw0, hb0, hw1, hb1, hw2, hb2, out);
}

// Round 9
// 2325.536 us; speedup vs baseline: 1.3077x; 1.0001x over previous
//
#include <hip/hip_runtime.h>
#include <cstddef>
#include <cstdint>

#define EPS_BN 1e-5f
#define NBINS 4
#define NEG_INF (-__builtin_inff())

// =====================================================================
// Tiled fp32 GEMM:  Y[r][o] = sum_ci X'[r][ci] * W[o][ci]   (Y = X' W^T)
// 128x128 tile, BK=16, 256 threads, 8x8 microtile/thread. Validated.
// =====================================================================
template <bool FUSE_IN, bool FUSE_MAX>
__global__ __launch_bounds__(256) void gemm_xwt(const float* __restrict__ X,
                                                const float* __restrict__ Wm,
                                                float* __restrict__ Y,
                                                int R, int Cin, int Cout,
                                                const float* __restrict__ st_in, int Rin,
                                                float* __restrict__ st_out,
                                                float* __restrict__ pooled, int ns) {
  __shared__ __align__(16) float Xs[16][132];
  __shared__ __align__(16) float Ws[16][132];
  __shared__ float sMean[512], sScale[512];
  const int t  = threadIdx.x;
  const int r0 = blockIdx.x << 7;
  const int n0 = blockIdx.y << 7;
  const int tx = t & 15;
  const int ty = t >> 4;

  if constexpr (FUSE_IN) {
    const float inv = 1.f / (float)Rin;
    for (int k = t; k < Cin; k += 256) {
      float s = 0.f, q = 0.f;
#pragma unroll
      for (int bn = 0; bn < NBINS; ++bn) {
        s += st_in[bn * 2 * Cin + k];
        q += st_in[bn * 2 * Cin + Cin + k];
      }
      const float m  = s * inv;
      const float vr = fmaf(-m, m, q * inv);
      sMean[k]  = m;
      sScale[k] = rsqrtf(vr + EPS_BN);
    }
    __syncthreads();
  }

  float acc[8][8] = {};
  const int rStage = t >> 1;
  const int kBase  = (t & 1) << 3;
  const int nr     = n0 + rStage;

  for (int k0 = 0; k0 < Cin; k0 += 16) {
    const float* xrow = X  + (size_t)(r0 + rStage) * Cin + k0 + kBase;
    const float* wrow = Wm + (size_t)nr * Cin + k0 + kBase;
    if (((Cin & 3) == 0) && (k0 + 16 <= Cin)) {
      float4 xa = *(const float4*)(xrow);
      float4 xb = *(const float4*)(xrow + 4);
      if constexpr (FUSE_IN) {
        const int kb = k0 + kBase;
        xa.x = fmaxf(0.f, (xa.x - sMean[kb + 0]) * sScale[kb + 0]);
        xa.y = fmaxf(0.f, (xa.y - sMean[kb + 1]) * sScale[kb + 1]);
        xa.z = fmaxf(0.f, (xa.z - sMean[kb + 2]) * sScale[kb + 2]);
        xa.w = fmaxf(0.f, (xa.w - sMean[kb + 3]) * sScale[kb + 3]);
        xb.x = fmaxf(0.f, (xb.x - sMean[kb + 4]) * sScale[kb + 4]);
        xb.y = fmaxf(0.f, (xb.y - sMean[kb + 5]) * sScale[kb + 5]);
        xb.z = fmaxf(0.f, (xb.z - sMean[kb + 6]) * sScale[kb + 6]);
        xb.w = fmaxf(0.f, (xb.w - sMean[kb + 7]) * sScale[kb + 7]);
      }
      Xs[kBase + 0][rStage] = xa.x; Xs[kBase + 1][rStage] = xa.y;
      Xs[kBase + 2][rStage] = xa.z; Xs[kBase + 3][rStage] = xa.w;
      Xs[kBase + 4][rStage] = xb.x; Xs[kBase + 5][rStage] = xb.y;
      Xs[kBase + 6][rStage] = xb.z; Xs[kBase + 7][rStage] = xb.w;
      float4 wa = {0, 0, 0, 0}, wb = {0, 0, 0, 0};
      if (nr < Cout) { wa = *(const float4*)(wrow); wb = *(const float4*)(wrow + 4); }
      Ws[kBase + 0][rStage] = wa.x; Ws[kBase + 1][rStage] = wa.y;
      Ws[kBase + 2][rStage] = wa.z; Ws[kBase + 3][rStage] = wa.w;
      Ws[kBase + 4][rStage] = wb.x; Ws[kBase + 5][rStage] = wb.y;
      Ws[kBase + 6][rStage] = wb.z; Ws[kBase + 7][rStage] = wb.w;
    } else {
#pragma unroll
      for (int u = 0; u < 8; ++u) {
        const int k = k0 + kBase + u;
        float xe = 0.f, we = 0.f;
        if (k < Cin) {
          xe = xrow[u];
          if constexpr (FUSE_IN) xe = fmaxf(0.f, (xe - sMean[k]) * sScale[k]);
          if (nr < Cout) we = wrow[u];
        }
        Xs[kBase + u][rStage] = xe;
        Ws[kBase + u][rStage] = we;
      }
    }
    __syncthreads();
#pragma unroll
    for (int kk = 0; kk < 16; ++kk) {
      const float4 a0 = *(const float4*)(&Xs[kk][ty << 2]);
      const float4 a1 = *(const float4*)(&Xs[kk][64 + (ty << 2)]);
      const float4 b0 = *(const float4*)(&Ws[kk][tx << 2]);
      const float4 b1 = *(const float4*)(&Ws[kk][64 + (tx << 2)]);
      const float av[8] = {a0.x, a0.y, a0.z, a0.w, a1.x, a1.y, a1.z, a1.w};
      const float bw[8] = {b0.x, b0.y, b0.z, b0.w, b1.x, b1.y, b1.z, b1.w};
#pragma unroll
      for (int i = 0; i < 8; ++i)
#pragma unroll
        for (int j = 0; j < 8; ++j) acc[i][j] = fmaf(av[i], bw[j], acc[i][j]);
    }
    __syncthreads();
  }
  if constexpr (!FUSE_MAX) {
#pragma unroll
    for (int h = 0; h < 2; ++h)
#pragma unroll
      for (int i = 0; i < 4; ++i) {
        const int r = r0 + h * 64 + (ty << 2) + i;
        float* yr = Y + (size_t)r * Cout;
#pragma unroll
        for (int g = 0; g < 2; ++g) {
          const int n = n0 + g * 64 + (tx << 2);
          if (n < Cout) {
            float4 o = {acc[h * 4 + i][g * 4 + 0], acc[h * 4 + i][g * 4 + 1],
                        acc[h * 4 + i][g * 4 + 2], acc[h * 4 + i][g * 4 + 3]};
            *(float4*)(yr + n) = o;
          }
        }
      }
  }
  // stats epilogue: per-column partials -> LDS reduce -> binned atomics
#pragma unroll
  for (int g = 0; g < 2; ++g)
#pragma unroll
    for (int j = 0; j < 4; ++j) {
      float s = 0.f, q = 0.f;
#pragma unroll
      for (int rh = 0; rh < 8; ++rh) {
        const float v = acc[rh][g * 4 + j];
        s += v;
        q = fmaf(v, v, q);
      }
      Xs[ty][g * 64 + (tx << 2) + j] = s;
      Ws[ty][g * 64 + (tx << 2) + j] = q;
    }
  __syncthreads();
  if (t < 128) {
    const int n = n0 + t;
    if (n < Cout) {
      float s = 0.f, q = 0.f;
#pragma unroll
      for (int w = 0; w < 16; ++w) { s += Xs[w][t]; q += Ws[w][t]; }
      float* dst = st_out + (blockIdx.x & (NBINS - 1)) * 2 * Cout;
      atomicAdd(dst + n, s);
      atomicAdd(dst + Cout + n, q);
    }
  }
  // maxpool epilogue: ns in {32, 64, 128}
  if constexpr (FUSE_MAX) {
    __syncthreads();
    float mxAll = NEG_INF;
#pragma unroll
    for (int h = 0; h < 2; ++h) {
#pragma unroll
      for (int g2 = 0; g2 < 2; ++g2)
#pragma unroll
        for (int j = 0; j < 4; ++j) {
          float mx = acc[h * 4 + 0][g2 * 4 + j];
          mx = fmaxf(mx, acc[h * 4 + 1][g2 * 4 + j]);
          mx = fmaxf(mx, acc[h * 4 + 2][g2 * 4 + j]);
          mx = fmaxf(mx, acc[h * 4 + 3][g2 * 4 + j]);
          Xs[ty][g2 * 64 + (tx << 2) + j] = mx;
        }
      __syncthreads();
      if (t < 128) {
        const int n = n0 + t;
        if (n < Cout) {
          if (ns <= 64) {
            const int tpg = ns >> 2;
            const int gph = 64 / ns;
            for (int gq = 0; gq < gph; ++gq) {
              float mx = NEG_INF;
              for (int w = gq * tpg; w < gq * tpg + tpg; ++w) mx = fmaxf(mx, Xs[w][t]);
              const int g = (r0 + h * 64) / ns + gq;
              pooled[(size_t)g * Cout + n] = mx;
            }
          } else {
            float mx = NEG_INF;
            for (int w = 0; w < 16; ++w) mx = fmaxf(mx, Xs[w][t]);
            mxAll = fmaxf(mxAll, mx);
          }
        }
      }
      __syncthreads();
    }
    if (ns > 64 && t < 128) {
      const int n = n0 + t;
      if (n < Cout) pooled[(size_t)(r0 >> 7) * Cout + n] = mxAll;
    }
  }
}

// normalize -> relu -> max over ns rows per group (gripper path, ns=512)
__global__ void bn_apply_relu_maxpool(const float* __restrict__ Y,
                                      const float* __restrict__ st,
                                      float* __restrict__ o, int G, int ns, int C) {
  const int i = blockIdx.x * 256 + threadIdx.x;
  if (i >= G * C) return;
  const int c = i % C;
  const int g = i / C;
  float s = 0.f, q = 0.f;
#pragma unroll
  for (int bn = 0; bn < NBINS; ++bn) {
    s += st[bn * 2 * C + c];
    q += st[bn * 2 * C + C + c];
  }
  const int R = G * ns;
  const float inv = 1.f / (float)R;
  const float m  = s * inv;
  const float vr = fmaf(-m, m, q * inv);
  const float sc = rsqrtf(vr + EPS_BN);
  const float* p = Y + (size_t)g * ns * C + c;
  float mx = NEG_INF;
  for (int k = 0; k < ns; ++k) mx = fmaxf(mx, p[(size_t)k * C]);
  o[i] = fmaxf(0.f, (mx - m) * sc);
}

// =====================================================================
// FPS for SA1 (N=20000 -> 512) — R22: R20's named-scalar scan with
// amdgpu_num_vgpr(128) PINNING the register allocation. R20 measured
// VGPR=64 + no spill + FETCH ~980KB: the allocator rematerialized ~12
// groups' coords via per-step L2 loads to hit its 8-waves/EU occupancy
// target (worthless here: grid is 8 blocks on 8 CUs). launch_bounds
// min-waves and waves_per_eu hints both failed to move it; num_vgpr
// pins the allocation directly (~105 needed < 128 -> no spill, no
// remat). If the attribute is ignored, codegen stays at R20 (1348 us):
// asymmetric bet, no regression path.
// Step semantics bit-identical to R5/R20 (absmax 0.0 every round).
// =====================================================================
#define REP20(X) X(0) X(1) X(2) X(3) X(4) X(5) X(6) X(7) X(8) X(9) \
                 X(10) X(11) X(12) X(13) X(14) X(15) X(16) X(17) X(18) X(19)

__global__ __launch_bounds__(1024)
__attribute__((amdgpu_waves_per_eu(4, 4), amdgpu_num_vgpr(128)))
void fps_sa1_kernel(const float* __restrict__ xyz, float* __restrict__ new_xyz) {
  const int b    = blockIdx.x;
  const int tid  = threadIdx.x;
  const int lane = tid & 63;
  const int wave = tid >> 6;  // 0..15
  const float* p = xyz + (size_t)b * 20000 * 3;

  __shared__ float sv[16], sx[16], sy[16], sz[16];
  __shared__ int   si[16];
  __shared__ float bc[3];

#define DECLR(k) float px##k, py##k, pz##k, dd##k;
  REP20(DECLR)
#undef DECLR

#define INITR(k) {                                                          \
    const int i = tid + ((k) << 10);                                        \
    if (i < 20000) {                                                        \
      px##k = p[i * 3 + 0]; py##k = p[i * 3 + 1]; pz##k = p[i * 3 + 2];     \
      dd##k = 1e10f;                                                        \
    } else {                                                                \
      px##k = 0.f; py##k = 0.f; pz##k = 0.f;                                \
      dd##k = NEG_INF;                                                      \
    } }
  REP20(INITR)
#undef INITR

  float fx = p[0], fy = p[1], fz = p[2];
  if (tid == 0) {
    float* o = new_xyz + (size_t)b * 512 * 3;
    o[0] = fx; o[1] = fy; o[2] = fz;
  }
  __syncthreads();

  for (int s = 1; s < 512; ++s) {
    float bv = NEG_INF;
    int   bi = 0x7fffffff;
    float bx = 0.f, by = 0.f, bz = 0.f;
#define SCANR(k) {                                                          \
    const float dx = px##k - fx, dy = py##k - fy, dz = pz##k - fz;          \
    const float d  = __fadd_rn(__fadd_rn(__fmul_rn(dx, dx), __fmul_rn(dy, dy)), \
                               __fmul_rn(dz, dz));                          \
    const float nd = fminf(dd##k, d);                                       \
    dd##k = nd;                                                             \
    if (nd > bv) { bv = nd; bi = tid + ((k) << 10);                         \
                   bx = px##k; by = py##k; bz = pz##k; } }
    REP20(SCANR)
#undef SCANR
    float v  = bv;
    int   i0 = bi;
#pragma unroll
    for (int m = 1; m < 64; m <<= 1) {
      const float ov = __shfl_xor(v, m, 64);
      const int   oi = __shfl_xor(i0, m, 64);
      if (ov > v || (ov == v && oi < i0)) { v = ov; i0 = oi; }
    }
    if (i0 == bi) {  // unique owner lane of this wave's winner
      sv[wave] = bv; si[wave] = bi; sx[wave] = bx; sy[wave] = by; sz[wave] = bz;
    }
    __syncthreads();
    if (tid < 64) {
      const float lv = (lane < 16) ? sv[lane] : NEG_INF;
      const int   li = (lane < 16) ? si[lane] : 0x7fffffff;
      float v2 = lv;
      int   i2 = li;
#pragma unroll
      for (int m = 1; m < 16; m <<= 1) {
        const float ov = __shfl_xor(v2, m, 64);
        const int   oi = __shfl_xor(i2, m, 64);
        if (ov > v2 || (ov == v2 && oi < i2)) { v2 = ov; i2 = oi; }
      }
      if (lane < 16 && li == i2) {  // unique global owner
        const float wx = sx[lane], wy = sy[lane], wz = sz[lane];
        bc[0] = wx; bc[1] = wy; bc[2] = wz;
        float* o = new_xyz + ((size_t)b * 512 + s) * 3;
        o[0] = wx; o[1] = wy; o[2] = wz;
      }
    }
    __syncthreads();
    fx = bc[0]; fy = bc[1]; fz = bc[2];
  }
}

// =====================================================================
// FPS small (SA2: 512 -> 128) — single wave, zero barriers (R21).
// =====================================================================
__global__ __launch_bounds__(64)
void fps2_wave_kernel(const float* __restrict__ xyz, float* __restrict__ new_xyz) {
  const int b    = blockIdx.x;
  const int lane = threadIdx.x;
  const float* p = xyz + (size_t)b * 512 * 3;
  float px[8], py[8], pz[8], dd[8];
#pragma unroll
  for (int j = 0; j < 8; ++j) {
    const int i = lane + (j << 6);
    px[j] = p[i * 3 + 0]; py[j] = p[i * 3 + 1]; pz[j] = p[i * 3 + 2];
    dd[j] = 1e10f;
  }
  float fx = p[0], fy = p[1], fz = p[2];
  if (lane == 0) {
    float* o = new_xyz + (size_t)b * 128 * 3;
    o[0] = fx; o[1] = fy; o[2] = fz;
  }
  for (int s = 1; s < 128; ++s) {
    float bv = NEG_INF;
    int   bi = 0x7fffffff;
    float bx = 0.f, by = 0.f, bz = 0.f;
#pragma unroll
    for (int j = 0; j < 8; ++j) {
      const float dx = px[j] - fx, dy = py[j] - fy, dz = pz[j] - fz;
      const float d  = __fadd_rn(__fadd_rn(__fmul_rn(dx, dx), __fmul_rn(dy, dy)),
                                 __fmul_rn(dz, dz));
      const float nd = fminf(dd[j], d);
      dd[j] = nd;
      if (nd > bv) { bv = nd; bi = lane + (j << 6); bx = px[j]; by = py[j]; bz = pz[j]; }
    }
    float v = bv; int i0 = bi;
    float wx = bx, wy = by, wz = bz;
#pragma unroll
    for (int m = 1; m < 64; m <<= 1) {
      const float ov = __shfl_xor(v, m, 64);
      const int   oi = __shfl_xor(i0, m, 64);
      const float ox = __shfl_xor(wx, m, 64);
      const float oy = __shfl_xor(wy, m, 64);
      const float oz = __shfl_xor(wz, m, 64);
      if (ov > v || (ov == v && oi < i0)) { v = ov; i0 = oi; wx = ox; wy = oy; wz = oz; }
    }
    fx = wx; fy = wy; fz = wz;  // converged on all lanes
    if (lane == 0) {
      float* o = new_xyz + ((size_t)b * 128 + s) * 3;
      o[0] = fx; o[1] = fy; o[2] = fz;
    }
  }
}

// =====================================================================
// Ball query (SA2): ONE WAVE PER CENTER, ballot + prefix-popcount.
// =====================================================================
template <int N, int NS>
__global__ __launch_bounds__(256)
void ballquery_wave_kernel(const float* __restrict__ centers,
                           const float* __restrict__ pts,
                           int* __restrict__ idx, int BS, int S, float r2) {
  const int w    = (blockIdx.x * 256 + threadIdx.x) >> 6;
  const int lane = threadIdx.x & 63;
  if (w >= BS) return;
  const int b = w / S;
  const float cx = centers[w * 3 + 0];
  const float cy = centers[w * 3 + 1];
  const float cz = centers[w * 3 + 2];
  const float* p = pts + (size_t)b * N * 3;
  int* o = idx + (size_t)w * NS;
  int total = 0;
  int first = -1;
  for (int i0 = 0; i0 < N && total < NS; i0 += 64) {
    const int i = i0 + lane;
    bool pred = false;
    if (i < N) {
      const float dx = cx - p[i * 3 + 0];
      const float dy = cy - p[i * 3 + 1];
      const float dz = cz - p[i * 3 + 2];
      const float d2 = __fadd_rn(__fadd_rn(__fmul_rn(dx, dx), __fmul_rn(dy, dy)),
                                 __fmul_rn(dz, dz));
      pred = (d2 < r2);
    }
    const unsigned long long mask = __ballot(pred);
    if (mask) {
      const unsigned long long below = (lane == 0) ? 0ull : (mask << (64 - lane));
      const int before = __popcll(below);
      if (pred && (total + before) < NS) o[total + before] = i;
      if (first < 0) first = i0 + (__ffsll((long long)mask) - 1);
      total += __popcll(mask);
    }
  }
  if (lane >= total && lane < NS) o[lane] = first;
}

// =====================================================================
// Fused ballquery(SA1, r=0.2, ns=32) + group1 (R21, validated).
// =====================================================================
__global__ __launch_bounds__(256)
void ballq_group1_kernel(const float* __restrict__ centers,  // xyz1 [8,512,3]
                         const float* __restrict__ pts,      // obj  [8,20000,3]
                         float* __restrict__ X1) {           // [8*512*32,3]
  __shared__ int sIdx[4][32];
  const int wIn  = threadIdx.x >> 6;
  const int w    = (blockIdx.x * 256 + threadIdx.x) >> 6;
  const int lane = threadIdx.x & 63;
  if (w >= 4096) return;
  const int b = w >> 9;
  const float cx = centers[w * 3 + 0];
  const float cy = centers[w * 3 + 1];
  const float cz = centers[w * 3 + 2];
  const float* p = pts + (size_t)b * 20000 * 3;
  int total = 0;
  int first = -1;
  for (int i0 = 0; i0 < 20000 && total < 32; i0 += 64) {
    const int i = i0 + lane;
    bool pred = false;
    if (i < 20000) {
      const float dx = cx - p[i * 3 + 0];
      const float dy = cy - p[i * 3 + 1];
      const float dz = cz - p[i * 3 + 2];
      const float d2 = __fadd_rn(__fadd_rn(__fmul_rn(dx, dx), __fmul_rn(dy, dy)),
                                 __fmul_rn(dz, dz));
      pred = (d2 < 0.04f);
    }
    const unsigned long long mask = __ballot(pred);
    if (mask) {
      const unsigned long long below = (lane == 0) ? 0ull : (mask << (64 - lane));
      const int before = __popcll(below);
      if (pred && (total + before) < 32) sIdx[wIn][total + before] = i;
      if (first < 0) first = i0 + (__ffsll((long long)mask) - 1);
      total += __popcll(mask);
    }
  }
  __builtin_amdgcn_wave_barrier();  // scheduling fence: LDS writes before reads
  if (lane < 32) {
    const int i = (lane < total) ? sIdx[wIn][lane] : first;
    const float* q = p + (size_t)i * 3;
    float* o = X1 + ((size_t)w * 32 + lane) * 3;
    o[0] = (q[0] - cx) / 0.2f;
    o[1] = (q[1] - cy) / 0.2f;
    o[2] = (q[2] - cz) / 0.2f;
  }
}

// =====================================================================
// group2 with BN(f1) fused (R21, validated).
// =====================================================================
__global__ __launch_bounds__(256)
void group2_kernel(const float* __restrict__ xyz1,
                   const float* __restrict__ xyz2,
                   const float* __restrict__ P1,
                   const float* __restrict__ st,
                   const int* __restrict__ idx2,
                   float* __restrict__ X2) {
  __shared__ float sM[128], sS[128];
  const int t0 = threadIdx.x;
  if (t0 < 128) {
    float s = 0.f, q = 0.f;
#pragma unroll
    for (int bn = 0; bn < NBINS; ++bn) {
      s += st[bn * 256 + t0];
      q += st[bn * 256 + 128 + t0];
    }
    const float inv = 1.f / 131072.f;
    const float m  = s * inv;
    const float vr = fmaf(-m, m, q * inv);
    sM[t0] = m;
    sS[t0] = rsqrtf(vr + EPS_BN);
  }
  __syncthreads();
  const int t = blockIdx.x * 256 + t0;
  if (t >= 65536 * 131) return;
  const int r = t / 131;
  const int c = t - r * 131;
  const int g = r >> 6;
  const int b = g >> 7;
  const int i = idx2[r];
  float v;
  if (c < 3) {
    v = (xyz1[((size_t)b * 512 + i) * 3 + c] - xyz2[(size_t)g * 3 + c]) / 0.4f;
  } else {
    const int cc = c - 3;
    v = P1[((size_t)b * 512 + i) * 128 + cc];
    v = fmaxf(0.f, (v - sM[cc]) * sS[cc]);
  }
  X2[t] = v;
}

// =====================================================================
// build_x3 with BN(f2) fused (R21, validated).
// =====================================================================
__global__ __launch_bounds__(256)
void build_x3_kernel(const float* __restrict__ xyz2, const float* __restrict__ P2,
                     const float* __restrict__ st, float* __restrict__ X3) {
  __shared__ float sM[256], sS[256];
  const int t0 = threadIdx.x;
  {
    float s = 0.f, q = 0.f;
#pragma unroll
    for (int bn = 0; bn < NBINS; ++bn) {
      s += st[bn * 512 + t0];
      q += st[bn * 512 + 256 + t0];
    }
    const float inv = 1.f / 65536.f;
    const float m  = s * inv;
    const float vr = fmaf(-m, m, q * inv);
    sM[t0] = m;
    sS[t0] = rsqrtf(vr + EPS_BN);
  }
  __syncthreads();
  const int t = blockIdx.x * 256 + t0;
  if (t >= 1024 * 259) return;
  const int r = t / 259;
  const int c = t - r * 259;
  float v;
  if (c < 3) {
    v = xyz2[r * 3 + c];
  } else {
    const int cc = c - 3;
    v = P2[(size_t)r * 256 + cc];
    v = fmaxf(0.f, (v - sM[cc]) * sS[cc]);
  }
  X3[t] = v;
}

// =====================================================================
// Fused head — BN(objf) inlined into comb load (R21, validated).
// =====================================================================
__global__ __launch_bounds__(512) void head_kernel(
    const float* __restrict__ gfeat, const float* __restrict__ Y3p,
    const float* __restrict__ st11,
    const float* __restrict__ w0, const float* __restrict__ b0,
    const float* __restrict__ w1, const float* __restrict__ b1,
    const float* __restrict__ w2, const float* __restrict__ b2,
    float* __restrict__ out) {
  __shared__ __align__(16) float comb[8 * 1152];
  __shared__ __align__(16) float h1[8 * 512];
  __shared__ __align__(16) float h2[8 * 256];
  const int tid = threadIdx.x;
  for (int i = tid; i < 8 * 1152; i += 512) {
    const int b = i / 1152, c = i - b * 1152;
    float v;
    if (c < 128) {
      v = gfeat[b * 128 + c];
    } else {
      const int cc = c - 128;
      float s = 0.f, q = 0.f;
#pragma unroll
      for (int bn = 0; bn < NBINS; ++bn) {
        s += st11[bn * 2048 + cc];
        q += st11[bn * 2048 + 1024 + cc];
      }
      const float inv = 1.f / 1024.f;
      const float m  = s * inv;
      const float vr = fmaf(-m, m, q * inv);
      const float sc = rsqrtf(vr + EPS_BN);
      v = fmaxf(0.f, (Y3p[b * 1024 + cc] - m) * sc);
    }
    comb[i] = v;
  }
  __syncthreads();
  for (int c = tid; c < 1152; c += 512) {
    float s = 0.f;
#pragma unroll
    for (int b = 0; b < 8; ++b) s += comb[b * 1152 + c];
    const float m = s * 0.125f;
    float v = 0.f;
#pragma unroll
    for (int b = 0; b < 8; ++b) { const float d = comb[b * 1152 + c] - m; v = fmaf(d, d, v); }
    const float sc = rsqrtf(v * 0.125f + EPS_BN);
#pragma unroll
    for (int b = 0; b < 8; ++b) comb[b * 1152 + c] = (comb[b * 1152 + c] - m) * sc;
  }
  __syncthreads();
  {  // layer 0: 1152 -> 512
    float a[8];
#pragma unroll
    for (int b = 0; b < 8; ++b) a[b] = b0[tid];
    const float* wr = w0 + (size_t)tid * 1152;
    for (int ci = 0; ci < 1152; ci += 4) {
      const float4 wv = *(const float4*)(wr + ci);
#pragma unroll
      for (int b = 0; b < 8; ++b) {
        const float4 xv = *(const float4*)(&comb[b * 1152 + ci]);
        a[b] = fmaf(xv.x, wv.x, a[b]);
        a[b] = fmaf(xv.y, wv.y, a[b]);
        a[b] = fmaf(xv.z, wv.z, a[b]);
        a[b] = fmaf(xv.w, wv.w, a[b]);
      }
    }
    float s = 0.f;
#pragma unroll
    for (int b = 0; b < 8; ++b) s += a[b];
    const float m = s * 0.125f;
    float v = 0.f;
#pragma unroll
    for (int b = 0; b < 8; ++b) { const float d = a[b] - m; v = fmaf(d, d, v); }
    const float sc = rsqrtf(v * 0.125f + EPS_BN);
#pragma unroll
    for (int b = 0; b < 8; ++b) h1[b * 512 + tid] = fmaxf(0.f, (a[b] - m) * sc);
  }
  __syncthreads();
  if (tid < 256) {  // layer 1: 512 -> 256
    float a[8];
#pragma unroll
    for (int b = 0; b < 8; ++b) a[b] = b1[tid];
    const float* wr = w1 + (size_t)tid * 512;
    for (int ci = 0; ci < 512; ci += 4) {
      const float4 wv = *(const float4*)(wr + ci);
#pragma unroll
      for (int b = 0; b < 8; ++b) {
        const float4 xv = *(const float4*)(&h1[b * 512 + ci]);
        a[b] = fmaf(xv.x, wv.x, a[b]);
        a[b] = fmaf(xv.y, wv.y, a[b]);
        a[b] = fmaf(xv.z, wv.z, a[b]);
        a[b] = fmaf(xv.w, wv.w, a[b]);
      }
    }
    float s = 0.f;
#pragma unroll
    for (int b = 0; b < 8; ++b) s += a[b];
    const float m = s * 0.125f;
    float v = 0.f;
#pragma unroll
    for (int b = 0; b < 8; ++b) { const float d = a[b] - m; v = fmaf(d, d, v); }
    const float sc = rsqrtf(v * 0.125f + EPS_BN);
#pragma unroll
    for (int b = 0; b < 8; ++b) h2[b * 256 + tid] = fmaxf(0.f, (a[b] - m) * sc);
  }
  __syncthreads();
  if (tid < 8) {  // layer 2: 256 -> 1, relu
    float s = b2[0];
    for (int ci = 0; ci < 256; ++ci) s = fmaf(h2[tid * 256 + ci], w2[ci], s);
    out[tid] = fmaxf(0.f, s);
  }
}

// =====================================================================
// Host orchestration — R21 structure (validated), FPS with num_vgpr pin.
// =====================================================================
extern "C" void kernel_launch(void* const* d_in, const int* in_sizes, int n_in,
                              void* d_out, int out_size, void* d_ws, size_t ws_size,
                              hipStream_t stream) {
  (void)in_sizes; (void)n_in; (void)out_size; (void)ws_size;
  const float* obj  = (const float*)d_in[0];
  const float* grip = (const float*)d_in[1];
  const float* s1w0 = (const float*)d_in[2];
  const float* s1w1 = (const float*)d_in[3];
  const float* s1w2 = (const float*)d_in[4];
  const float* s2w0 = (const float*)d_in[5];
  const float* s2w1 = (const float*)d_in[6];
  const float* s2w2 = (const float*)d_in[7];
  const float* s3w0 = (const float*)d_in[8];
  const float* s3w1 = (const float*)d_in[9];
  const float* s3w2 = (const float*)d_in[10];
  const float* gw0  = (const float*)d_in[11];
  const float* gw1  = (const float*)d_in[12];
  const float* gw2  = (const float*)d_in[13];
  const float* hw0  = (const float*)d_in[14];
  const float* hb0  = (const float*)d_in[15];
  const float* hw1  = (const float*)d_in[16];
  const float* hb1  = (const float*)d_in[17];
  const float* hw2  = (const float*)d_in[18];
  const float* hb2  = (const float*)d_in[19];
  float* out = (float*)d_out;

  // ---- workspace layout (float offsets) ----
  float* wsf   = (float*)d_ws;
  float* stats = wsf;
  float* xyz1  = wsf + 23040;
  float* xyz2  = wsf + 35328;
  float* gfeat = wsf + 38400;
  float* x3    = wsf + 834048;
  int*   idx2  = (int*)(wsf + 1230336);
  float* bufP  = wsf + 1295872;
  float* bufQ  = wsf + 18073088;

  static const int st_off[12] = {0, 512, 1536, 2560, 3072, 3584,
                                 4608, 5632, 6656, 8704, 10752, 14848};
  auto st = [&](int li) { return stats + st_off[li]; };

  hipMemsetAsync(stats, 0, 23040 * sizeof(float), stream);

  auto gemm0 = [&](const float* X, const float* Wm, float* Y, int R, int Cin, int Cout,
                   int lo) {
    dim3 g((R + 127) / 128, (Cout + 127) / 128);
    gemm_xwt<false, false><<<g, 256, 0, stream>>>(X, Wm, Y, R, Cin, Cout, nullptr, 0,
                                                  st(lo), nullptr, 0);
  };
  auto gemmf = [&](const float* X, const float* Wm, float* Y, int R, int Cin, int Cout,
                   int li, int lo) {
    dim3 g((R + 127) / 128, (Cout + 127) / 128);
    gemm_xwt<true, false><<<g, 256, 0, stream>>>(X, Wm, Y, R, Cin, Cout, st(li), R,
                                                 st(lo), nullptr, 0);
  };
  auto gemmfM = [&](const float* X, const float* Wm, float* pooled, int R, int Cin,
                    int Cout, int li, int lo, int ns) {
    dim3 g((R + 127) / 128, (Cout + 127) / 128);
    gemm_xwt<true, true><<<g, 256, 0, stream>>>(X, Wm, nullptr, R, Cin, Cout, st(li), R,
                                                st(lo), pooled, ns);
  };
  auto applymax_k = [&](const float* Y, int li, int G, int ns, int C, float* o) {
    const int n = G * C;
    bn_apply_relu_maxpool<<<(n + 255) / 256, 256, 0, stream>>>(Y, st(li), o, G, ns, C);
  };

  // ---- SA1 FPS (R22: num_vgpr(128) pin) ----
  fps_sa1_kernel<<<8, 1024, 0, stream>>>(obj, xyz1);

  // ---- gripper encoder: 3 -> 64 -> 128 -> 128 -> maxpool ----
  float* gY1 = bufP;
  float* gY2 = bufP + 262144;
  float* gY3 = bufP + 786432;
  gemm0(grip, gw0, gY1, 4096, 3, 64, 0);
  gemmf(gY1, gw1, gY2, 4096, 64, 128, 0, 1);
  gemmf(gY2, gw2, gY3, 4096, 128, 128, 1, 2);
  applymax_k(gY3, 2, 8, 512, 128, gfeat);

  // ---- SA1: fused ballquery+group (ns=32), MLP 3->64->64->128 ----
  float* X1 = bufQ;
  ballq_group1_kernel<<<1024, 256, 0, stream>>>(xyz1, obj, X1);
  gemm0(X1, s1w0, bufP, 131072, 3, 64, 3);
  gemmf(bufP, s1w1, bufQ, 131072, 64, 64, 3, 4);
  gemmfM(bufQ, s1w2, bufP, 131072, 64, 128, 4, 5, 32);   // bufP: pooled f1-raw 4096x128

  // ---- SA2: FPS 512->128 (single wave), ball ns=64, MLP 131->128->128->256 ----
  fps2_wave_kernel<<<8, 64, 0, stream>>>(xyz1, xyz2);
  ballquery_wave_kernel<512, 64><<<256, 256, 0, stream>>>(xyz2, xyz1, idx2, 1024, 128, 0.16f);
  float* X2 = bufQ;
  group2_kernel<<<(65536 * 131 + 255) / 256, 256, 0, stream>>>(xyz1, xyz2, bufP, st(5),
                                                               idx2, X2);
  gemm0(X2, s2w0, bufP, 65536, 131, 128, 6);
  gemmf(bufP, s2w1, bufQ, 65536, 128, 128, 6, 7);
  gemmfM(bufQ, s2w2, bufP, 65536, 128, 256, 7, 8, 64);   // bufP: pooled f2-raw 1024x256

  // ---- SA3 (group_all): x3 (BN fused) -> 256 -> 512 -> 1024 -> maxpool ----
  build_x3_kernel<<<(1024 * 259 + 255) / 256, 256, 0, stream>>>(xyz2, bufP, st(8), x3);
  float* Y3a = bufQ;
  float* Y3b = bufQ + 262144;
  float* Y3p = bufQ + 786432;
  gemm0(x3, s3w0, Y3a, 1024, 259, 256, 9);
  gemmf(Y3a, s3w1, Y3b, 1024, 256, 512, 9, 10);
  gemmfM(Y3b, s3w2, Y3p, 1024, 512, 1024, 10, 11, 128);  // Y3p: pooled objf-raw 8x1024

  // ---- head (BN(objf) fused) ----
  head_kernel<<<1, 512, 0, stream>>>(gfeat, Y3p, st(11), hw0, hb0, hw1, hb1, hw2, hb2, out);
}

// Round 11
// 2289.423 us; speedup vs baseline: 1.3283x; 1.0158x over previous
//
#include <hip/hip_runtime.h>
#include <cstddef>
#include <cstdint>

#define EPS_BN 1e-5f
#define NBINS 4
#define NEG_INF (-__builtin_inff())

// =====================================================================
// Tiled fp32 GEMM:  Y[r][o] = sum_ci X'[r][ci] * W[o][ci]   (Y = X' W^T)
// 128x128 tile, BK=16, 256 threads, 8x8 microtile/thread. Validated.
// =====================================================================
template <bool FUSE_IN, bool FUSE_MAX>
__global__ __launch_bounds__(256) void gemm_xwt(const float* __restrict__ X,
                                                const float* __restrict__ Wm,
                                                float* __restrict__ Y,
                                                int R, int Cin, int Cout,
                                                const float* __restrict__ st_in, int Rin,
                                                float* __restrict__ st_out,
                                                float* __restrict__ pooled, int ns) {
  __shared__ __align__(16) float Xs[16][132];
  __shared__ __align__(16) float Ws[16][132];
  __shared__ float sMean[512], sScale[512];
  const int t  = threadIdx.x;
  const int r0 = blockIdx.x << 7;
  const int n0 = blockIdx.y << 7;
  const int tx = t & 15;
  const int ty = t >> 4;

  if constexpr (FUSE_IN) {
    const float inv = 1.f / (float)Rin;
    for (int k = t; k < Cin; k += 256) {
      float s = 0.f, q = 0.f;
#pragma unroll
      for (int bn = 0; bn < NBINS; ++bn) {
        s += st_in[bn * 2 * Cin + k];
        q += st_in[bn * 2 * Cin + Cin + k];
      }
      const float m  = s * inv;
      const float vr = fmaf(-m, m, q * inv);
      sMean[k]  = m;
      sScale[k] = rsqrtf(vr + EPS_BN);
    }
    __syncthreads();
  }

  float acc[8][8] = {};
  const int rStage = t >> 1;
  const int kBase  = (t & 1) << 3;
  const int nr     = n0 + rStage;

  for (int k0 = 0; k0 < Cin; k0 += 16) {
    const float* xrow = X  + (size_t)(r0 + rStage) * Cin + k0 + kBase;
    const float* wrow = Wm + (size_t)nr * Cin + k0 + kBase;
    if (((Cin & 3) == 0) && (k0 + 16 <= Cin)) {
      float4 xa = *(const float4*)(xrow);
      float4 xb = *(const float4*)(xrow + 4);
      if constexpr (FUSE_IN) {
        const int kb = k0 + kBase;
        xa.x = fmaxf(0.f, (xa.x - sMean[kb + 0]) * sScale[kb + 0]);
        xa.y = fmaxf(0.f, (xa.y - sMean[kb + 1]) * sScale[kb + 1]);
        xa.z = fmaxf(0.f, (xa.z - sMean[kb + 2]) * sScale[kb + 2]);
        xa.w = fmaxf(0.f, (xa.w - sMean[kb + 3]) * sScale[kb + 3]);
        xb.x = fmaxf(0.f, (xb.x - sMean[kb + 4]) * sScale[kb + 4]);
        xb.y = fmaxf(0.f, (xb.y - sMean[kb + 5]) * sScale[kb + 5]);
        xb.z = fmaxf(0.f, (xb.z - sMean[kb + 6]) * sScale[kb + 6]);
        xb.w = fmaxf(0.f, (xb.w - sMean[kb + 7]) * sScale[kb + 7]);
      }
      Xs[kBase + 0][rStage] = xa.x; Xs[kBase + 1][rStage] = xa.y;
      Xs[kBase + 2][rStage] = xa.z; Xs[kBase + 3][rStage] = xa.w;
      Xs[kBase + 4][rStage] = xb.x; Xs[kBase + 5][rStage] = xb.y;
      Xs[kBase + 6][rStage] = xb.z; Xs[kBase + 7][rStage] = xb.w;
      float4 wa = {0, 0, 0, 0}, wb = {0, 0, 0, 0};
      if (nr < Cout) { wa = *(const float4*)(wrow); wb = *(const float4*)(wrow + 4); }
      Ws[kBase + 0][rStage] = wa.x; Ws[kBase + 1][rStage] = wa.y;
      Ws[kBase + 2][rStage] = wa.z; Ws[kBase + 3][rStage] = wa.w;
      Ws[kBase + 4][rStage] = wb.x; Ws[kBase + 5][rStage] = wb.y;
      Ws[kBase + 6][rStage] = wb.z; Ws[kBase + 7][rStage] = wb.w;
    } else {
#pragma unroll
      for (int u = 0; u < 8; ++u) {
        const int k = k0 + kBase + u;
        float xe = 0.f, we = 0.f;
        if (k < Cin) {
          xe = xrow[u];
          if constexpr (FUSE_IN) xe = fmaxf(0.f, (xe - sMean[k]) * sScale[k]);
          if (nr < Cout) we = wrow[u];
        }
        Xs[kBase + u][rStage] = xe;
        Ws[kBase + u][rStage] = we;
      }
    }
    __syncthreads();
#pragma unroll
    for (int kk = 0; kk < 16; ++kk) {
      const float4 a0 = *(const float4*)(&Xs[kk][ty << 2]);
      const float4 a1 = *(const float4*)(&Xs[kk][64 + (ty << 2)]);
      const float4 b0 = *(const float4*)(&Ws[kk][tx << 2]);
      const float4 b1 = *(const float4*)(&Ws[kk][64 + (tx << 2)]);
      const float av[8] = {a0.x, a0.y, a0.z, a0.w, a1.x, a1.y, a1.z, a1.w};
      const float bw[8] = {b0.x, b0.y, b0.z, b0.w, b1.x, b1.y, b1.z, b1.w};
#pragma unroll
      for (int i = 0; i < 8; ++i)
#pragma unroll
        for (int j = 0; j < 8; ++j) acc[i][j] = fmaf(av[i], bw[j], acc[i][j]);
    }
    __syncthreads();
  }
  if constexpr (!FUSE_MAX) {
#pragma unroll
    for (int h = 0; h < 2; ++h)
#pragma unroll
      for (int i = 0; i < 4; ++i) {
        const int r = r0 + h * 64 + (ty << 2) + i;
        float* yr = Y + (size_t)r * Cout;
#pragma unroll
        for (int g = 0; g < 2; ++g) {
          const int n = n0 + g * 64 + (tx << 2);
          if (n < Cout) {
            float4 o = {acc[h * 4 + i][g * 4 + 0], acc[h * 4 + i][g * 4 + 1],
                        acc[h * 4 + i][g * 4 + 2], acc[h * 4 + i][g * 4 + 3]};
            *(float4*)(yr + n) = o;
          }
        }
      }
  }
  // stats epilogue: per-column partials -> LDS reduce -> binned atomics
#pragma unroll
  for (int g = 0; g < 2; ++g)
#pragma unroll
    for (int j = 0; j < 4; ++j) {
      float s = 0.f, q = 0.f;
#pragma unroll
      for (int rh = 0; rh < 8; ++rh) {
        const float v = acc[rh][g * 4 + j];
        s += v;
        q = fmaf(v, v, q);
      }
      Xs[ty][g * 64 + (tx << 2) + j] = s;
      Ws[ty][g * 64 + (tx << 2) + j] = q;
    }
  __syncthreads();
  if (t < 128) {
    const int n = n0 + t;
    if (n < Cout) {
      float s = 0.f, q = 0.f;
#pragma unroll
      for (int w = 0; w < 16; ++w) { s += Xs[w][t]; q += Ws[w][t]; }
      float* dst = st_out + (blockIdx.x & (NBINS - 1)) * 2 * Cout;
      atomicAdd(dst + n, s);
      atomicAdd(dst + Cout + n, q);
    }
  }
  // maxpool epilogue: ns in {32, 64, 128}
  if constexpr (FUSE_MAX) {
    __syncthreads();
    float mxAll = NEG_INF;
#pragma unroll
    for (int h = 0; h < 2; ++h) {
#pragma unroll
      for (int g2 = 0; g2 < 2; ++g2)
#pragma unroll
        for (int j = 0; j < 4; ++j) {
          float mx = acc[h * 4 + 0][g2 * 4 + j];
          mx = fmaxf(mx, acc[h * 4 + 1][g2 * 4 + j]);
          mx = fmaxf(mx, acc[h * 4 + 2][g2 * 4 + j]);
          mx = fmaxf(mx, acc[h * 4 + 3][g2 * 4 + j]);
          Xs[ty][g2 * 64 + (tx << 2) + j] = mx;
        }
      __syncthreads();
      if (t < 128) {
        const int n = n0 + t;
        if (n < Cout) {
          if (ns <= 64) {
            const int tpg = ns >> 2;
            const int gph = 64 / ns;
            for (int gq = 0; gq < gph; ++gq) {
              float mx = NEG_INF;
              for (int w = gq * tpg; w < gq * tpg + tpg; ++w) mx = fmaxf(mx, Xs[w][t]);
              const int g = (r0 + h * 64) / ns + gq;
              pooled[(size_t)g * Cout + n] = mx;
            }
          } else {
            float mx = NEG_INF;
            for (int w = 0; w < 16; ++w) mx = fmaxf(mx, Xs[w][t]);
            mxAll = fmaxf(mxAll, mx);
          }
        }
      }
      __syncthreads();
    }
    if (ns > 64 && t < 128) {
      const int n = n0 + t;
      if (n < Cout) pooled[(size_t)(r0 >> 7) * Cout + n] = mxAll;
    }
  }
}

// normalize -> relu -> max over ns rows per group (gripper path, ns=512)
__global__ void bn_apply_relu_maxpool(const float* __restrict__ Y,
                                      const float* __restrict__ st,
                                      float* __restrict__ o, int G, int ns, int C) {
  const int i = blockIdx.x * 256 + threadIdx.x;
  if (i >= G * C) return;
  const int c = i % C;
  const int g = i / C;
  float s = 0.f, q = 0.f;
#pragma unroll
  for (int bn = 0; bn < NBINS; ++bn) {
    s += st[bn * 2 * C + c];
    q += st[bn * 2 * C + C + c];
  }
  const int R = G * ns;
  const float inv = 1.f / (float)R;
  const float m  = s * inv;
  const float vr = fmaf(-m, m, q * inv);
  const float sc = rsqrtf(vr + EPS_BN);
  const float* p = Y + (size_t)g * ns * C + c;
  float mx = NEG_INF;
  for (int k = 0; k < ns; ++k) mx = fmaxf(mx, p[(size_t)k * C]);
  o[i] = fmaxf(0.f, (mx - m) * sc);
}

// =====================================================================
// FPS for SA1 (N=20000 -> 512) — R23 (resubmit; R10 bench was an infra
// failure): R20/R22 scan with the per-group COORDINATE cndmask tracking
// removed (3 of 5 conditional updates per group, 60 instr/thread/step).
// The winner's coords are instead read once from p[i2*3..] in the
// wave-0 serial section after the cross-wave reduce — identical source
// values, so output is bit-exact. Selection chain (nd, bi) untouched.
// Register axis closed (VGPR ceiling 64 is toolchain-clamped).
// =====================================================================
#define REP20(X) X(0) X(1) X(2) X(3) X(4) X(5) X(6) X(7) X(8) X(9) \
                 X(10) X(11) X(12) X(13) X(14) X(15) X(16) X(17) X(18) X(19)

__global__ __launch_bounds__(1024)
__attribute__((amdgpu_waves_per_eu(4, 4), amdgpu_num_vgpr(128)))
void fps_sa1_kernel(const float* __restrict__ xyz, float* __restrict__ new_xyz) {
  const int b    = blockIdx.x;
  const int tid  = threadIdx.x;
  const int lane = tid & 63;
  const int wave = tid >> 6;  // 0..15
  const float* p = xyz + (size_t)b * 20000 * 3;

  __shared__ float sv[16];
  __shared__ int   si[16];
  __shared__ float bc[3];

#define DECLR(k) float px##k, py##k, pz##k, dd##k;
  REP20(DECLR)
#undef DECLR

#define INITR(k) {                                                          \
    const int i = tid + ((k) << 10);                                        \
    if (i < 20000) {                                                        \
      px##k = p[i * 3 + 0]; py##k = p[i * 3 + 1]; pz##k = p[i * 3 + 2];     \
      dd##k = 1e10f;                                                        \
    } else {                                                                \
      px##k = 0.f; py##k = 0.f; pz##k = 0.f;                                \
      dd##k = NEG_INF;                                                      \
    } }
  REP20(INITR)
#undef INITR

  float fx = p[0], fy = p[1], fz = p[2];
  if (tid == 0) {
    float* o = new_xyz + (size_t)b * 512 * 3;
    o[0] = fx; o[1] = fy; o[2] = fz;
  }
  __syncthreads();

  for (int s = 1; s < 512; ++s) {
    float bv = NEG_INF;
    int   bi = 0x7fffffff;
#define SCANR(k) {                                                          \
    const float dx = px##k - fx, dy = py##k - fy, dz = pz##k - fz;          \
    const float d  = __fadd_rn(__fadd_rn(__fmul_rn(dx, dx), __fmul_rn(dy, dy)), \
                               __fmul_rn(dz, dz));                          \
    const float nd = fminf(dd##k, d);                                       \
    dd##k = nd;                                                             \
    if (nd > bv) { bv = nd; bi = tid + ((k) << 10); } }
    REP20(SCANR)
#undef SCANR
    float v  = bv;
    int   i0 = bi;
#pragma unroll
    for (int m = 1; m < 64; m <<= 1) {
      const float ov = __shfl_xor(v, m, 64);
      const int   oi = __shfl_xor(i0, m, 64);
      if (ov > v || (ov == v && oi < i0)) { v = ov; i0 = oi; }
    }
    if (i0 == bi) {  // unique owner lane of this wave's winner
      sv[wave] = bv; si[wave] = bi;
    }
    __syncthreads();
    if (tid < 64) {
      const float lv = (lane < 16) ? sv[lane] : NEG_INF;
      const int   li = (lane < 16) ? si[lane] : 0x7fffffff;
      float v2 = lv;
      int   i2 = li;
#pragma unroll
      for (int m = 1; m < 16; m <<= 1) {
        const float ov = __shfl_xor(v2, m, 64);
        const int   oi = __shfl_xor(i2, m, 64);
        if (ov > v2 || (ov == v2 && oi < i2)) { v2 = ov; i2 = oi; }
      }
      // lanes 0..15 hold the converged winner index i2
      if (lane == 0) {
        const float wx = p[(size_t)i2 * 3 + 0];
        const float wy = p[(size_t)i2 * 3 + 1];
        const float wz = p[(size_t)i2 * 3 + 2];
        bc[0] = wx; bc[1] = wy; bc[2] = wz;
        float* o = new_xyz + ((size_t)b * 512 + s) * 3;
        o[0] = wx; o[1] = wy; o[2] = wz;
      }
    }
    __syncthreads();
    fx = bc[0]; fy = bc[1]; fz = bc[2];
  }
}

// =====================================================================
// FPS small (SA2: 512 -> 128) — single wave, zero barriers (R21).
// Butterfly keeps coords (data is L1-resident; a load would regress).
// =====================================================================
__global__ __launch_bounds__(64)
void fps2_wave_kernel(const float* __restrict__ xyz, float* __restrict__ new_xyz) {
  const int b    = blockIdx.x;
  const int lane = threadIdx.x;
  const float* p = xyz + (size_t)b * 512 * 3;
  float px[8], py[8], pz[8], dd[8];
#pragma unroll
  for (int j = 0; j < 8; ++j) {
    const int i = lane + (j << 6);
    px[j] = p[i * 3 + 0]; py[j] = p[i * 3 + 1]; pz[j] = p[i * 3 + 2];
    dd[j] = 1e10f;
  }
  float fx = p[0], fy = p[1], fz = p[2];
  if (lane == 0) {
    float* o = new_xyz + (size_t)b * 128 * 3;
    o[0] = fx; o[1] = fy; o[2] = fz;
  }
  for (int s = 1; s < 128; ++s) {
    float bv = NEG_INF;
    int   bi = 0x7fffffff;
    float bx = 0.f, by = 0.f, bz = 0.f;
#pragma unroll
    for (int j = 0; j < 8; ++j) {
      const float dx = px[j] - fx, dy = py[j] - fy, dz = pz[j] - fz;
      const float d  = __fadd_rn(__fadd_rn(__fmul_rn(dx, dx), __fmul_rn(dy, dy)),
                                 __fmul_rn(dz, dz));
      const float nd = fminf(dd[j], d);
      dd[j] = nd;
      if (nd > bv) { bv = nd; bi = lane + (j << 6); bx = px[j]; by = py[j]; bz = pz[j]; }
    }
    float v = bv; int i0 = bi;
    float wx = bx, wy = by, wz = bz;
#pragma unroll
    for (int m = 1; m < 64; m <<= 1) {
      const float ov = __shfl_xor(v, m, 64);
      const int   oi = __shfl_xor(i0, m, 64);
      const float ox = __shfl_xor(wx, m, 64);
      const float oy = __shfl_xor(wy, m, 64);
      const float oz = __shfl_xor(wz, m, 64);
      if (ov > v || (ov == v && oi < i0)) { v = ov; i0 = oi; wx = ox; wy = oy; wz = oz; }
    }
    fx = wx; fy = wy; fz = wz;  // converged on all lanes
    if (lane == 0) {
      float* o = new_xyz + ((size_t)b * 128 + s) * 3;
      o[0] = fx; o[1] = fy; o[2] = fz;
    }
  }
}

// =====================================================================
// Ball query (SA2): ONE WAVE PER CENTER, ballot + prefix-popcount.
// =====================================================================
template <int N, int NS>
__global__ __launch_bounds__(256)
void ballquery_wave_kernel(const float* __restrict__ centers,
                           const float* __restrict__ pts,
                           int* __restrict__ idx, int BS, int S, float r2) {
  const int w    = (blockIdx.x * 256 + threadIdx.x) >> 6;
  const int lane = threadIdx.x & 63;
  if (w >= BS) return;
  const int b = w / S;
  const float cx = centers[w * 3 + 0];
  const float cy = centers[w * 3 + 1];
  const float cz = centers[w * 3 + 2];
  const float* p = pts + (size_t)b * N * 3;
  int* o = idx + (size_t)w * NS;
  int total = 0;
  int first = -1;
  for (int i0 = 0; i0 < N && total < NS; i0 += 64) {
    const int i = i0 + lane;
    bool pred = false;
    if (i < N) {
      const float dx = cx - p[i * 3 + 0];
      const float dy = cy - p[i * 3 + 1];
      const float dz = cz - p[i * 3 + 2];
      const float d2 = __fadd_rn(__fadd_rn(__fmul_rn(dx, dx), __fmul_rn(dy, dy)),
                                 __fmul_rn(dz, dz));
      pred = (d2 < r2);
    }
    const unsigned long long mask = __ballot(pred);
    if (mask) {
      const unsigned long long below = (lane == 0) ? 0ull : (mask << (64 - lane));
      const int before = __popcll(below);
      if (pred && (total + before) < NS) o[total + before] = i;
      if (first < 0) first = i0 + (__ffsll((long long)mask) - 1);
      total += __popcll(mask);
    }
  }
  if (lane >= total && lane < NS) o[lane] = first;
}

// =====================================================================
// Fused ballquery(SA1, r=0.2, ns=32) + group1 (R21, validated).
// =====================================================================
__global__ __launch_bounds__(256)
void ballq_group1_kernel(const float* __restrict__ centers,  // xyz1 [8,512,3]
                         const float* __restrict__ pts,      // obj  [8,20000,3]
                         float* __restrict__ X1) {           // [8*512*32,3]
  __shared__ int sIdx[4][32];
  const int wIn  = threadIdx.x >> 6;
  const int w    = (blockIdx.x * 256 + threadIdx.x) >> 6;
  const int lane = threadIdx.x & 63;
  if (w >= 4096) return;
  const int b = w >> 9;
  const float cx = centers[w * 3 + 0];
  const float cy = centers[w * 3 + 1];
  const float cz = centers[w * 3 + 2];
  const float* p = pts + (size_t)b * 20000 * 3;
  int total = 0;
  int first = -1;
  for (int i0 = 0; i0 < 20000 && total < 32; i0 += 64) {
    const int i = i0 + lane;
    bool pred = false;
    if (i < 20000) {
      const float dx = cx - p[i * 3 + 0];
      const float dy = cy - p[i * 3 + 1];
      const float dz = cz - p[i * 3 + 2];
      const float d2 = __fadd_rn(__fadd_rn(__fmul_rn(dx, dx), __fmul_rn(dy, dy)),
                                 __fmul_rn(dz, dz));
      pred = (d2 < 0.04f);
    }
    const unsigned long long mask = __ballot(pred);
    if (mask) {
      const unsigned long long below = (lane == 0) ? 0ull : (mask << (64 - lane));
      const int before = __popcll(below);
      if (pred && (total + before) < 32) sIdx[wIn][total + before] = i;
      if (first < 0) first = i0 + (__ffsll((long long)mask) - 1);
      total += __popcll(mask);
    }
  }
  __builtin_amdgcn_wave_barrier();  // scheduling fence: LDS writes before reads
  if (lane < 32) {
    const int i = (lane < total) ? sIdx[wIn][lane] : first;
    const float* q = p + (size_t)i * 3;
    float* o = X1 + ((size_t)w * 32 + lane) * 3;
    o[0] = (q[0] - cx) / 0.2f;
    o[1] = (q[1] - cy) / 0.2f;
    o[2] = (q[2] - cz) / 0.2f;
  }
}

// =====================================================================
// group2 with BN(f1) fused (R21, validated).
// =====================================================================
__global__ __launch_bounds__(256)
void group2_kernel(const float* __restrict__ xyz1,
                   const float* __restrict__ xyz2,
                   const float* __restrict__ P1,
                   const float* __restrict__ st,
                   const int* __restrict__ idx2,
                   float* __restrict__ X2) {
  __shared__ float sM[128], sS[128];
  const int t0 = threadIdx.x;
  if (t0 < 128) {
    float s = 0.f, q = 0.f;
#pragma unroll
    for (int bn = 0; bn < NBINS; ++bn) {
      s += st[bn * 256 + t0];
      q += st[bn * 256 + 128 + t0];
    }
    const float inv = 1.f / 131072.f;
    const float m  = s * inv;
    const float vr = fmaf(-m, m, q * inv);
    sM[t0] = m;
    sS[t0] = rsqrtf(vr + EPS_BN);
  }
  __syncthreads();
  const int t = blockIdx.x * 256 + t0;
  if (t >= 65536 * 131) return;
  const int r = t / 131;
  const int c = t - r * 131;
  const int g = r >> 6;
  const int b = g >> 7;
  const int i = idx2[r];
  float v;
  if (c < 3) {
    v = (xyz1[((size_t)b * 512 + i) * 3 + c] - xyz2[(size_t)g * 3 + c]) / 0.4f;
  } else {
    const int cc = c - 3;
    v = P1[((size_t)b * 512 + i) * 128 + cc];
    v = fmaxf(0.f, (v - sM[cc]) * sS[cc]);
  }
  X2[t] = v;
}

// =====================================================================
// build_x3 with BN(f2) fused (R21, validated).
// =====================================================================
__global__ __launch_bounds__(256)
void build_x3_kernel(const float* __restrict__ xyz2, const float* __restrict__ P2,
                     const float* __restrict__ st, float* __restrict__ X3) {
  __shared__ float sM[256], sS[256];
  const int t0 = threadIdx.x;
  {
    float s = 0.f, q = 0.f;
#pragma unroll
    for (int bn = 0; bn < NBINS; ++bn) {
      s += st[bn * 512 + t0];
      q += st[bn * 512 + 256 + t0];
    }
    const float inv = 1.f / 65536.f;
    const float m  = s * inv;
    const float vr = fmaf(-m, m, q * inv);
    sM[t0] = m;
    sS[t0] = rsqrtf(vr + EPS_BN);
  }
  __syncthreads();
  const int t = blockIdx.x * 256 + t0;
  if (t >= 1024 * 259) return;
  const int r = t / 259;
  const int c = t - r * 259;
  float v;
  if (c < 3) {
    v = xyz2[r * 3 + c];
  } else {
    const int cc = c - 3;
    v = P2[(size_t)r * 256 + cc];
    v = fmaxf(0.f, (v - sM[cc]) * sS[cc]);
  }
  X3[t] = v;
}

// =====================================================================
// Fused head — BN(objf) inlined into comb load (R21, validated).
// =====================================================================
__global__ __launch_bounds__(512) void head_kernel(
    const float* __restrict__ gfeat, const float* __restrict__ Y3p,
    const float* __restrict__ st11,
    const float* __restrict__ w0, const float* __restrict__ b0,
    const float* __restrict__ w1, const float* __restrict__ b1,
    const float* __restrict__ w2, const float* __restrict__ b2,
    float* __restrict__ out) {
  __shared__ __align__(16) float comb[8 * 1152];
  __shared__ __align__(16) float h1[8 * 512];
  __shared__ __align__(16) float h2[8 * 256];
  const int tid = threadIdx.x;
  for (int i = tid; i < 8 * 1152; i += 512) {
    const int b = i / 1152, c = i - b * 1152;
    float v;
    if (c < 128) {
      v = gfeat[b * 128 + c];
    } else {
      const int cc = c - 128;
      float s = 0.f, q = 0.f;
#pragma unroll
      for (int bn = 0; bn < NBINS; ++bn) {
        s += st11[bn * 2048 + cc];
        q += st11[bn * 2048 + 1024 + cc];
      }
      const float inv = 1.f / 1024.f;
      const float m  = s * inv;
      const float vr = fmaf(-m, m, q * inv);
      const float sc = rsqrtf(vr + EPS_BN);
      v = fmaxf(0.f, (Y3p[b * 1024 + cc] - m) * sc);
    }
    comb[i] = v;
  }
  __syncthreads();
  for (int c = tid; c < 1152; c += 512) {
    float s = 0.f;
#pragma unroll
    for (int b = 0; b < 8; ++b) s += comb[b * 1152 + c];
    const float m = s * 0.125f;
    float v = 0.f;
#pragma unroll
    for (int b = 0; b < 8; ++b) { const float d = comb[b * 1152 + c] - m; v = fmaf(d, d, v); }
    const float sc = rsqrtf(v * 0.125f + EPS_BN);
#pragma unroll
    for (int b = 0; b < 8; ++b) comb[b * 1152 + c] = (comb[b * 1152 + c] - m) * sc;
  }
  __syncthreads();
  {  // layer 0: 1152 -> 512
    float a[8];
#pragma unroll
    for (int b = 0; b < 8; ++b) a[b] = b0[tid];
    const float* wr = w0 + (size_t)tid * 1152;
    for (int ci = 0; ci < 1152; ci += 4) {
      const float4 wv = *(const float4*)(wr + ci);
#pragma unroll
      for (int b = 0; b < 8; ++b) {
        const float4 xv = *(const float4*)(&comb[b * 1152 + ci]);
        a[b] = fmaf(xv.x, wv.x, a[b]);
        a[b] = fmaf(xv.y, wv.y, a[b]);
        a[b] = fmaf(xv.z, wv.z, a[b]);
        a[b] = fmaf(xv.w, wv.w, a[b]);
      }
    }
    float s = 0.f;
#pragma unroll
    for (int b = 0; b < 8; ++b) s += a[b];
    const float m = s * 0.125f;
    float v = 0.f;
#pragma unroll
    for (int b = 0; b < 8; ++b) { const float d = a[b] - m; v = fmaf(d, d, v); }
    const float sc = rsqrtf(v * 0.125f + EPS_BN);
#pragma unroll
    for (int b = 0; b < 8; ++b) h1[b * 512 + tid] = fmaxf(0.f, (a[b] - m) * sc);
  }
  __syncthreads();
  if (tid < 256) {  // layer 1: 512 -> 256
    float a[8];
#pragma unroll
    for (int b = 0; b < 8; ++b) a[b] = b1[tid];
    const float* wr = w1 + (size_t)tid * 512;
    for (int ci = 0; ci < 512; ci += 4) {
      const float4 wv = *(const float4*)(wr + ci);
#pragma unroll
      for (int b = 0; b < 8; ++b) {
        const float4 xv = *(const float4*)(&h1[b * 512 + ci]);
        a[b] = fmaf(xv.x, wv.x, a[b]);
        a[b] = fmaf(xv.y, wv.y, a[b]);
        a[b] = fmaf(xv.z, wv.z, a[b]);
        a[b] = fmaf(xv.w, wv.w, a[b]);
      }
    }
    float s = 0.f;
#pragma unroll
    for (int b = 0; b < 8; ++b) s += a[b];
    const float m = s * 0.125f;
    float v = 0.f;
#pragma unroll
    for (int b = 0; b < 8; ++b) { const float d = a[b] - m; v = fmaf(d, d, v); }
    const float sc = rsqrtf(v * 0.125f + EPS_BN);
#pragma unroll
    for (int b = 0; b < 8; ++b) h2[b * 256 + tid] = fmaxf(0.f, (a[b] - m) * sc);
  }
  __syncthreads();
  if (tid < 8) {  // layer 2: 256 -> 1, relu
    float s = b2[0];
    for (int ci = 0; ci < 256; ++ci) s = fmaf(h2[tid * 256 + ci], w2[ci], s);
    out[tid] = fmaxf(0.f, s);
  }
}

// =====================================================================
// Host orchestration — R21 structure (validated).
// =====================================================================
extern "C" void kernel_launch(void* const* d_in, const int* in_sizes, int n_in,
                              void* d_out, int out_size, void* d_ws, size_t ws_size,
                              hipStream_t stream) {
  (void)in_sizes; (void)n_in; (void)out_size; (void)ws_size;
  const float* obj  = (const float*)d_in[0];
  const float* grip = (const float*)d_in[1];
  const float* s1w0 = (const float*)d_in[2];
  const float* s1w1 = (const float*)d_in[3];
  const float* s1w2 = (const float*)d_in[4];
  const float* s2w0 = (const float*)d_in[5];
  const float* s2w1 = (const float*)d_in[6];
  const float* s2w2 = (const float*)d_in[7];
  const float* s3w0 = (const float*)d_in[8];
  const float* s3w1 = (const float*)d_in[9];
  const float* s3w2 = (const float*)d_in[10];
  const float* gw0  = (const float*)d_in[11];
  const float* gw1  = (const float*)d_in[12];
  const float* gw2  = (const float*)d_in[13];
  const float* hw0  = (const float*)d_in[14];
  const float* hb0  = (const float*)d_in[15];
  const float* hw1  = (const float*)d_in[16];
  const float* hb1  = (const float*)d_in[17];
  const float* hw2  = (const float*)d_in[18];
  const float* hb2  = (const float*)d_in[19];
  float* out = (float*)d_out;

  // ---- workspace layout (float offsets) ----
  float* wsf   = (float*)d_ws;
  float* stats = wsf;
  float* xyz1  = wsf + 23040;
  float* xyz2  = wsf + 35328;
  float* gfeat = wsf + 38400;
  float* x3    = wsf + 834048;
  int*   idx2  = (int*)(wsf + 1230336);
  float* bufP  = wsf + 1295872;
  float* bufQ  = wsf + 18073088;

  static const int st_off[12] = {0, 512, 1536, 2560, 3072, 3584,
                                 4608, 5632, 6656, 8704, 10752, 14848};
  auto st = [&](int li) { return stats + st_off[li]; };

  hipMemsetAsync(stats, 0, 23040 * sizeof(float), stream);

  auto gemm0 = [&](const float* X, const float* Wm, float* Y, int R, int Cin, int Cout,
                   int lo) {
    dim3 g((R + 127) / 128, (Cout + 127) / 128);
    gemm_xwt<false, false><<<g, 256, 0, stream>>>(X, Wm, Y, R, Cin, Cout, nullptr, 0,
                                                  st(lo), nullptr, 0);
  };
  auto gemmf = [&](const float* X, const float* Wm, float* Y, int R, int Cin, int Cout,
                   int li, int lo) {
    dim3 g((R + 127) / 128, (Cout + 127) / 128);
    gemm_xwt<true, false><<<g, 256, 0, stream>>>(X, Wm, Y, R, Cin, Cout, st(li), R,
                                                 st(lo), nullptr, 0);
  };
  auto gemmfM = [&](const float* X, const float* Wm, float* pooled, int R, int Cin,
                    int Cout, int li, int lo, int ns) {
    dim3 g((R + 127) / 128, (Cout + 127) / 128);
    gemm_xwt<true, true><<<g, 256, 0, stream>>>(X, Wm, nullptr, R, Cin, Cout, st(li), R,
                                                st(lo), pooled, ns);
  };
  auto applymax_k = [&](const float* Y, int li, int G, int ns, int C, float* o) {
    const int n = G * C;
    bn_apply_relu_maxpool<<<(n + 255) / 256, 256, 0, stream>>>(Y, st(li), o, G, ns, C);
  };

  // ---- SA1 FPS (R23: coord-tracking-free scan) ----
  fps_sa1_kernel<<<8, 1024, 0, stream>>>(obj, xyz1);

  // ---- gripper encoder: 3 -> 64 -> 128 -> 128 -> maxpool ----
  float* gY1 = bufP;
  float* gY2 = bufP + 262144;
  float* gY3 = bufP + 786432;
  gemm0(grip, gw0, gY1, 4096, 3, 64, 0);
  gemmf(gY1, gw1, gY2, 4096, 64, 128, 0, 1);
  gemmf(gY2, gw2, gY3, 4096, 128, 128, 1, 2);
  applymax_k(gY3, 2, 8, 512, 128, gfeat);

  // ---- SA1: fused ballquery+group (ns=32), MLP 3->64->64->128 ----
  float* X1 = bufQ;
  ballq_group1_kernel<<<1024, 256, 0, stream>>>(xyz1, obj, X1);
  gemm0(X1, s1w0, bufP, 131072, 3, 64, 3);
  gemmf(bufP, s1w1, bufQ, 131072, 64, 64, 3, 4);
  gemmfM(bufQ, s1w2, bufP, 131072, 64, 128, 4, 5, 32);   // bufP: pooled f1-raw 4096x128

  // ---- SA2: FPS 512->128 (single wave), ball ns=64, MLP 131->128->128->256 ----
  fps2_wave_kernel<<<8, 64, 0, stream>>>(xyz1, xyz2);
  ballquery_wave_kernel<512, 64><<<256, 256, 0, stream>>>(xyz2, xyz1, idx2, 1024, 128, 0.16f);
  float* X2 = bufQ;
  group2_kernel<<<(65536 * 131 + 255) / 256, 256, 0, stream>>>(xyz1, xyz2, bufP, st(5),
                                                               idx2, X2);
  gemm0(X2, s2w0, bufP, 65536, 131, 128, 6);
  gemmf(bufP, s2w1, bufQ, 65536, 128, 128, 6, 7);
  gemmfM(bufQ, s2w2, bufP, 65536, 128, 256, 7, 8, 64);   // bufP: pooled f2-raw 1024x256

  // ---- SA3 (group_all): x3 (BN fused) -> 256 -> 512 -> 1024 -> maxpool ----
  build_x3_kernel<<<(1024 * 259 + 255) / 256, 256, 0, stream>>>(xyz2, bufP, st(8), x3);
  float* Y3a = bufQ;
  float* Y3b = bufQ + 262144;
  float* Y3p = bufQ + 786432;
  gemm0(x3, s3w0, Y3a, 1024, 259, 256, 9);
  gemmf(Y3a, s3w1, Y3b, 1024, 256, 512, 9, 10);
  gemmfM(Y3b, s3w2, Y3p, 1024, 512, 1024, 10, 11, 128);  // Y3p: pooled objf-raw 8x1024

  // ---- head (BN(objf) fused) ----
  head_kernel<<<1, 512, 0, stream>>>(gfeat, Y3p, st(11), hw0, hb0, hw1, hb1, hw2, hb2, out);
}